// Round 4
// baseline (963.702 us; speedup 1.0000x reference)
//
#include <hip/hip_runtime.h>
#include <hip/hip_bf16.h>

#define BB  32
#define LHH 1024
#define LUU 128
#define HDD 256
#define NEGF (-1e30f)

// ---- workspace layout (float offsets) ----
static constexpr size_t S_OFF    = 0;                           // [B][LH][LU] raw S
static constexpr size_t UWB_OFF  = S_OFF + (size_t)BB*LHH*LUU;  // [B][LU]
static constexpr size_t RM_OFF   = UWB_OFF + (size_t)BB*LUU;    // [B][LH] row max
static constexpr size_t RI_OFF   = RM_OFF + (size_t)BB*LHH;     // [B][LH] 1/row sum
static constexpr size_t PM_OFF   = RI_OFF + (size_t)BB*LHH;     // [B][8][LU]
static constexpr size_t PS_OFF   = PM_OFF + (size_t)BB*8*LUU;   // [B][8][LU]
static constexpr size_t CM_OFF   = PS_OFF + (size_t)BB*8*LUU;   // [B][LU] col max
static constexpr size_t CI_OFF   = CM_OFF + (size_t)BB*LUU;     // [B][LU] 1/col sum
static constexpr size_t C_OFF    = CI_OFF + (size_t)BB*LUU;     // [B][LU][HD]
static constexpr size_t FLAG_OFF = C_OFF + (size_t)BB*LUU*HDD;  // 1 int (mask dtype flag)
static constexpr size_t WS_FLOATS= FLAG_OFF + 1;

// mask accessor: flag==1 -> bool8 bytes; flag==0 -> 4-byte elements (int32 or f32 bits)
__device__ __forceinline__ float mval(const void* p, int idx, int flag) {
    if (flag) return ((const unsigned char*)p)[idx] ? 1.0f : 0.0f;
    return (((const int*)p)[idx] != 0) ? 1.0f : 0.0f;
}
// clamped exp: identity for all mathematically-contributing args (<=0), never inf
__device__ __forceinline__ float cexpf(float x) { return __expf(fminf(x, 60.0f)); }
__device__ __forceinline__ float grcp(float x)  { return 1.0f / fmaxf(x, 1e-38f); }

// ---------------- detect mask dtype ----------------
__global__ void k_detect(const unsigned char* __restrict__ hm, float* __restrict__ ws) {
    if (threadIdx.x == 0)
        reinterpret_cast<int*>(ws)[FLAG_OFF] = (hm[1] != 0) ? 1 : 0;
}

// ---------------- K0: uwb[b,j] = u[b,j,:]·w_u + bias ----------------
__global__ __launch_bounds__(256) void k_uwb(const float* __restrict__ u,
                                             const float* __restrict__ w,
                                             const float* __restrict__ bias,
                                             float* __restrict__ ws) {
    int wave = threadIdx.x >> 6;
    int lane = threadIdx.x & 63;
    int idx  = blockIdx.x * 4 + wave;          // b*LU + j
    int b = idx >> 7, j = idx & 127;
    const float4* u4  = reinterpret_cast<const float4*>(u + ((size_t)(b * LUU + j)) * HDD);
    const float4* wu4 = reinterpret_cast<const float4*>(w + HDD);
    float4 a = u4[lane], c = wu4[lane];
    float s = a.x * c.x + a.y * c.y + a.z * c.z + a.w * c.w;
    #pragma unroll
    for (int off = 32; off; off >>= 1) s += __shfl_xor(s, off);
    if (lane == 0) ws[UWB_OFF + idx] = s + bias[0];
}

// ---------------- K1: S + row softmax stats ----------------
// v[j][k] = w_h[k] + w_hu[k]*u[b,j,k], staged in 32-k double-buffered LDS chunks,
// transposed layout v_lds[k][j] with row stride 129 (bank-conflict-free scalar reads).
// Each block: 32 i-rows (4 waves x 8 rows), all 128 j, K=256 in 8 chunks.
__global__ __launch_bounds__(256, 4) void k_S(const float* __restrict__ h,
                                              const float* __restrict__ u,
                                              const void* __restrict__ u_mask,
                                              const float* __restrict__ w,
                                              float* __restrict__ ws) {
    __shared__ float vbuf[2][32 * 129];        // 2 x 16.1 KiB
    int b  = blockIdx.x;
    int it = blockIdx.y;                       // i-tile of 32 rows
    int t  = threadIdx.x;
    int flag = reinterpret_cast<const int*>(ws)[FLAG_OFF];
    const float* wh  = w;
    const float* whu = w + 2 * HDD;

    // staging mapping: thread covers u-row jrow, k-halfchunk of 16
    int jrow = t >> 1, half = t & 1;
    const float* ubase = u + ((size_t)(b * LUU + jrow)) * HDD + half * 16;
    const float* whb   = wh  + half * 16;
    const float* whub  = whu + half * 16;

    float4 ur[4];
    // prologue: stage chunk 0
    #pragma unroll
    for (int q = 0; q < 4; ++q) ur[q] = *reinterpret_cast<const float4*>(ubase + q * 4);
    #pragma unroll
    for (int q = 0; q < 4; ++q) {
        float4 a  = *reinterpret_cast<const float4*>(whb  + q * 4);
        float4 cc = *reinterpret_cast<const float4*>(whub + q * 4);
        int kl = half * 16 + q * 4;
        vbuf[0][(kl + 0) * 129 + jrow] = a.x + cc.x * ur[q].x;
        vbuf[0][(kl + 1) * 129 + jrow] = a.y + cc.y * ur[q].y;
        vbuf[0][(kl + 2) * 129 + jrow] = a.z + cc.z * ur[q].z;
        vbuf[0][(kl + 3) * 129 + jrow] = a.w + cc.w * ur[q].w;
    }

    int wave = t >> 6, lane = t & 63;
    int row0 = it * 32 + wave * 8;
    const float* hbase = h + ((size_t)(b * LHH + row0)) * HDD;
    float um0 = mval(u_mask, b * LUU + lane, flag);
    float um1 = mval(u_mask, b * LUU + lane + 64, flag);
    float uw0 = ws[UWB_OFF + b * LUU + lane];
    float uw1 = ws[UWB_OFF + b * LUU + lane + 64];

    float acc0[8], acc1[8];
    #pragma unroll
    for (int r = 0; r < 8; ++r) { acc0[r] = 0.f; acc1[r] = 0.f; }

    for (int c = 0; c < 8; ++c) {
        __syncthreads();                       // chunk c resident in vbuf[c&1]
        int k0 = c * 32;
        if (c < 7) {                           // issue next chunk's global loads early
            #pragma unroll
            for (int q = 0; q < 4; ++q)
                ur[q] = *reinterpret_cast<const float4*>(ubase + (c + 1) * 32 + q * 4);
        }
        const float* vb = vbuf[c & 1];
        #pragma unroll
        for (int k4 = 0; k4 < 8; ++k4) {
            int kk = k0 + k4 * 4;
            const float* vk = vb + (k4 * 4) * 129;
            float4 v0, v1;
            v0.x = vk[lane];           v1.x = vk[lane + 64];
            v0.y = vk[129 + lane];     v1.y = vk[129 + lane + 64];
            v0.z = vk[258 + lane];     v1.z = vk[258 + lane + 64];
            v0.w = vk[387 + lane];     v1.w = vk[387 + lane + 64];
            #pragma unroll
            for (int r = 0; r < 8; ++r) {
                float4 hv = *reinterpret_cast<const float4*>(hbase + (size_t)r * HDD + kk);
                acc0[r] += hv.x * v0.x + hv.y * v0.y + hv.z * v0.z + hv.w * v0.w;
                acc1[r] += hv.x * v1.x + hv.y * v1.y + hv.z * v1.z + hv.w * v1.w;
            }
        }
        if (c < 7) {                           // write next chunk (other buffer) late
            float* vbn = vbuf[(c + 1) & 1];
            const float* whn  = whb  + (c + 1) * 32;
            const float* whun = whub + (c + 1) * 32;
            #pragma unroll
            for (int q = 0; q < 4; ++q) {
                float4 a  = *reinterpret_cast<const float4*>(whn  + q * 4);
                float4 cc = *reinterpret_cast<const float4*>(whun + q * 4);
                int kl = half * 16 + q * 4;
                vbn[(kl + 0) * 129 + jrow] = a.x + cc.x * ur[q].x;
                vbn[(kl + 1) * 129 + jrow] = a.y + cc.y * ur[q].y;
                vbn[(kl + 2) * 129 + jrow] = a.z + cc.z * ur[q].z;
                vbn[(kl + 3) * 129 + jrow] = a.w + cc.w * ur[q].w;
            }
        }
    }

    #pragma unroll
    for (int r = 0; r < 8; ++r) {
        int row = row0 + r;
        float S0 = acc0[r] + uw0;
        float S1 = acc1[r] + uw1;
        float* Srow = ws + S_OFF + ((size_t)(b * LHH + row)) * LUU;
        Srow[lane] = S0;
        Srow[lane + 64] = S1;
        float ms = fmaxf(um0 > 0.f ? S0 : NEGF, um1 > 0.f ? S1 : NEGF);
        #pragma unroll
        for (int off = 32; off; off >>= 1) ms = fmaxf(ms, __shfl_xor(ms, off));
        float e = um0 * cexpf(S0 - ms) + um1 * cexpf(S1 - ms);
        #pragma unroll
        for (int off = 32; off; off >>= 1) e += __shfl_xor(e, off);
        if (lane == 0) {
            ws[RM_OFF + b * LHH + row] = ms;
            ws[RI_OFF + b * LHH + row] = grcp(e);
        }
    }
}

// ---------------- K2: partial column stats ----------------
__global__ __launch_bounds__(256) void k_colpart(const void* __restrict__ h_mask,
                                                 float* __restrict__ ws) {
    int b = blockIdx.x, c = blockIdx.y;        // chunk of 128 i
    int t = threadIdx.x;
    int j = t & 127, ih = t >> 7;
    int flag = reinterpret_cast<const int*>(ws)[FLAG_OFF];
    float m = NEGF, s = 0.f;
    const float* Sb = ws + S_OFF + ((size_t)b * LHH) * LUU;
    int i0 = c * 128;
    for (int ii = ih; ii < 128; ii += 2) {
        int i = i0 + ii;
        if (mval(h_mask, b * LHH + i, flag) > 0.f) {
            float x  = Sb[(size_t)i * LUU + j];
            float mn = fmaxf(m, x);
            s = s * __expf(m - mn) + __expf(x - mn);
            m = mn;
        }
    }
    __shared__ float sm_m[128], sm_s[128];
    if (ih == 0) { sm_m[j] = m; sm_s[j] = s; }
    __syncthreads();
    if (ih == 1) {
        float m0 = sm_m[j], s0 = sm_s[j];
        float mn = fmaxf(m0, m);
        float sc = s0 * __expf(fminf(m0 - mn, 0.f)) + s * __expf(fminf(m - mn, 0.f));
        ws[PM_OFF + (b * 8 + c) * LUU + j] = mn;
        ws[PS_OFF + (b * 8 + c) * LUU + j] = sc;
    }
}

// ---------------- K2b: combine partial column stats ----------------
__global__ __launch_bounds__(128) void k_colcomb(float* __restrict__ ws) {
    int b = blockIdx.x, j = threadIdx.x;
    float m = NEGF;
    #pragma unroll
    for (int c = 0; c < 8; ++c) m = fmaxf(m, ws[PM_OFF + (b * 8 + c) * LUU + j]);
    float s = 0.f;
    #pragma unroll
    for (int c = 0; c < 8; ++c)
        s += ws[PS_OFF + (b * 8 + c) * LUU + j] * cexpf(ws[PM_OFF + (b * 8 + c) * LUU + j] - m);
    ws[CM_OFF + b * LUU + j] = m;
    ws[CI_OFF + b * LUU + j] = grcp(s);
}

// ---------------- K3: C[b,q,:] = sum_i a_t[i,q] * h[b,i,:] ----------------
__global__ __launch_bounds__(256) void k_C(const float* __restrict__ h,
                                           const void* __restrict__ u_mask,
                                           float* __restrict__ ws) {
    int b = blockIdx.x, ut = blockIdx.y;       // u-tile of 16
    int u0 = ut * 16;
    int t = threadIdx.x;
    int flag = reinterpret_cast<const int*>(ws)[FLAG_OFF];
    __shared__ float a_l[64][16];
    float acc[16];
    #pragma unroll
    for (int q = 0; q < 16; ++q) acc[q] = 0.f;

    const float* Sb = ws + S_OFF + (size_t)b * LHH * LUU;
    const float* rm = ws + RM_OFF + b * LHH;
    const float* ri = ws + RI_OFF + b * LHH;
    const float* hb = h + (size_t)b * LHH * HDD;

    int iq = t >> 2, uq = t & 3;
    float um_[4];
    #pragma unroll
    for (int c = 0; c < 4; ++c)
        um_[c] = mval(u_mask, b * LUU + u0 + uq * 4 + c, flag);

    for (int i0 = 0; i0 < LHH; i0 += 64) {
        __syncthreads();
        {
            int i = i0 + iq;
            float4 s4 = *reinterpret_cast<const float4*>(Sb + (size_t)i * LUU + u0 + uq * 4);
            float mm = rm[i], rr = ri[i];
            a_l[iq][uq * 4 + 0] = um_[0] * cexpf(s4.x - mm) * rr;
            a_l[iq][uq * 4 + 1] = um_[1] * cexpf(s4.y - mm) * rr;
            a_l[iq][uq * 4 + 2] = um_[2] * cexpf(s4.z - mm) * rr;
            a_l[iq][uq * 4 + 3] = um_[3] * cexpf(s4.w - mm) * rr;
        }
        __syncthreads();
        #pragma unroll 4
        for (int ii = 0; ii < 64; ++ii) {
            float hval = hb[(size_t)(i0 + ii) * HDD + t];
            #pragma unroll
            for (int q = 0; q < 4; ++q) {
                float4 a4 = *reinterpret_cast<const float4*>(&a_l[ii][q * 4]);
                acc[q * 4 + 0] += a4.x * hval;
                acc[q * 4 + 1] += a4.y * hval;
                acc[q * 4 + 2] += a4.z * hval;
                acc[q * 4 + 3] += a4.w * hval;
            }
        }
    }
    #pragma unroll
    for (int q = 0; q < 16; ++q)
        ws[C_OFF + ((size_t)(b * LUU + u0 + q)) * HDD + t] = acc[q];
}

// ---------------- K4: U_tilde, H_tilde, output concat ----------------
__global__ __launch_bounds__(256) void k_out(const float* __restrict__ h,
                                             const float* __restrict__ u,
                                             const void* __restrict__ h_mask,
                                             const void* __restrict__ u_mask,
                                             const float* __restrict__ ws,
                                             float* __restrict__ out) {
    int b = blockIdx.x, itile = blockIdx.y;    // tiles of 16 rows
    int i0 = itile * 16;
    int t = threadIdx.x;
    int flag = reinterpret_cast<const int*>(ws)[FLAG_OFF];
    __shared__ float aT[128][16], bT[128][16];
    __shared__ float cm_l[128], ci_l[128], um_l[128];
    __shared__ float rm_l[16], ri_l[16], hm_l[16];

    if (t < 128) {
        cm_l[t] = ws[CM_OFF + b * LUU + t];
        ci_l[t] = ws[CI_OFF + b * LUU + t];
        um_l[t] = mval(u_mask, b * LUU + t, flag);
    } else if (t < 144) {
        int r = t - 128;
        rm_l[r] = ws[RM_OFF + b * LHH + i0 + r];
        ri_l[r] = ws[RI_OFF + b * LHH + i0 + r];
        hm_l[r] = mval(h_mask, b * LHH + i0 + r, flag);
    }
    __syncthreads();

    {
        int j4 = t & 31, rp = t >> 5;          // rp in [0,8)
        #pragma unroll
        for (int half = 0; half < 2; ++half) {
            int r = rp + half * 8;
            int i = i0 + r;
            float4 s4 = *reinterpret_cast<const float4*>(
                ws + S_OFF + ((size_t)(b * LHH + i)) * LUU + j4 * 4);
            float mm = rm_l[r], rr = ri_l[r], hm = hm_l[r];
            float xs[4] = {s4.x, s4.y, s4.z, s4.w};
            #pragma unroll
            for (int c = 0; c < 4; ++c) {
                int j = j4 * 4 + c;
                aT[j][r] = um_l[j] * cexpf(xs[c] - mm) * rr;
                bT[j][r] = hm * cexpf(xs[c] - cm_l[j]) * ci_l[j];
            }
        }
    }
    __syncthreads();

    float accU[16], accH[16];
    #pragma unroll
    for (int r = 0; r < 16; ++r) { accU[r] = 0.f; accH[r] = 0.f; }

    const float* ub = u + (size_t)b * LUU * HDD;
    const float* Cb = ws + C_OFF + (size_t)b * LUU * HDD;

    #pragma unroll 2
    for (int j = 0; j < LUU; ++j) {
        float uval = ub[(size_t)j * HDD + t];
        float cval = Cb[(size_t)j * HDD + t];
        #pragma unroll
        for (int q = 0; q < 4; ++q) {
            float4 a4 = *reinterpret_cast<const float4*>(&aT[j][q * 4]);
            float4 b4 = *reinterpret_cast<const float4*>(&bT[j][q * 4]);
            accU[q * 4 + 0] += a4.x * uval;
            accU[q * 4 + 1] += a4.y * uval;
            accU[q * 4 + 2] += a4.z * uval;
            accU[q * 4 + 3] += a4.w * uval;
            accH[q * 4 + 0] += b4.x * cval;
            accH[q * 4 + 1] += b4.y * cval;
            accH[q * 4 + 2] += b4.z * cval;
            accH[q * 4 + 3] += b4.w * cval;
        }
    }

    #pragma unroll
    for (int r = 0; r < 16; ++r) {
        int i = i0 + r;
        float hval = h[((size_t)(b * LHH + i)) * HDD + t];
        size_t base = ((size_t)(b * LHH + i)) * (4 * HDD) + t;
        out[base]           = hval;
        out[base + HDD]     = accU[r];
        out[base + 2 * HDD] = hval * accU[r];
        out[base + 3 * HDD] = hval * accH[r];
    }
}

extern "C" void kernel_launch(void* const* d_in, const int* in_sizes, int n_in,
                              void* d_out, int out_size, void* d_ws, size_t ws_size,
                              hipStream_t stream) {
    const float* h = (const float*)d_in[0];
    const float* u = (const float*)d_in[1];
    const void*  h_mask = d_in[2];
    const void*  u_mask = d_in[3];
    const float* w    = (const float*)d_in[4];
    const float* bias = (const float*)d_in[5];
    float* ws  = (float*)d_ws;
    float* out = (float*)d_out;

    if (ws_size < WS_FLOATS * sizeof(float)) return;  // diagnostic: leaves out zeroed

    k_detect<<<dim3(1), 64, 0, stream>>>((const unsigned char*)h_mask, ws);
    k_uwb<<<dim3(BB * LUU / 4), 256, 0, stream>>>(u, w, bias, ws);
    k_S<<<dim3(BB, LHH / 32), 256, 0, stream>>>(h, u, u_mask, w, ws);
    k_colpart<<<dim3(BB, 8), 256, 0, stream>>>(h_mask, ws);
    k_colcomb<<<dim3(BB), 128, 0, stream>>>(ws);
    k_C<<<dim3(BB, LUU / 16), 256, 0, stream>>>(h, u_mask, ws);
    k_out<<<dim3(BB, LHH / 16), 256, 0, stream>>>(h, u, h_mask, u_mask, ws, out);
}

// Round 5
// 351.845 us; speedup vs baseline: 2.7390x; 2.7390x over previous
//
#include <hip/hip_runtime.h>
#include <hip/hip_bf16.h>

#define BB  32
#define LHH 1024
#define LUU 128
#define HDD 256
#define NEGF (-1e30f)

// ---- workspace layout (float offsets) ----
static constexpr size_t S_OFF    = 0;                           // [B][LH][LU] raw S
static constexpr size_t UWB_OFF  = S_OFF + (size_t)BB*LHH*LUU;  // [B][LU]
static constexpr size_t RM_OFF   = UWB_OFF + (size_t)BB*LUU;    // [B][LH] row max
static constexpr size_t RI_OFF   = RM_OFF + (size_t)BB*LHH;     // [B][LH] 1/row sum
static constexpr size_t PM_OFF   = RI_OFF + (size_t)BB*LHH;     // [B][8][LU]
static constexpr size_t PS_OFF   = PM_OFF + (size_t)BB*8*LUU;   // [B][8][LU]
static constexpr size_t CM_OFF   = PS_OFF + (size_t)BB*8*LUU;   // [B][LU] col max
static constexpr size_t CI_OFF   = CM_OFF + (size_t)BB*LUU;     // [B][LU] 1/col sum
static constexpr size_t C_OFF    = CI_OFF + (size_t)BB*LUU;     // [B][LU][HD]
static constexpr size_t FLAG_OFF = C_OFF + (size_t)BB*LUU*HDD;  // 1 int (mask dtype flag)
static constexpr size_t WS_FLOATS= FLAG_OFF + 1;

// mask accessor: flag==1 -> bool8 bytes; flag==0 -> 4-byte elements (int32 or f32 bits)
__device__ __forceinline__ float mval(const void* p, int idx, int flag) {
    if (flag) return ((const unsigned char*)p)[idx] ? 1.0f : 0.0f;
    return (((const int*)p)[idx] != 0) ? 1.0f : 0.0f;
}
// clamped exp: identity for all mathematically-contributing args (<=0), never inf
__device__ __forceinline__ float cexpf(float x) { return __expf(fminf(x, 60.0f)); }
__device__ __forceinline__ float grcp(float x)  { return 1.0f / fmaxf(x, 1e-38f); }

// ---------------- detect mask dtype ----------------
__global__ void k_detect(const unsigned char* __restrict__ hm, float* __restrict__ ws) {
    if (threadIdx.x == 0)
        reinterpret_cast<int*>(ws)[FLAG_OFF] = (hm[1] != 0) ? 1 : 0;
}

// ---------------- K0: uwb[b,j] = u[b,j,:]·w_u + bias ----------------
__global__ __launch_bounds__(256) void k_uwb(const float* __restrict__ u,
                                             const float* __restrict__ w,
                                             const float* __restrict__ bias,
                                             float* __restrict__ ws) {
    int wave = threadIdx.x >> 6;
    int lane = threadIdx.x & 63;
    int idx  = blockIdx.x * 4 + wave;          // b*LU + j
    int b = idx >> 7, j = idx & 127;
    const float4* u4  = reinterpret_cast<const float4*>(u + ((size_t)(b * LUU + j)) * HDD);
    const float4* wu4 = reinterpret_cast<const float4*>(w + HDD);
    float4 a = u4[lane], c = wu4[lane];
    float s = a.x * c.x + a.y * c.y + a.z * c.z + a.w * c.w;
    #pragma unroll
    for (int off = 32; off; off >>= 1) s += __shfl_xor(s, off);
    if (lane == 0) ws[UWB_OFF + idx] = s + bias[0];
}

// ---------------- K1: S + row softmax stats ----------------
// v[j][k] = w_h[k] + w_hu[k]*u[b,j,k], staged per 32-k chunk in a SINGLE 16.5 KB LDS
// buffer, transposed layout v_lds[k][j] row stride 129 (conflict-free scalar reads).
// No launch-bounds min-waves hint (round-4 lesson: it forced VGPR=64 + scratch spill).
// Occupancy (VGPR-bound ~4 blocks/CU) provides the latency hiding; 2 barriers/chunk.
__global__ __launch_bounds__(256) void k_S(const float* __restrict__ h,
                                           const float* __restrict__ u,
                                           const void* __restrict__ u_mask,
                                           const float* __restrict__ w,
                                           float* __restrict__ ws) {
    __shared__ float vt[32 * 129];             // 16.5 KiB single buffer
    int b  = blockIdx.x;
    int it = blockIdx.y;                       // i-tile of 32 rows
    int t  = threadIdx.x;
    int flag = reinterpret_cast<const int*>(ws)[FLAG_OFF];

    // staging mapping: thread covers u-row jrow, k-halfchunk of 16
    int jrow = t >> 1, half = t & 1;
    const float* ubase = u + ((size_t)(b * LUU + jrow)) * HDD + half * 16;
    const float* whb   = w + half * 16;            // w_h
    const float* whub  = w + 2 * HDD + half * 16;  // w_hu

    int wave = t >> 6, lane = t & 63;
    int row0 = it * 32 + wave * 8;
    const float* hbase = h + ((size_t)(b * LHH + row0)) * HDD;
    float um0 = mval(u_mask, b * LUU + lane, flag);
    float um1 = mval(u_mask, b * LUU + lane + 64, flag);
    float uw0 = ws[UWB_OFF + b * LUU + lane];
    float uw1 = ws[UWB_OFF + b * LUU + lane + 64];

    float acc0[8], acc1[8];
    #pragma unroll
    for (int r = 0; r < 8; ++r) { acc0[r] = 0.f; acc1[r] = 0.f; }

    for (int c = 0; c < 8; ++c) {
        __syncthreads();                       // previous chunk's compute done
        // stage chunk c: v[kl][jrow] for kl in this thread's 16-k slice
        #pragma unroll
        for (int q = 0; q < 4; ++q) {
            float4 uu = *reinterpret_cast<const float4*>(ubase + c * 32 + q * 4);
            float4 a  = *reinterpret_cast<const float4*>(whb  + c * 32 + q * 4);
            float4 cc = *reinterpret_cast<const float4*>(whub + c * 32 + q * 4);
            int kl = half * 16 + q * 4;
            vt[(kl + 0) * 129 + jrow] = a.x + cc.x * uu.x;
            vt[(kl + 1) * 129 + jrow] = a.y + cc.y * uu.y;
            vt[(kl + 2) * 129 + jrow] = a.z + cc.z * uu.z;
            vt[(kl + 3) * 129 + jrow] = a.w + cc.w * uu.w;
        }
        __syncthreads();                       // chunk c resident
        int k0 = c * 32;
        #pragma unroll
        for (int k4 = 0; k4 < 8; ++k4) {
            int kk = k0 + k4 * 4;
            const float* vk = vt + (k4 * 4) * 129;
            float4 v0, v1;
            v0.x = vk[lane];           v1.x = vk[lane + 64];
            v0.y = vk[129 + lane];     v1.y = vk[129 + lane + 64];
            v0.z = vk[258 + lane];     v1.z = vk[258 + lane + 64];
            v0.w = vk[387 + lane];     v1.w = vk[387 + lane + 64];
            #pragma unroll
            for (int r = 0; r < 8; ++r) {
                float4 hv = *reinterpret_cast<const float4*>(hbase + (size_t)r * HDD + kk);
                acc0[r] += hv.x * v0.x + hv.y * v0.y + hv.z * v0.z + hv.w * v0.w;
                acc1[r] += hv.x * v1.x + hv.y * v1.y + hv.z * v1.z + hv.w * v1.w;
            }
        }
    }

    #pragma unroll
    for (int r = 0; r < 8; ++r) {
        int row = row0 + r;
        float S0 = acc0[r] + uw0;
        float S1 = acc1[r] + uw1;
        float* Srow = ws + S_OFF + ((size_t)(b * LHH + row)) * LUU;
        Srow[lane] = S0;
        Srow[lane + 64] = S1;
        float ms = fmaxf(um0 > 0.f ? S0 : NEGF, um1 > 0.f ? S1 : NEGF);
        #pragma unroll
        for (int off = 32; off; off >>= 1) ms = fmaxf(ms, __shfl_xor(ms, off));
        float e = um0 * cexpf(S0 - ms) + um1 * cexpf(S1 - ms);
        #pragma unroll
        for (int off = 32; off; off >>= 1) e += __shfl_xor(e, off);
        if (lane == 0) {
            ws[RM_OFF + b * LHH + row] = ms;
            ws[RI_OFF + b * LHH + row] = grcp(e);
        }
    }
}

// ---------------- K2: partial column stats ----------------
__global__ __launch_bounds__(256) void k_colpart(const void* __restrict__ h_mask,
                                                 float* __restrict__ ws) {
    int b = blockIdx.x, c = blockIdx.y;        // chunk of 128 i
    int t = threadIdx.x;
    int j = t & 127, ih = t >> 7;
    int flag = reinterpret_cast<const int*>(ws)[FLAG_OFF];
    float m = NEGF, s = 0.f;
    const float* Sb = ws + S_OFF + ((size_t)b * LHH) * LUU;
    int i0 = c * 128;
    for (int ii = ih; ii < 128; ii += 2) {
        int i = i0 + ii;
        if (mval(h_mask, b * LHH + i, flag) > 0.f) {
            float x  = Sb[(size_t)i * LUU + j];
            float mn = fmaxf(m, x);
            s = s * __expf(m - mn) + __expf(x - mn);
            m = mn;
        }
    }
    __shared__ float sm_m[128], sm_s[128];
    if (ih == 0) { sm_m[j] = m; sm_s[j] = s; }
    __syncthreads();
    if (ih == 1) {
        float m0 = sm_m[j], s0 = sm_s[j];
        float mn = fmaxf(m0, m);
        float sc = s0 * __expf(fminf(m0 - mn, 0.f)) + s * __expf(fminf(m - mn, 0.f));
        ws[PM_OFF + (b * 8 + c) * LUU + j] = mn;
        ws[PS_OFF + (b * 8 + c) * LUU + j] = sc;
    }
}

// ---------------- K2b: combine partial column stats ----------------
__global__ __launch_bounds__(128) void k_colcomb(float* __restrict__ ws) {
    int b = blockIdx.x, j = threadIdx.x;
    float m = NEGF;
    #pragma unroll
    for (int c = 0; c < 8; ++c) m = fmaxf(m, ws[PM_OFF + (b * 8 + c) * LUU + j]);
    float s = 0.f;
    #pragma unroll
    for (int c = 0; c < 8; ++c)
        s += ws[PS_OFF + (b * 8 + c) * LUU + j] * cexpf(ws[PM_OFF + (b * 8 + c) * LUU + j] - m);
    ws[CM_OFF + b * LUU + j] = m;
    ws[CI_OFF + b * LUU + j] = grcp(s);
}

// ---------------- K3: C[b,q,:] = sum_i a_t[i,q] * h[b,i,:] ----------------
__global__ __launch_bounds__(256) void k_C(const float* __restrict__ h,
                                           const void* __restrict__ u_mask,
                                           float* __restrict__ ws) {
    int b = blockIdx.x, ut = blockIdx.y;       // u-tile of 16
    int u0 = ut * 16;
    int t = threadIdx.x;
    int flag = reinterpret_cast<const int*>(ws)[FLAG_OFF];
    __shared__ float a_l[64][16];
    float acc[16];
    #pragma unroll
    for (int q = 0; q < 16; ++q) acc[q] = 0.f;

    const float* Sb = ws + S_OFF + (size_t)b * LHH * LUU;
    const float* rm = ws + RM_OFF + b * LHH;
    const float* ri = ws + RI_OFF + b * LHH;
    const float* hb = h + (size_t)b * LHH * HDD;

    int iq = t >> 2, uq = t & 3;
    float um_[4];
    #pragma unroll
    for (int c = 0; c < 4; ++c)
        um_[c] = mval(u_mask, b * LUU + u0 + uq * 4 + c, flag);

    for (int i0 = 0; i0 < LHH; i0 += 64) {
        __syncthreads();
        {
            int i = i0 + iq;
            float4 s4 = *reinterpret_cast<const float4*>(Sb + (size_t)i * LUU + u0 + uq * 4);
            float mm = rm[i], rr = ri[i];
            a_l[iq][uq * 4 + 0] = um_[0] * cexpf(s4.x - mm) * rr;
            a_l[iq][uq * 4 + 1] = um_[1] * cexpf(s4.y - mm) * rr;
            a_l[iq][uq * 4 + 2] = um_[2] * cexpf(s4.z - mm) * rr;
            a_l[iq][uq * 4 + 3] = um_[3] * cexpf(s4.w - mm) * rr;
        }
        __syncthreads();
        #pragma unroll 4
        for (int ii = 0; ii < 64; ++ii) {
            float hval = hb[(size_t)(i0 + ii) * HDD + t];
            #pragma unroll
            for (int q = 0; q < 4; ++q) {
                float4 a4 = *reinterpret_cast<const float4*>(&a_l[ii][q * 4]);
                acc[q * 4 + 0] += a4.x * hval;
                acc[q * 4 + 1] += a4.y * hval;
                acc[q * 4 + 2] += a4.z * hval;
                acc[q * 4 + 3] += a4.w * hval;
            }
        }
    }
    #pragma unroll
    for (int q = 0; q < 16; ++q)
        ws[C_OFF + ((size_t)(b * LUU + u0 + q)) * HDD + t] = acc[q];
}

// ---------------- K4: U_tilde, H_tilde, output concat ----------------
__global__ __launch_bounds__(256) void k_out(const float* __restrict__ h,
                                             const float* __restrict__ u,
                                             const void* __restrict__ h_mask,
                                             const void* __restrict__ u_mask,
                                             const float* __restrict__ ws,
                                             float* __restrict__ out) {
    int b = blockIdx.x, itile = blockIdx.y;    // tiles of 16 rows
    int i0 = itile * 16;
    int t = threadIdx.x;
    int flag = reinterpret_cast<const int*>(ws)[FLAG_OFF];
    __shared__ float aT[128][16], bT[128][16];
    __shared__ float cm_l[128], ci_l[128], um_l[128];
    __shared__ float rm_l[16], ri_l[16], hm_l[16];

    if (t < 128) {
        cm_l[t] = ws[CM_OFF + b * LUU + t];
        ci_l[t] = ws[CI_OFF + b * LUU + t];
        um_l[t] = mval(u_mask, b * LUU + t, flag);
    } else if (t < 144) {
        int r = t - 128;
        rm_l[r] = ws[RM_OFF + b * LHH + i0 + r];
        ri_l[r] = ws[RI_OFF + b * LHH + i0 + r];
        hm_l[r] = mval(h_mask, b * LHH + i0 + r, flag);
    }
    __syncthreads();

    {
        int j4 = t & 31, rp = t >> 5;          // rp in [0,8)
        #pragma unroll
        for (int half = 0; half < 2; ++half) {
            int r = rp + half * 8;
            int i = i0 + r;
            float4 s4 = *reinterpret_cast<const float4*>(
                ws + S_OFF + ((size_t)(b * LHH + i)) * LUU + j4 * 4);
            float mm = rm_l[r], rr = ri_l[r], hm = hm_l[r];
            float xs[4] = {s4.x, s4.y, s4.z, s4.w};
            #pragma unroll
            for (int c = 0; c < 4; ++c) {
                int j = j4 * 4 + c;
                aT[j][r] = um_l[j] * cexpf(xs[c] - mm) * rr;
                bT[j][r] = hm * cexpf(xs[c] - cm_l[j]) * ci_l[j];
            }
        }
    }
    __syncthreads();

    float accU[16], accH[16];
    #pragma unroll
    for (int r = 0; r < 16; ++r) { accU[r] = 0.f; accH[r] = 0.f; }

    const float* ub = u + (size_t)b * LUU * HDD;
    const float* Cb = ws + C_OFF + (size_t)b * LUU * HDD;

    #pragma unroll 2
    for (int j = 0; j < LUU; ++j) {
        float uval = ub[(size_t)j * HDD + t];
        float cval = Cb[(size_t)j * HDD + t];
        #pragma unroll
        for (int q = 0; q < 4; ++q) {
            float4 a4 = *reinterpret_cast<const float4*>(&aT[j][q * 4]);
            float4 b4 = *reinterpret_cast<const float4*>(&bT[j][q * 4]);
            accU[q * 4 + 0] += a4.x * uval;
            accU[q * 4 + 1] += a4.y * uval;
            accU[q * 4 + 2] += a4.z * uval;
            accU[q * 4 + 3] += a4.w * uval;
            accH[q * 4 + 0] += b4.x * cval;
            accH[q * 4 + 1] += b4.y * cval;
            accH[q * 4 + 2] += b4.z * cval;
            accH[q * 4 + 3] += b4.w * cval;
        }
    }

    #pragma unroll
    for (int r = 0; r < 16; ++r) {
        int i = i0 + r;
        float hval = h[((size_t)(b * LHH + i)) * HDD + t];
        size_t base = ((size_t)(b * LHH + i)) * (4 * HDD) + t;
        out[base]           = hval;
        out[base + HDD]     = accU[r];
        out[base + 2 * HDD] = hval * accU[r];
        out[base + 3 * HDD] = hval * accH[r];
    }
}

extern "C" void kernel_launch(void* const* d_in, const int* in_sizes, int n_in,
                              void* d_out, int out_size, void* d_ws, size_t ws_size,
                              hipStream_t stream) {
    const float* h = (const float*)d_in[0];
    const float* u = (const float*)d_in[1];
    const void*  h_mask = d_in[2];
    const void*  u_mask = d_in[3];
    const float* w    = (const float*)d_in[4];
    const float* bias = (const float*)d_in[5];
    float* ws  = (float*)d_ws;
    float* out = (float*)d_out;

    if (ws_size < WS_FLOATS * sizeof(float)) return;  // diagnostic: leaves out zeroed

    k_detect<<<dim3(1), 64, 0, stream>>>((const unsigned char*)h_mask, ws);
    k_uwb<<<dim3(BB * LUU / 4), 256, 0, stream>>>(u, w, bias, ws);
    k_S<<<dim3(BB, LHH / 32), 256, 0, stream>>>(h, u, u_mask, w, ws);
    k_colpart<<<dim3(BB, 8), 256, 0, stream>>>(h_mask, ws);
    k_colcomb<<<dim3(BB), 128, 0, stream>>>(ws);
    k_C<<<dim3(BB, LUU / 16), 256, 0, stream>>>(h, u_mask, ws);
    k_out<<<dim3(BB, LHH / 16), 256, 0, stream>>>(h, u, h_mask, u_mask, ws, out);
}

// Round 6
// 254.706 us; speedup vs baseline: 3.7836x; 1.3814x over previous
//
#include <hip/hip_runtime.h>
#include <hip/hip_bf16.h>

#define BB  32
#define LHH 1024
#define LUU 128
#define HDD 256
#define NEGF (-1e30f)

typedef __attribute__((ext_vector_type(8))) short short8;
typedef __attribute__((ext_vector_type(4))) float f32x4;

// ---- workspace layout (float offsets) ----
static constexpr size_t S_OFF    = 0;                           // [B][LH][LU] full S
static constexpr size_t UWB_OFF  = S_OFF + (size_t)BB*LHH*LUU;  // [B][LU]
static constexpr size_t RM_OFF   = UWB_OFF + (size_t)BB*LUU;    // [B][LH] row max
static constexpr size_t RI_OFF   = RM_OFF + (size_t)BB*LHH;     // [B][LH] 1/row sum
static constexpr size_t PM_OFF   = RI_OFF + (size_t)BB*LHH;     // [B][8][LU]
static constexpr size_t PS_OFF   = PM_OFF + (size_t)BB*8*LUU;   // [B][8][LU]
static constexpr size_t CM_OFF   = PS_OFF + (size_t)BB*8*LUU;   // [B][LU] col max
static constexpr size_t CI_OFF   = CM_OFF + (size_t)BB*LUU;     // [B][LU] 1/col sum
static constexpr size_t C_OFF    = CI_OFF + (size_t)BB*LUU;     // [B][LU][HD]
static constexpr size_t FLAG_OFF = C_OFF + (size_t)BB*LUU*HDD;  // 1 int (mask dtype flag)
static constexpr size_t WS_FLOATS= FLAG_OFF + 1;

__device__ __forceinline__ float mval(const void* p, int idx, int flag) {
    if (flag) return ((const unsigned char*)p)[idx] ? 1.0f : 0.0f;
    return (((const int*)p)[idx] != 0) ? 1.0f : 0.0f;
}
__device__ __forceinline__ float cexpf(float x) { return __expf(fminf(x, 60.0f)); }
__device__ __forceinline__ float grcp(float x)  { return 1.0f / fmaxf(x, 1e-38f); }

// ---------------- detect mask dtype ----------------
__global__ void k_detect(const unsigned char* __restrict__ hm, float* __restrict__ ws) {
    if (threadIdx.x == 0)
        reinterpret_cast<int*>(ws)[FLAG_OFF] = (hm[1] != 0) ? 1 : 0;
}

// ---------------- K0: uwb[b,j] = u[b,j,:]·w_u + bias ----------------
__global__ __launch_bounds__(256) void k_uwb(const float* __restrict__ u,
                                             const float* __restrict__ w,
                                             const float* __restrict__ bias,
                                             float* __restrict__ ws) {
    int wave = threadIdx.x >> 6;
    int lane = threadIdx.x & 63;
    int idx  = blockIdx.x * 4 + wave;          // b*LU + j
    int b = idx >> 7, j = idx & 127;
    const float4* u4  = reinterpret_cast<const float4*>(u + ((size_t)(b * LUU + j)) * HDD);
    const float4* wu4 = reinterpret_cast<const float4*>(w + HDD);
    float4 a = u4[lane], c = wu4[lane];
    float s = a.x * c.x + a.y * c.y + a.z * c.z + a.w * c.w;
    #pragma unroll
    for (int off = 32; off; off >>= 1) s += __shfl_xor(s, off);
    if (lane == 0) ws[UWB_OFF + idx] = s + bias[0];
}

// ---------------- K1 (MFMA): S = h·v^T + uwb, row softmax stats ----------------
// bf16 MFMA 16x16x32, f32 acc. BM=64, BN=128(all j), BK=32, 4 waves x (16i x 128j).
// v[j][k] = w_h[k] + w_hu[k]*u[b,j,k] computed during staging (f32->bf16).
// LDS tiles swizzled in 16B chunks: slot(row,c) holds logical chunk c ^ sw(row),
// sw(r) = (r ^ (r>>2)) & 3  -> conflict-free ds_read_b128 fragment reads.
__device__ __forceinline__ int swz(int r) { return (r ^ (r >> 2)) & 3; }

__global__ __launch_bounds__(256) void k_Smfma(const float* __restrict__ h,
                                               const float* __restrict__ u,
                                               const void* __restrict__ u_mask,
                                               const float* __restrict__ w,
                                               float* __restrict__ ws) {
    __shared__ __align__(16) short lh[64 * 32];    // 4 KB  [row][4 chunks of 8 bf16]
    __shared__ __align__(16) short lv[128 * 32];   // 8 KB
    __shared__ float uwb_l[128], um_l[128];

    int b  = blockIdx.x;
    int i0 = blockIdx.y * 64;
    int t  = threadIdx.x;
    int flag = reinterpret_cast<const int*>(ws)[FLAG_OFF];
    int wave = t >> 6, lane = t & 63;
    int lj = lane & 15, lq = lane >> 4;

    if (t < 128) {
        uwb_l[t] = ws[UWB_OFF + b * LUU + t];
        um_l[t]  = mval(u_mask, b * LUU + t, flag);
    }

    // staging assignments (constant across steps)
    int hrow = t >> 2,  hc = t & 3,  hlc = hc ^ swz(hrow);     // 64x4 chunks, 1/thread
    int vrow0 = t >> 2, vc0 = t & 3, vlc0 = vc0 ^ swz(vrow0);  // chunks t and t+256
    int vrow1 = (t + 256) >> 2, vc1 = t & 3, vlc1 = vc1 ^ swz(vrow1);
    const float* hsrc = h + ((size_t)(b * LHH + i0 + hrow)) * HDD + hlc * 8;
    const float* us0  = u + ((size_t)(b * LUU + vrow0)) * HDD + vlc0 * 8;
    const float* us1  = u + ((size_t)(b * LUU + vrow1)) * HDD + vlc1 * 8;

    // fragment read addresses (constant across steps)
    int arow = wave * 16 + lj;
    int a_idx = arow * 32 + ((lq ^ swz(arow)) * 8);
    int b_idx[8];
    #pragma unroll
    for (int n = 0; n < 8; ++n) {
        int j = n * 16 + lj;
        b_idx[n] = j * 32 + ((lq ^ swz(j)) * 8);
    }

    f32x4 acc[8];
    #pragma unroll
    for (int n = 0; n < 8; ++n) acc[n] = (f32x4){0.f, 0.f, 0.f, 0.f};

    for (int step = 0; step < 8; ++step) {
        int k0 = step * 32;
        if (step) __syncthreads();             // prev compute done before overwrite
        // stage h chunk
        {
            float4 f0 = *reinterpret_cast<const float4*>(hsrc + k0);
            float4 f1 = *reinterpret_cast<const float4*>(hsrc + k0 + 4);
            union { short8 s8; __hip_bfloat16 bh[8]; } pk;
            pk.bh[0]=__float2bfloat16(f0.x); pk.bh[1]=__float2bfloat16(f0.y);
            pk.bh[2]=__float2bfloat16(f0.z); pk.bh[3]=__float2bfloat16(f0.w);
            pk.bh[4]=__float2bfloat16(f1.x); pk.bh[5]=__float2bfloat16(f1.y);
            pk.bh[6]=__float2bfloat16(f1.z); pk.bh[7]=__float2bfloat16(f1.w);
            *reinterpret_cast<short8*>(&lh[hrow * 32 + hc * 8]) = pk.s8;
        }
        // stage v chunks (2 per thread)
        #pragma unroll
        for (int p = 0; p < 2; ++p) {
            const float* usrc = p ? us1 : us0;
            int vlc = p ? vlc1 : vlc0;
            int vrow = p ? vrow1 : vrow0;
            int vc = p ? vc1 : vc0;
            float4 uu0 = *reinterpret_cast<const float4*>(usrc + k0);
            float4 uu1 = *reinterpret_cast<const float4*>(usrc + k0 + 4);
            float4 wh0 = *reinterpret_cast<const float4*>(w + k0 + vlc * 8);
            float4 wh1 = *reinterpret_cast<const float4*>(w + k0 + vlc * 8 + 4);
            float4 wu0 = *reinterpret_cast<const float4*>(w + 2 * HDD + k0 + vlc * 8);
            float4 wu1 = *reinterpret_cast<const float4*>(w + 2 * HDD + k0 + vlc * 8 + 4);
            union { short8 s8; __hip_bfloat16 bh[8]; } pk;
            pk.bh[0]=__float2bfloat16(wh0.x + wu0.x * uu0.x);
            pk.bh[1]=__float2bfloat16(wh0.y + wu0.y * uu0.y);
            pk.bh[2]=__float2bfloat16(wh0.z + wu0.z * uu0.z);
            pk.bh[3]=__float2bfloat16(wh0.w + wu0.w * uu0.w);
            pk.bh[4]=__float2bfloat16(wh1.x + wu1.x * uu1.x);
            pk.bh[5]=__float2bfloat16(wh1.y + wu1.y * uu1.y);
            pk.bh[6]=__float2bfloat16(wh1.z + wu1.z * uu1.z);
            pk.bh[7]=__float2bfloat16(wh1.w + wu1.w * uu1.w);
            *reinterpret_cast<short8*>(&lv[vrow * 32 + vc * 8]) = pk.s8;
        }
        __syncthreads();                       // tiles resident
        short8 af = *reinterpret_cast<const short8*>(&lh[a_idx]);
        #pragma unroll
        for (int n = 0; n < 8; ++n) {
            short8 bf = *reinterpret_cast<const short8*>(&lv[b_idx[n]]);
            acc[n] = __builtin_amdgcn_mfma_f32_16x16x32_bf16(af, bf, acc[n], 0, 0, 0);
        }
    }

    // ---- epilogue: add uwb, row stats over 128 j, write S f32 ----
    float sv[8][4];
    #pragma unroll
    for (int n = 0; n < 8; ++n) {
        float uw = uwb_l[n * 16 + lj];
        #pragma unroll
        for (int q = 0; q < 4; ++q) sv[n][q] = acc[n][q] + uw;
    }
    float umv[8];
    #pragma unroll
    for (int n = 0; n < 8; ++n) umv[n] = um_l[n * 16 + lj];

    #pragma unroll
    for (int q = 0; q < 4; ++q) {
        float ms = NEGF;
        #pragma unroll
        for (int n = 0; n < 8; ++n) ms = fmaxf(ms, umv[n] > 0.f ? sv[n][q] : NEGF);
        #pragma unroll
        for (int off = 8; off; off >>= 1) ms = fmaxf(ms, __shfl_xor(ms, off));
        float e = 0.f;
        #pragma unroll
        for (int n = 0; n < 8; ++n) e += umv[n] * cexpf(sv[n][q] - ms);
        #pragma unroll
        for (int off = 8; off; off >>= 1) e += __shfl_xor(e, off);
        int i = i0 + wave * 16 + lq * 4 + q;
        float* Srow = ws + S_OFF + ((size_t)(b * LHH + i)) * LUU;
        #pragma unroll
        for (int n = 0; n < 8; ++n) Srow[n * 16 + lj] = sv[n][q];
        if (lj == 0) {
            ws[RM_OFF + b * LHH + i] = ms;
            ws[RI_OFF + b * LHH + i] = grcp(e);
        }
    }
}

// ---------------- K2: partial column stats ----------------
__global__ __launch_bounds__(256) void k_colpart(const void* __restrict__ h_mask,
                                                 float* __restrict__ ws) {
    int b = blockIdx.x, c = blockIdx.y;        // chunk of 128 i
    int t = threadIdx.x;
    int j = t & 127, ih = t >> 7;
    int flag = reinterpret_cast<const int*>(ws)[FLAG_OFF];
    float m = NEGF, s = 0.f;
    const float* Sb = ws + S_OFF + ((size_t)b * LHH) * LUU;
    int i0 = c * 128;
    for (int ii = ih; ii < 128; ii += 2) {
        int i = i0 + ii;
        if (mval(h_mask, b * LHH + i, flag) > 0.f) {
            float x  = Sb[(size_t)i * LUU + j];
            float mn = fmaxf(m, x);
            s = s * __expf(m - mn) + __expf(x - mn);
            m = mn;
        }
    }
    __shared__ float sm_m[128], sm_s[128];
    if (ih == 0) { sm_m[j] = m; sm_s[j] = s; }
    __syncthreads();
    if (ih == 1) {
        float m0 = sm_m[j], s0 = sm_s[j];
        float mn = fmaxf(m0, m);
        float sc = s0 * __expf(fminf(m0 - mn, 0.f)) + s * __expf(fminf(m - mn, 0.f));
        ws[PM_OFF + (b * 8 + c) * LUU + j] = mn;
        ws[PS_OFF + (b * 8 + c) * LUU + j] = sc;
    }
}

// ---------------- K2b: combine partial column stats ----------------
__global__ __launch_bounds__(128) void k_colcomb(float* __restrict__ ws) {
    int b = blockIdx.x, j = threadIdx.x;
    float m = NEGF;
    #pragma unroll
    for (int c = 0; c < 8; ++c) m = fmaxf(m, ws[PM_OFF + (b * 8 + c) * LUU + j]);
    float s = 0.f;
    #pragma unroll
    for (int c = 0; c < 8; ++c)
        s += ws[PS_OFF + (b * 8 + c) * LUU + j] * cexpf(ws[PM_OFF + (b * 8 + c) * LUU + j] - m);
    ws[CM_OFF + b * LUU + j] = m;
    ws[CI_OFF + b * LUU + j] = grcp(s);
}

// ---------------- K3: C[b,q,:] = sum_i a_t[i,q] * h[b,i,:] ----------------
__global__ __launch_bounds__(256) void k_C(const float* __restrict__ h,
                                           const void* __restrict__ u_mask,
                                           float* __restrict__ ws) {
    int b = blockIdx.x, ut = blockIdx.y;       // u-tile of 16
    int u0 = ut * 16;
    int t = threadIdx.x;
    int flag = reinterpret_cast<const int*>(ws)[FLAG_OFF];
    __shared__ float a_l[64][16];
    float acc[16];
    #pragma unroll
    for (int q = 0; q < 16; ++q) acc[q] = 0.f;

    const float* Sb = ws + S_OFF + (size_t)b * LHH * LUU;
    const float* rm = ws + RM_OFF + b * LHH;
    const float* ri = ws + RI_OFF + b * LHH;
    const float* hb = h + (size_t)b * LHH * HDD;

    int iq = t >> 2, uq = t & 3;
    float um_[4];
    #pragma unroll
    for (int c = 0; c < 4; ++c)
        um_[c] = mval(u_mask, b * LUU + u0 + uq * 4 + c, flag);

    for (int i0 = 0; i0 < LHH; i0 += 64) {
        __syncthreads();
        {
            int i = i0 + iq;
            float4 s4 = *reinterpret_cast<const float4*>(Sb + (size_t)i * LUU + u0 + uq * 4);
            float mm = rm[i], rr = ri[i];
            a_l[iq][uq * 4 + 0] = um_[0] * cexpf(s4.x - mm) * rr;
            a_l[iq][uq * 4 + 1] = um_[1] * cexpf(s4.y - mm) * rr;
            a_l[iq][uq * 4 + 2] = um_[2] * cexpf(s4.z - mm) * rr;
            a_l[iq][uq * 4 + 3] = um_[3] * cexpf(s4.w - mm) * rr;
        }
        __syncthreads();
        #pragma unroll 4
        for (int ii = 0; ii < 64; ++ii) {
            float hval = hb[(size_t)(i0 + ii) * HDD + t];
            #pragma unroll
            for (int q = 0; q < 4; ++q) {
                float4 a4 = *reinterpret_cast<const float4*>(&a_l[ii][q * 4]);
                acc[q * 4 + 0] += a4.x * hval;
                acc[q * 4 + 1] += a4.y * hval;
                acc[q * 4 + 2] += a4.z * hval;
                acc[q * 4 + 3] += a4.w * hval;
            }
        }
    }
    #pragma unroll
    for (int q = 0; q < 16; ++q)
        ws[C_OFF + ((size_t)(b * LUU + u0 + q)) * HDD + t] = acc[q];
}

// ---------------- K4: U_tilde, H_tilde, output concat ----------------
__global__ __launch_bounds__(256) void k_out(const float* __restrict__ h,
                                             const float* __restrict__ u,
                                             const void* __restrict__ h_mask,
                                             const void* __restrict__ u_mask,
                                             const float* __restrict__ ws,
                                             float* __restrict__ out) {
    int b = blockIdx.x, itile = blockIdx.y;    // tiles of 16 rows
    int i0 = itile * 16;
    int t = threadIdx.x;
    int flag = reinterpret_cast<const int*>(ws)[FLAG_OFF];
    __shared__ float aT[128][16], bT[128][16];
    __shared__ float cm_l[128], ci_l[128], um_l[128];
    __shared__ float rm_l[16], ri_l[16], hm_l[16];

    if (t < 128) {
        cm_l[t] = ws[CM_OFF + b * LUU + t];
        ci_l[t] = ws[CI_OFF + b * LUU + t];
        um_l[t] = mval(u_mask, b * LUU + t, flag);
    } else if (t < 144) {
        int r = t - 128;
        rm_l[r] = ws[RM_OFF + b * LHH + i0 + r];
        ri_l[r] = ws[RI_OFF + b * LHH + i0 + r];
        hm_l[r] = mval(h_mask, b * LHH + i0 + r, flag);
    }
    __syncthreads();

    {
        int j4 = t & 31, rp = t >> 5;          // rp in [0,8)
        #pragma unroll
        for (int half = 0; half < 2; ++half) {
            int r = rp + half * 8;
            int i = i0 + r;
            float4 s4 = *reinterpret_cast<const float4*>(
                ws + S_OFF + ((size_t)(b * LHH + i)) * LUU + j4 * 4);
            float mm = rm_l[r], rr = ri_l[r], hm = hm_l[r];
            float xs[4] = {s4.x, s4.y, s4.z, s4.w};
            #pragma unroll
            for (int c = 0; c < 4; ++c) {
                int j = j4 * 4 + c;
                aT[j][r] = um_l[j] * cexpf(xs[c] - mm) * rr;
                bT[j][r] = hm * cexpf(xs[c] - cm_l[j]) * ci_l[j];
            }
        }
    }
    __syncthreads();

    float accU[16], accH[16];
    #pragma unroll
    for (int r = 0; r < 16; ++r) { accU[r] = 0.f; accH[r] = 0.f; }

    const float* ub = u + (size_t)b * LUU * HDD;
    const float* Cb = ws + C_OFF + (size_t)b * LUU * HDD;

    #pragma unroll 2
    for (int j = 0; j < LUU; ++j) {
        float uval = ub[(size_t)j * HDD + t];
        float cval = Cb[(size_t)j * HDD + t];
        #pragma unroll
        for (int q = 0; q < 4; ++q) {
            float4 a4 = *reinterpret_cast<const float4*>(&aT[j][q * 4]);
            float4 b4 = *reinterpret_cast<const float4*>(&bT[j][q * 4]);
            accU[q * 4 + 0] += a4.x * uval;
            accU[q * 4 + 1] += a4.y * uval;
            accU[q * 4 + 2] += a4.z * uval;
            accU[q * 4 + 3] += a4.w * uval;
            accH[q * 4 + 0] += b4.x * cval;
            accH[q * 4 + 1] += b4.y * cval;
            accH[q * 4 + 2] += b4.z * cval;
            accH[q * 4 + 3] += b4.w * cval;
        }
    }

    #pragma unroll
    for (int r = 0; r < 16; ++r) {
        int i = i0 + r;
        float hval = h[((size_t)(b * LHH + i)) * HDD + t];
        size_t base = ((size_t)(b * LHH + i)) * (4 * HDD) + t;
        out[base]           = hval;
        out[base + HDD]     = accU[r];
        out[base + 2 * HDD] = hval * accU[r];
        out[base + 3 * HDD] = hval * accH[r];
    }
}

extern "C" void kernel_launch(void* const* d_in, const int* in_sizes, int n_in,
                              void* d_out, int out_size, void* d_ws, size_t ws_size,
                              hipStream_t stream) {
    const float* h = (const float*)d_in[0];
    const float* u = (const float*)d_in[1];
    const void*  h_mask = d_in[2];
    const void*  u_mask = d_in[3];
    const float* w    = (const float*)d_in[4];
    const float* bias = (const float*)d_in[5];
    float* ws  = (float*)d_ws;
    float* out = (float*)d_out;

    if (ws_size < WS_FLOATS * sizeof(float)) return;  // diagnostic: leaves out zeroed

    k_detect<<<dim3(1), 64, 0, stream>>>((const unsigned char*)h_mask, ws);
    k_uwb<<<dim3(BB * LUU / 4), 256, 0, stream>>>(u, w, bias, ws);
    k_Smfma<<<dim3(BB, LHH / 64), 256, 0, stream>>>(h, u, u_mask, w, ws);
    k_colpart<<<dim3(BB, 8), 256, 0, stream>>>(h_mask, ws);
    k_colcomb<<<dim3(BB), 128, 0, stream>>>(ws);
    k_C<<<dim3(BB, LUU / 16), 256, 0, stream>>>(h, u_mask, ws);
    k_out<<<dim3(BB, LHH / 16), 256, 0, stream>>>(h, u, h_mask, u_mask, ws, out);
}

// Round 7
// 150.363 us; speedup vs baseline: 6.4092x; 1.6939x over previous
//
#include <hip/hip_runtime.h>
#include <hip/hip_bf16.h>

#define BB  32
#define LHH 1024
#define LUU 128
#define HDD 256
#define NEGF (-1e30f)

typedef __attribute__((ext_vector_type(8))) short short8;
typedef __attribute__((ext_vector_type(4))) float f32x4;

// ---- workspace layout (float offsets) ----
static constexpr size_t S_OFF    = 0;                           // [B][LH][LU] full S f32
static constexpr size_t UWB_OFF  = S_OFF + (size_t)BB*LHH*LUU;  // [B][LU]
static constexpr size_t RM_OFF   = UWB_OFF + (size_t)BB*LUU;    // [B][LH] row max
static constexpr size_t RI_OFF   = RM_OFF + (size_t)BB*LHH;     // [B][LH] 1/row sum
static constexpr size_t PM_OFF   = RI_OFF + (size_t)BB*LHH;     // [B][8][LU]
static constexpr size_t PS_OFF   = PM_OFF + (size_t)BB*8*LUU;   // [B][8][LU]
static constexpr size_t CM_OFF   = PS_OFF + (size_t)BB*8*LUU;   // [B][LU] col max
static constexpr size_t CI_OFF   = CM_OFF + (size_t)BB*LUU;     // [B][LU] 1/col sum
static constexpr size_t CP_OFF   = CI_OFF + (size_t)BB*LUU;     // [B][4][LU][HD] C partials f32
static constexpr size_t UBT_OFF  = CP_OFF + (size_t)BB*4*LUU*HDD;  // [B][HD][LU] bf16 u^T
static constexpr size_t CBT_OFF  = UBT_OFF + (size_t)BB*HDD*LUU/2; // [B][HD][LU] bf16 C^T
static constexpr size_t FLAG_OFF = CBT_OFF + (size_t)BB*HDD*LUU/2; // 1 int
static constexpr size_t WS_FLOATS= FLAG_OFF + 1;

__device__ __forceinline__ float mval(const void* p, int idx, int flag) {
    if (flag) return ((const unsigned char*)p)[idx] ? 1.0f : 0.0f;
    return (((const int*)p)[idx] != 0) ? 1.0f : 0.0f;
}
__device__ __forceinline__ float cexpf(float x) { return __expf(fminf(x, 60.0f)); }
__device__ __forceinline__ float grcp(float x)  { return 1.0f / fmaxf(x, 1e-38f); }
__device__ __forceinline__ int swz(int r) { return (r ^ (r >> 2)) & 3; }

// ---------------- detect mask dtype ----------------
__global__ void k_detect(const unsigned char* __restrict__ hm, float* __restrict__ ws) {
    if (threadIdx.x == 0)
        reinterpret_cast<int*>(ws)[FLAG_OFF] = (hm[1] != 0) ? 1 : 0;
}

// ---------------- K0: uwb[b,j] = u[b,j,:]·w_u + bias ----------------
__global__ __launch_bounds__(256) void k_uwb(const float* __restrict__ u,
                                             const float* __restrict__ w,
                                             const float* __restrict__ bias,
                                             float* __restrict__ ws) {
    int wave = threadIdx.x >> 6;
    int lane = threadIdx.x & 63;
    int idx  = blockIdx.x * 4 + wave;          // b*LU + j
    int b = idx >> 7, j = idx & 127;
    const float4* u4  = reinterpret_cast<const float4*>(u + ((size_t)(b * LUU + j)) * HDD);
    const float4* wu4 = reinterpret_cast<const float4*>(w + HDD);
    float4 a = u4[lane], c = wu4[lane];
    float s = a.x * c.x + a.y * c.y + a.z * c.z + a.w * c.w;
    #pragma unroll
    for (int off = 32; off; off >>= 1) s += __shfl_xor(s, off);
    if (lane == 0) ws[UWB_OFF + idx] = s + bias[0];
}

// ---------------- K0b: u_bfT[b][hd][j] = bf16(u[b][j][hd]) ----------------
__global__ __launch_bounds__(256) void k_uT(const float* __restrict__ u,
                                            float* __restrict__ ws) {
    __shared__ float ls[32][132];
    int b = blockIdx.x, hd0 = blockIdx.y * 32;
    int t = threadIdx.x;
    int hc = t & 7, jj = t >> 3;
    #pragma unroll
    for (int pass = 0; pass < 4; ++pass) {
        int j = jj + pass * 32;
        float4 v = *reinterpret_cast<const float4*>(u + ((size_t)(b * LUU + j)) * HDD + hd0 + hc * 4);
        ls[hc * 4 + 0][j] = v.x; ls[hc * 4 + 1][j] = v.y;
        ls[hc * 4 + 2][j] = v.z; ls[hc * 4 + 3][j] = v.w;
    }
    __syncthreads();
    int r = t >> 3, ck = t & 7;                // row hd0+r, j chunk of 16
    short* ubt = reinterpret_cast<short*>(ws + UBT_OFF);
    union { short8 s8; __hip_bfloat16 bh[8]; } pk;
    #pragma unroll
    for (int hhalf = 0; hhalf < 2; ++hhalf) {
        #pragma unroll
        for (int c = 0; c < 8; ++c)
            pk.bh[c] = __float2bfloat16(ls[r][ck * 16 + hhalf * 8 + c]);
        *reinterpret_cast<short8*>(&ubt[((size_t)(b * 256 + hd0 + r)) * 128 + ck * 16 + hhalf * 8]) = pk.s8;
    }
}

// ---------------- K1 (MFMA): S = h·v^T + uwb, row softmax stats ----------------
__global__ __launch_bounds__(256) void k_Smfma(const float* __restrict__ h,
                                               const float* __restrict__ u,
                                               const void* __restrict__ u_mask,
                                               const float* __restrict__ w,
                                               float* __restrict__ ws) {
    __shared__ __align__(16) short lh[64 * 32];
    __shared__ __align__(16) short lv[128 * 32];
    __shared__ float uwb_l[128], um_l[128];

    int b  = blockIdx.x;
    int i0 = blockIdx.y * 64;
    int t  = threadIdx.x;
    int flag = reinterpret_cast<const int*>(ws)[FLAG_OFF];
    int wave = t >> 6, lane = t & 63;
    int lj = lane & 15, lq = lane >> 4;

    if (t < 128) {
        uwb_l[t] = ws[UWB_OFF + b * LUU + t];
        um_l[t]  = mval(u_mask, b * LUU + t, flag);
    }

    int hrow = t >> 2,  hc = t & 3,  hlc = hc ^ swz(hrow);
    int vrow0 = t >> 2, vc0 = t & 3, vlc0 = vc0 ^ swz(vrow0);
    int vrow1 = (t + 256) >> 2, vc1 = t & 3, vlc1 = vc1 ^ swz(vrow1);
    const float* hsrc = h + ((size_t)(b * LHH + i0 + hrow)) * HDD + hlc * 8;
    const float* us0  = u + ((size_t)(b * LUU + vrow0)) * HDD + vlc0 * 8;
    const float* us1  = u + ((size_t)(b * LUU + vrow1)) * HDD + vlc1 * 8;

    int arow = wave * 16 + lj;
    int a_idx = arow * 32 + ((lq ^ swz(arow)) * 8);
    int b_idx[8];
    #pragma unroll
    for (int n = 0; n < 8; ++n) {
        int j = n * 16 + lj;
        b_idx[n] = j * 32 + ((lq ^ swz(j)) * 8);
    }

    f32x4 acc[8];
    #pragma unroll
    for (int n = 0; n < 8; ++n) acc[n] = (f32x4){0.f, 0.f, 0.f, 0.f};

    for (int step = 0; step < 8; ++step) {
        int k0 = step * 32;
        if (step) __syncthreads();
        {
            float4 f0 = *reinterpret_cast<const float4*>(hsrc + k0);
            float4 f1 = *reinterpret_cast<const float4*>(hsrc + k0 + 4);
            union { short8 s8; __hip_bfloat16 bh[8]; } pk;
            pk.bh[0]=__float2bfloat16(f0.x); pk.bh[1]=__float2bfloat16(f0.y);
            pk.bh[2]=__float2bfloat16(f0.z); pk.bh[3]=__float2bfloat16(f0.w);
            pk.bh[4]=__float2bfloat16(f1.x); pk.bh[5]=__float2bfloat16(f1.y);
            pk.bh[6]=__float2bfloat16(f1.z); pk.bh[7]=__float2bfloat16(f1.w);
            *reinterpret_cast<short8*>(&lh[hrow * 32 + hc * 8]) = pk.s8;
        }
        #pragma unroll
        for (int p = 0; p < 2; ++p) {
            const float* usrc = p ? us1 : us0;
            int vlc = p ? vlc1 : vlc0;
            int vrow = p ? vrow1 : vrow0;
            int vc = p ? vc1 : vc0;
            float4 uu0 = *reinterpret_cast<const float4*>(usrc + k0);
            float4 uu1 = *reinterpret_cast<const float4*>(usrc + k0 + 4);
            float4 wh0 = *reinterpret_cast<const float4*>(w + k0 + vlc * 8);
            float4 wh1 = *reinterpret_cast<const float4*>(w + k0 + vlc * 8 + 4);
            float4 wu0 = *reinterpret_cast<const float4*>(w + 2 * HDD + k0 + vlc * 8);
            float4 wu1 = *reinterpret_cast<const float4*>(w + 2 * HDD + k0 + vlc * 8 + 4);
            union { short8 s8; __hip_bfloat16 bh[8]; } pk;
            pk.bh[0]=__float2bfloat16(wh0.x + wu0.x * uu0.x);
            pk.bh[1]=__float2bfloat16(wh0.y + wu0.y * uu0.y);
            pk.bh[2]=__float2bfloat16(wh0.z + wu0.z * uu0.z);
            pk.bh[3]=__float2bfloat16(wh0.w + wu0.w * uu0.w);
            pk.bh[4]=__float2bfloat16(wh1.x + wu1.x * uu1.x);
            pk.bh[5]=__float2bfloat16(wh1.y + wu1.y * uu1.y);
            pk.bh[6]=__float2bfloat16(wh1.z + wu1.z * uu1.z);
            pk.bh[7]=__float2bfloat16(wh1.w + wu1.w * uu1.w);
            *reinterpret_cast<short8*>(&lv[vrow * 32 + vc * 8]) = pk.s8;
        }
        __syncthreads();
        short8 af = *reinterpret_cast<const short8*>(&lh[a_idx]);
        #pragma unroll
        for (int n = 0; n < 8; ++n) {
            short8 bf = *reinterpret_cast<const short8*>(&lv[b_idx[n]]);
            acc[n] = __builtin_amdgcn_mfma_f32_16x16x32_bf16(af, bf, acc[n], 0, 0, 0);
        }
    }

    float sv[8][4];
    #pragma unroll
    for (int n = 0; n < 8; ++n) {
        float uw = uwb_l[n * 16 + lj];
        #pragma unroll
        for (int q = 0; q < 4; ++q) sv[n][q] = acc[n][q] + uw;
    }
    float umv[8];
    #pragma unroll
    for (int n = 0; n < 8; ++n) umv[n] = um_l[n * 16 + lj];

    #pragma unroll
    for (int q = 0; q < 4; ++q) {
        float ms = NEGF;
        #pragma unroll
        for (int n = 0; n < 8; ++n) ms = fmaxf(ms, umv[n] > 0.f ? sv[n][q] : NEGF);
        #pragma unroll
        for (int off = 8; off; off >>= 1) ms = fmaxf(ms, __shfl_xor(ms, off));
        float e = 0.f;
        #pragma unroll
        for (int n = 0; n < 8; ++n) e += umv[n] * cexpf(sv[n][q] - ms);
        #pragma unroll
        for (int off = 8; off; off >>= 1) e += __shfl_xor(e, off);
        int i = i0 + wave * 16 + lq * 4 + q;
        float* Srow = ws + S_OFF + ((size_t)(b * LHH + i)) * LUU;
        #pragma unroll
        for (int n = 0; n < 8; ++n) Srow[n * 16 + lj] = sv[n][q];
        if (lj == 0) {
            ws[RM_OFF + b * LHH + i] = ms;
            ws[RI_OFF + b * LHH + i] = grcp(e);
        }
    }
}

// ---------------- K2: partial column stats ----------------
__global__ __launch_bounds__(256) void k_colpart(const void* __restrict__ h_mask,
                                                 float* __restrict__ ws) {
    int b = blockIdx.x, c = blockIdx.y;
    int t = threadIdx.x;
    int j = t & 127, ih = t >> 7;
    int flag = reinterpret_cast<const int*>(ws)[FLAG_OFF];
    float m = NEGF, s = 0.f;
    const float* Sb = ws + S_OFF + ((size_t)b * LHH) * LUU;
    int i0 = c * 128;
    for (int ii = ih; ii < 128; ii += 2) {
        int i = i0 + ii;
        if (mval(h_mask, b * LHH + i, flag) > 0.f) {
            float x  = Sb[(size_t)i * LUU + j];
            float mn = fmaxf(m, x);
            s = s * __expf(m - mn) + __expf(x - mn);
            m = mn;
        }
    }
    __shared__ float sm_m[128], sm_s[128];
    if (ih == 0) { sm_m[j] = m; sm_s[j] = s; }
    __syncthreads();
    if (ih == 1) {
        float m0 = sm_m[j], s0 = sm_s[j];
        float mn = fmaxf(m0, m);
        float sc = s0 * __expf(fminf(m0 - mn, 0.f)) + s * __expf(fminf(m - mn, 0.f));
        ws[PM_OFF + (b * 8 + c) * LUU + j] = mn;
        ws[PS_OFF + (b * 8 + c) * LUU + j] = sc;
    }
}

// ---------------- K2b: combine partial column stats ----------------
__global__ __launch_bounds__(128) void k_colcomb(float* __restrict__ ws) {
    int b = blockIdx.x, j = threadIdx.x;
    float m = NEGF;
    #pragma unroll
    for (int c = 0; c < 8; ++c) m = fmaxf(m, ws[PM_OFF + (b * 8 + c) * LUU + j]);
    float s = 0.f;
    #pragma unroll
    for (int c = 0; c < 8; ++c)
        s += ws[PS_OFF + (b * 8 + c) * LUU + j] * cexpf(ws[PM_OFF + (b * 8 + c) * LUU + j] - m);
    ws[CM_OFF + b * LUU + j] = m;
    ws[CI_OFF + b * LUU + j] = grcp(s);
}

// ---------------- K3: C partials: CP[b][ic][u][hd] = sum_{i in chunk} a_t[i,u]h[i,hd] ----
__global__ __launch_bounds__(256) void k_C(const float* __restrict__ h,
                                           const void* __restrict__ u_mask,
                                           float* __restrict__ ws) {
    int b = blockIdx.x, ut = blockIdx.y, ic = blockIdx.z;
    int u0 = ut * 16;
    int t = threadIdx.x;
    int flag = reinterpret_cast<const int*>(ws)[FLAG_OFF];
    __shared__ float a_l[64][16];
    float acc[16];
    #pragma unroll
    for (int q = 0; q < 16; ++q) acc[q] = 0.f;

    const float* Sb = ws + S_OFF + (size_t)b * LHH * LUU;
    const float* rm = ws + RM_OFF + b * LHH;
    const float* ri = ws + RI_OFF + b * LHH;
    const float* hb = h + (size_t)b * LHH * HDD;

    int iq = t >> 2, uq = t & 3;
    float um_[4];
    #pragma unroll
    for (int c = 0; c < 4; ++c)
        um_[c] = mval(u_mask, b * LUU + u0 + uq * 4 + c, flag);

    for (int i0 = ic * 256; i0 < ic * 256 + 256; i0 += 64) {
        __syncthreads();
        {
            int i = i0 + iq;
            float4 s4 = *reinterpret_cast<const float4*>(Sb + (size_t)i * LUU + u0 + uq * 4);
            float mm = rm[i], rr = ri[i];
            a_l[iq][uq * 4 + 0] = um_[0] * cexpf(s4.x - mm) * rr;
            a_l[iq][uq * 4 + 1] = um_[1] * cexpf(s4.y - mm) * rr;
            a_l[iq][uq * 4 + 2] = um_[2] * cexpf(s4.z - mm) * rr;
            a_l[iq][uq * 4 + 3] = um_[3] * cexpf(s4.w - mm) * rr;
        }
        __syncthreads();
        #pragma unroll 4
        for (int ii = 0; ii < 64; ++ii) {
            float hval = hb[(size_t)(i0 + ii) * HDD + t];
            #pragma unroll
            for (int q = 0; q < 4; ++q) {
                float4 a4 = *reinterpret_cast<const float4*>(&a_l[ii][q * 4]);
                acc[q * 4 + 0] += a4.x * hval;
                acc[q * 4 + 1] += a4.y * hval;
                acc[q * 4 + 2] += a4.z * hval;
                acc[q * 4 + 3] += a4.w * hval;
            }
        }
    }
    #pragma unroll
    for (int q = 0; q < 16; ++q)
        ws[CP_OFF + ((size_t)((b * 4 + ic) * LUU + u0 + q)) * HDD + t] = acc[q];
}

// ---------------- K3b: combine C partials -> C_bfT[b][hd][u] bf16 ----------------
__global__ __launch_bounds__(256) void k_Ccomb(float* __restrict__ ws) {
    __shared__ float ct[8][264];
    int b = blockIdx.x, u0 = blockIdx.y * 8;
    int t = threadIdx.x;
    int ur = t >> 5, hq = t & 31;
    float acc[8];
    #pragma unroll
    for (int c = 0; c < 8; ++c) acc[c] = 0.f;
    #pragma unroll
    for (int ic = 0; ic < 4; ++ic) {
        const float* p = ws + CP_OFF + ((size_t)((b * 4 + ic) * LUU + u0 + ur)) * HDD + hq * 8;
        float4 x0 = *reinterpret_cast<const float4*>(p);
        float4 x1 = *reinterpret_cast<const float4*>(p + 4);
        acc[0] += x0.x; acc[1] += x0.y; acc[2] += x0.z; acc[3] += x0.w;
        acc[4] += x1.x; acc[5] += x1.y; acc[6] += x1.z; acc[7] += x1.w;
    }
    #pragma unroll
    for (int c = 0; c < 8; ++c) ct[ur][hq * 8 + c] = acc[c];
    __syncthreads();
    int hd = t;
    short* cbt = reinterpret_cast<short*>(ws + CBT_OFF);
    union { short8 s8; __hip_bfloat16 bh[8]; } pk;
    #pragma unroll
    for (int uu = 0; uu < 8; ++uu) pk.bh[uu] = __float2bfloat16(ct[uu][hd]);
    *reinterpret_cast<short8*>(&cbt[((size_t)(b * 256 + hd)) * 128 + u0]) = pk.s8;
}

// ---------------- K4 (MFMA): U=a_t·u, H=b_t·C, concat output ----------------
// Per block: 64 i x 128 hd, K=128 (j) in 4 steps of 32. A tiles (a_t,b_t) bf16
// from S+stats; B tiles from precomputed bf16 u^T / C^T (K-contiguous rows).
__global__ __launch_bounds__(256) void k_outm(const float* __restrict__ h,
                                              const void* __restrict__ h_mask,
                                              const void* __restrict__ u_mask,
                                              const float* __restrict__ ws,
                                              float* __restrict__ out) {
    __shared__ __align__(16) short la[64 * 32], lb[64 * 32];
    __shared__ __align__(16) short lu[128 * 32], lc[128 * 32];
    __shared__ float rm_l[64], ri_l[64], hm_l[64];
    __shared__ float cm_l[128], ci_l[128], um_l[128];

    int b = blockIdx.x, i0 = blockIdx.y * 64, hd0 = blockIdx.z * 128;
    int t = threadIdx.x;
    int flag = reinterpret_cast<const int*>(ws)[FLAG_OFF];
    int wave = t >> 6, lane = t & 63, lj = lane & 15, lq = lane >> 4;

    if (t < 64) {
        rm_l[t] = ws[RM_OFF + b * LHH + i0 + t];
        ri_l[t] = ws[RI_OFF + b * LHH + i0 + t];
        hm_l[t] = mval(h_mask, b * LHH + i0 + t, flag);
    } else if (t < 192) {
        int j = t - 64;
        cm_l[j] = ws[CM_OFF + b * LUU + j];
        ci_l[j] = ws[CI_OFF + b * LUU + j];
        um_l[j] = mval(u_mask, b * LUU + j, flag);
    }

    const short* ubt = reinterpret_cast<const short*>(ws + UBT_OFF) + ((size_t)(b * 256 + hd0)) * 128;
    const short* cbt = reinterpret_cast<const short*>(ws + CBT_OFF) + ((size_t)(b * 256 + hd0)) * 128;

    int air = t >> 2, ap = t & 3;              // A staging: row, phys chunk
    int brow = t >> 1;                          // B staging: row 0..127
    int a_idx = (wave * 16 + lj) * 32 + ((lq ^ swz(wave * 16 + lj)) * 8);
    int b_idx[8];
    #pragma unroll
    for (int n = 0; n < 8; ++n) {
        int r = n * 16 + lj;
        b_idx[n] = r * 32 + ((lq ^ swz(r)) * 8);
    }

    f32x4 aU[8], aH[8];
    #pragma unroll
    for (int n = 0; n < 8; ++n) { aU[n] = (f32x4){0,0,0,0}; aH[n] = (f32x4){0,0,0,0}; }

    for (int step = 0; step < 4; ++step) {
        int j0 = step * 32;
        __syncthreads();                       // prev MFMA done (covers stats load at step 0)
        {
            int lgc = ap ^ swz(air);
            const float* Sp = ws + S_OFF + ((size_t)(b * LHH + i0 + air)) * LUU + j0 + lgc * 8;
            float4 s0 = *reinterpret_cast<const float4*>(Sp);
            float4 s1 = *reinterpret_cast<const float4*>(Sp + 4);
            float rmv = rm_l[air], riv = ri_l[air], hmv = hm_l[air];
            float sv[8] = {s0.x, s0.y, s0.z, s0.w, s1.x, s1.y, s1.z, s1.w};
            union { short8 s8; __hip_bfloat16 bh[8]; } pa, pb;
            #pragma unroll
            for (int c = 0; c < 8; ++c) {
                int j = j0 + lgc * 8 + c;
                pa.bh[c] = __float2bfloat16(um_l[j] * cexpf(sv[c] - rmv) * riv);
                pb.bh[c] = __float2bfloat16(hmv * cexpf(sv[c] - cm_l[j]) * ci_l[j]);
            }
            *reinterpret_cast<short8*>(&la[air * 32 + ap * 8]) = pa.s8;
            *reinterpret_cast<short8*>(&lb[air * 32 + ap * 8]) = pb.s8;
        }
        #pragma unroll
        for (int pp = 0; pp < 2; ++pp) {
            int p = (t & 1) * 2 + pp;
            int lgc = p ^ swz(brow);
            *reinterpret_cast<short8*>(&lu[brow * 32 + p * 8]) =
                *reinterpret_cast<const short8*>(ubt + (size_t)brow * 128 + j0 + lgc * 8);
            *reinterpret_cast<short8*>(&lc[brow * 32 + p * 8]) =
                *reinterpret_cast<const short8*>(cbt + (size_t)brow * 128 + j0 + lgc * 8);
        }
        __syncthreads();
        short8 fa = *reinterpret_cast<const short8*>(&la[a_idx]);
        short8 fb = *reinterpret_cast<const short8*>(&lb[a_idx]);
        #pragma unroll
        for (int n = 0; n < 8; ++n) {
            short8 gu = *reinterpret_cast<const short8*>(&lu[b_idx[n]]);
            short8 gc = *reinterpret_cast<const short8*>(&lc[b_idx[n]]);
            aU[n] = __builtin_amdgcn_mfma_f32_16x16x32_bf16(fa, gu, aU[n], 0, 0, 0);
            aH[n] = __builtin_amdgcn_mfma_f32_16x16x32_bf16(fb, gc, aH[n], 0, 0, 0);
        }
    }

    #pragma unroll
    for (int n = 0; n < 8; ++n) {
        int hd = hd0 + n * 16 + lj;
        #pragma unroll
        for (int q = 0; q < 4; ++q) {
            int i = i0 + wave * 16 + lq * 4 + q;
            float hv = h[((size_t)(b * LHH + i)) * HDD + hd];
            size_t base = ((size_t)(b * LHH + i)) * (4 * HDD) + hd;
            float Uv = aU[n][q], Hv = aH[n][q];
            out[base]           = hv;
            out[base + HDD]     = Uv;
            out[base + 2 * HDD] = hv * Uv;
            out[base + 3 * HDD] = hv * Hv;
        }
    }
}

extern "C" void kernel_launch(void* const* d_in, const int* in_sizes, int n_in,
                              void* d_out, int out_size, void* d_ws, size_t ws_size,
                              hipStream_t stream) {
    const float* h = (const float*)d_in[0];
    const float* u = (const float*)d_in[1];
    const void*  h_mask = d_in[2];
    const void*  u_mask = d_in[3];
    const float* w    = (const float*)d_in[4];
    const float* bias = (const float*)d_in[5];
    float* ws  = (float*)d_ws;
    float* out = (float*)d_out;

    if (ws_size < WS_FLOATS * sizeof(float)) return;  // diagnostic: leaves out zeroed

    k_detect<<<dim3(1), 64, 0, stream>>>((const unsigned char*)h_mask, ws);
    k_uwb<<<dim3(BB * LUU / 4), 256, 0, stream>>>(u, w, bias, ws);
    k_uT<<<dim3(BB, HDD / 32), 256, 0, stream>>>(u, ws);
    k_Smfma<<<dim3(BB, LHH / 64), 256, 0, stream>>>(h, u, u_mask, w, ws);
    k_colpart<<<dim3(BB, 8), 256, 0, stream>>>(h_mask, ws);
    k_colcomb<<<dim3(BB), 128, 0, stream>>>(ws);
    k_C<<<dim3(BB, LUU / 16, 4), 256, 0, stream>>>(h, u_mask, ws);
    k_Ccomb<<<dim3(BB, LUU / 8), 256, 0, stream>>>(ws);
    k_outm<<<dim3(BB, LHH / 64, 2), 256, 0, stream>>>(h, h_mask, u_mask, ws, out);
}

// Round 8
// 114.606 us; speedup vs baseline: 8.4088x; 1.3120x over previous
//
#include <hip/hip_runtime.h>
#include <hip/hip_bf16.h>

#define BB  32
#define LHH 1024
#define LUU 128
#define HDD 256
#define NEGF (-1e30f)

typedef __attribute__((ext_vector_type(8))) short short8;
typedef __attribute__((ext_vector_type(4))) float f32x4;

// ---- workspace layout (float offsets) ----
static constexpr size_t S_OFF    = 0;                           // [B][LH][LU] full S f32
static constexpr size_t UWB_OFF  = S_OFF + (size_t)BB*LHH*LUU;  // [B][LU]
static constexpr size_t RM_OFF   = UWB_OFF + (size_t)BB*LUU;    // [B][LH] row max
static constexpr size_t RI_OFF   = RM_OFF + (size_t)BB*LHH;     // [B][LH] 1/row sum
static constexpr size_t PM_OFF   = RI_OFF + (size_t)BB*LHH;     // [B][16][LU] col-max partials
static constexpr size_t PS_OFF   = PM_OFF + (size_t)BB*16*LUU;  // [B][16][LU] col-sum partials
static constexpr size_t CM_OFF   = PS_OFF + (size_t)BB*16*LUU;  // [B][LU] col max
static constexpr size_t CI_OFF   = CM_OFF + (size_t)BB*LUU;     // [B][LU] 1/col sum
static constexpr size_t CP_OFF   = CI_OFF + (size_t)BB*LUU;     // [B][8][LU][HD] C partials f32
static constexpr size_t UBT_OFF  = CP_OFF + (size_t)BB*8*LUU*HDD;  // [B][HD][LU] bf16 u^T
static constexpr size_t CBT_OFF  = UBT_OFF + (size_t)BB*HDD*LUU/2; // [B][HD][LU] bf16 C^T
static constexpr size_t FLAG_OFF = CBT_OFF + (size_t)BB*HDD*LUU/2; // 1 int
static constexpr size_t WS_FLOATS= FLAG_OFF + 1;

__device__ __forceinline__ float mval(const void* p, int idx, int flag) {
    if (flag) return ((const unsigned char*)p)[idx] ? 1.0f : 0.0f;
    return (((const int*)p)[idx] != 0) ? 1.0f : 0.0f;
}
__device__ __forceinline__ float cexpf(float x) { return __expf(fminf(x, 60.0f)); }
__device__ __forceinline__ float grcp(float x)  { return 1.0f / fmaxf(x, 1e-38f); }
__device__ __forceinline__ int swz(int r) { return (r ^ (r >> 2)) & 3; }

// ---------------- K0: uwb[b,j] = u[b,j,:]·w_u + bias (+ mask dtype flag) -----
__global__ __launch_bounds__(256) void k_uwb(const float* __restrict__ u,
                                             const float* __restrict__ w,
                                             const float* __restrict__ bias,
                                             const unsigned char* __restrict__ hm,
                                             float* __restrict__ ws) {
    if (blockIdx.x == 0 && threadIdx.x == 0)
        reinterpret_cast<int*>(ws)[FLAG_OFF] = (hm[1] != 0) ? 1 : 0;
    int wave = threadIdx.x >> 6;
    int lane = threadIdx.x & 63;
    int idx  = blockIdx.x * 4 + wave;          // b*LU + j
    int b = idx >> 7, j = idx & 127;
    const float4* u4  = reinterpret_cast<const float4*>(u + ((size_t)(b * LUU + j)) * HDD);
    const float4* wu4 = reinterpret_cast<const float4*>(w + HDD);
    float4 a = u4[lane], c = wu4[lane];
    float s = a.x * c.x + a.y * c.y + a.z * c.z + a.w * c.w;
    #pragma unroll
    for (int off = 32; off; off >>= 1) s += __shfl_xor(s, off);
    if (lane == 0) ws[UWB_OFF + idx] = s + bias[0];
}

// ---------------- K0b: u_bfT[b][hd][j] = bf16(u[b][j][hd]) ----------------
__global__ __launch_bounds__(256) void k_uT(const float* __restrict__ u,
                                            float* __restrict__ ws) {
    __shared__ float ls[32][132];
    int b = blockIdx.x, hd0 = blockIdx.y * 32;
    int t = threadIdx.x;
    int hc = t & 7, jj = t >> 3;
    #pragma unroll
    for (int pass = 0; pass < 4; ++pass) {
        int j = jj + pass * 32;
        float4 v = *reinterpret_cast<const float4*>(u + ((size_t)(b * LUU + j)) * HDD + hd0 + hc * 4);
        ls[hc * 4 + 0][j] = v.x; ls[hc * 4 + 1][j] = v.y;
        ls[hc * 4 + 2][j] = v.z; ls[hc * 4 + 3][j] = v.w;
    }
    __syncthreads();
    int r = t >> 3, ck = t & 7;                // row hd0+r, j chunk of 16
    short* ubt = reinterpret_cast<short*>(ws + UBT_OFF);
    union { short8 s8; __hip_bfloat16 bh[8]; } pk;
    #pragma unroll
    for (int hhalf = 0; hhalf < 2; ++hhalf) {
        #pragma unroll
        for (int c = 0; c < 8; ++c)
            pk.bh[c] = __float2bfloat16(ls[r][ck * 16 + hhalf * 8 + c]);
        *reinterpret_cast<short8*>(&ubt[((size_t)(b * 256 + hd0 + r)) * 128 + ck * 16 + hhalf * 8]) = pk.s8;
    }
}

// ---------------- K1 (MFMA): S = h·v^T + uwb, row stats, col-stat partials ---
__global__ __launch_bounds__(256) void k_Smfma(const float* __restrict__ h,
                                               const float* __restrict__ u,
                                               const void* __restrict__ u_mask,
                                               const void* __restrict__ h_mask,
                                               const float* __restrict__ w,
                                               float* __restrict__ ws) {
    __shared__ __align__(16) short lh[64 * 32];
    __shared__ __align__(16) short lv[128 * 32];
    __shared__ float uwb_l[128], um_l[128], hm_l[64];
    __shared__ float credm[4][128], creds[4][128];

    int b  = blockIdx.x;
    int i0 = blockIdx.y * 64;
    int t  = threadIdx.x;
    int flag = reinterpret_cast<const int*>(ws)[FLAG_OFF];
    int wave = t >> 6, lane = t & 63;
    int lj = lane & 15, lq = lane >> 4;

    if (t < 128) {
        uwb_l[t] = ws[UWB_OFF + b * LUU + t];
        um_l[t]  = mval(u_mask, b * LUU + t, flag);
    } else if (t < 192) {
        hm_l[t - 128] = mval(h_mask, b * LHH + i0 + (t - 128), flag);
    }

    int hrow = t >> 2,  hc = t & 3,  hlc = hc ^ swz(hrow);
    int vrow0 = t >> 2, vc0 = t & 3, vlc0 = vc0 ^ swz(vrow0);
    int vrow1 = (t + 256) >> 2, vc1 = t & 3, vlc1 = vc1 ^ swz(vrow1);
    const float* hsrc = h + ((size_t)(b * LHH + i0 + hrow)) * HDD + hlc * 8;
    const float* us0  = u + ((size_t)(b * LUU + vrow0)) * HDD + vlc0 * 8;
    const float* us1  = u + ((size_t)(b * LUU + vrow1)) * HDD + vlc1 * 8;

    int arow = wave * 16 + lj;
    int a_idx = arow * 32 + ((lq ^ swz(arow)) * 8);
    int b_idx[8];
    #pragma unroll
    for (int n = 0; n < 8; ++n) {
        int j = n * 16 + lj;
        b_idx[n] = j * 32 + ((lq ^ swz(j)) * 8);
    }

    f32x4 acc[8];
    #pragma unroll
    for (int n = 0; n < 8; ++n) acc[n] = (f32x4){0.f, 0.f, 0.f, 0.f};

    for (int step = 0; step < 8; ++step) {
        int k0 = step * 32;
        if (step) __syncthreads();
        {
            float4 f0 = *reinterpret_cast<const float4*>(hsrc + k0);
            float4 f1 = *reinterpret_cast<const float4*>(hsrc + k0 + 4);
            union { short8 s8; __hip_bfloat16 bh[8]; } pk;
            pk.bh[0]=__float2bfloat16(f0.x); pk.bh[1]=__float2bfloat16(f0.y);
            pk.bh[2]=__float2bfloat16(f0.z); pk.bh[3]=__float2bfloat16(f0.w);
            pk.bh[4]=__float2bfloat16(f1.x); pk.bh[5]=__float2bfloat16(f1.y);
            pk.bh[6]=__float2bfloat16(f1.z); pk.bh[7]=__float2bfloat16(f1.w);
            *reinterpret_cast<short8*>(&lh[hrow * 32 + hc * 8]) = pk.s8;
        }
        #pragma unroll
        for (int p = 0; p < 2; ++p) {
            const float* usrc = p ? us1 : us0;
            int vlc = p ? vlc1 : vlc0;
            int vrow = p ? vrow1 : vrow0;
            int vc = p ? vc1 : vc0;
            float4 uu0 = *reinterpret_cast<const float4*>(usrc + k0);
            float4 uu1 = *reinterpret_cast<const float4*>(usrc + k0 + 4);
            float4 wh0 = *reinterpret_cast<const float4*>(w + k0 + vlc * 8);
            float4 wh1 = *reinterpret_cast<const float4*>(w + k0 + vlc * 8 + 4);
            float4 wu0 = *reinterpret_cast<const float4*>(w + 2 * HDD + k0 + vlc * 8);
            float4 wu1 = *reinterpret_cast<const float4*>(w + 2 * HDD + k0 + vlc * 8 + 4);
            union { short8 s8; __hip_bfloat16 bh[8]; } pk;
            pk.bh[0]=__float2bfloat16(wh0.x + wu0.x * uu0.x);
            pk.bh[1]=__float2bfloat16(wh0.y + wu0.y * uu0.y);
            pk.bh[2]=__float2bfloat16(wh0.z + wu0.z * uu0.z);
            pk.bh[3]=__float2bfloat16(wh0.w + wu0.w * uu0.w);
            pk.bh[4]=__float2bfloat16(wh1.x + wu1.x * uu1.x);
            pk.bh[5]=__float2bfloat16(wh1.y + wu1.y * uu1.y);
            pk.bh[6]=__float2bfloat16(wh1.z + wu1.z * uu1.z);
            pk.bh[7]=__float2bfloat16(wh1.w + wu1.w * uu1.w);
            *reinterpret_cast<short8*>(&lv[vrow * 32 + vc * 8]) = pk.s8;
        }
        __syncthreads();
        short8 af = *reinterpret_cast<const short8*>(&lh[a_idx]);
        #pragma unroll
        for (int n = 0; n < 8; ++n) {
            short8 bf = *reinterpret_cast<const short8*>(&lv[b_idx[n]]);
            acc[n] = __builtin_amdgcn_mfma_f32_16x16x32_bf16(af, bf, acc[n], 0, 0, 0);
        }
    }

    // ---- epilogue 1: add uwb, row stats over 128 j, write S f32 ----
    float sv[8][4];
    #pragma unroll
    for (int n = 0; n < 8; ++n) {
        float uw = uwb_l[n * 16 + lj];
        #pragma unroll
        for (int q = 0; q < 4; ++q) sv[n][q] = acc[n][q] + uw;
    }
    float umv[8];
    #pragma unroll
    for (int n = 0; n < 8; ++n) umv[n] = um_l[n * 16 + lj];

    #pragma unroll
    for (int q = 0; q < 4; ++q) {
        float ms = NEGF;
        #pragma unroll
        for (int n = 0; n < 8; ++n) ms = fmaxf(ms, umv[n] > 0.f ? sv[n][q] : NEGF);
        #pragma unroll
        for (int off = 8; off; off >>= 1) ms = fmaxf(ms, __shfl_xor(ms, off));
        float e = 0.f;
        #pragma unroll
        for (int n = 0; n < 8; ++n) e += umv[n] * cexpf(sv[n][q] - ms);
        #pragma unroll
        for (int off = 8; off; off >>= 1) e += __shfl_xor(e, off);
        int i = i0 + wave * 16 + lq * 4 + q;
        float* Srow = ws + S_OFF + ((size_t)(b * LHH + i)) * LUU;
        #pragma unroll
        for (int n = 0; n < 8; ++n) Srow[n * 16 + lj] = sv[n][q];
        if (lj == 0) {
            ws[RM_OFF + b * LHH + i] = ms;
            ws[RI_OFF + b * LHH + i] = grcp(e);
        }
    }

    // ---- epilogue 2: col-stat partials over this block's 64 i-rows ----
    float hmq[4];
    #pragma unroll
    for (int q = 0; q < 4; ++q) hmq[q] = hm_l[wave * 16 + lq * 4 + q];
    #pragma unroll
    for (int n = 0; n < 8; ++n) {
        float cmx = NEGF, csx = 0.f;
        #pragma unroll
        for (int q = 0; q < 4; ++q) {
            if (hmq[q] > 0.f) {
                float x  = sv[n][q];
                float mn = fmaxf(cmx, x);
                csx = csx * cexpf(cmx - mn) + cexpf(x - mn);
                cmx = mn;
            }
        }
        #pragma unroll
        for (int off = 16; off <= 32; off <<= 1) {
            float om = __shfl_xor(cmx, off);
            float os = __shfl_xor(csx, off);
            float mn = fmaxf(cmx, om);
            csx = csx * cexpf(cmx - mn) + os * cexpf(om - mn);
            cmx = mn;
        }
        if (lq == 0) { credm[wave][n * 16 + lj] = cmx; creds[wave][n * 16 + lj] = csx; }
    }
    __syncthreads();
    if (t < 128) {
        float m = credm[0][t], s = creds[0][t];
        #pragma unroll
        for (int wv = 1; wv < 4; ++wv) {
            float om = credm[wv][t], os = creds[wv][t];
            float mn = fmaxf(m, om);
            s = s * cexpf(m - mn) + os * cexpf(om - mn);
            m = mn;
        }
        ws[PM_OFF + (b * 16 + blockIdx.y) * LUU + t] = m;
        ws[PS_OFF + (b * 16 + blockIdx.y) * LUU + t] = s;
    }
}

// ---------------- K2b: combine partial column stats (16 partials) ------------
__global__ __launch_bounds__(128) void k_colcomb(float* __restrict__ ws) {
    int b = blockIdx.x, j = threadIdx.x;
    float m = NEGF;
    #pragma unroll
    for (int c = 0; c < 16; ++c) m = fmaxf(m, ws[PM_OFF + (b * 16 + c) * LUU + j]);
    float s = 0.f;
    #pragma unroll
    for (int c = 0; c < 16; ++c)
        s += ws[PS_OFF + (b * 16 + c) * LUU + j] * cexpf(ws[PM_OFF + (b * 16 + c) * LUU + j] - m);
    ws[CM_OFF + b * LUU + j] = m;
    ws[CI_OFF + b * LUU + j] = grcp(s);
}

// ---------------- K3: C partials: CP[b][ic][u][hd] over 128-i chunks ---------
__global__ __launch_bounds__(256) void k_C(const float* __restrict__ h,
                                           const void* __restrict__ u_mask,
                                           float* __restrict__ ws) {
    int b = blockIdx.x, ut = blockIdx.y, ic = blockIdx.z;
    int u0 = ut * 16;
    int t = threadIdx.x;
    int flag = reinterpret_cast<const int*>(ws)[FLAG_OFF];
    __shared__ float a_l[64][16];
    float acc[16];
    #pragma unroll
    for (int q = 0; q < 16; ++q) acc[q] = 0.f;

    const float* Sb = ws + S_OFF + (size_t)b * LHH * LUU;
    const float* rm = ws + RM_OFF + b * LHH;
    const float* ri = ws + RI_OFF + b * LHH;
    const float* hb = h + (size_t)b * LHH * HDD;

    int iq = t >> 2, uq = t & 3;
    float um_[4];
    #pragma unroll
    for (int c = 0; c < 4; ++c)
        um_[c] = mval(u_mask, b * LUU + u0 + uq * 4 + c, flag);

    for (int i0 = ic * 128; i0 < ic * 128 + 128; i0 += 64) {
        __syncthreads();
        {
            int i = i0 + iq;
            float4 s4 = *reinterpret_cast<const float4*>(Sb + (size_t)i * LUU + u0 + uq * 4);
            float mm = rm[i], rr = ri[i];
            a_l[iq][uq * 4 + 0] = um_[0] * cexpf(s4.x - mm) * rr;
            a_l[iq][uq * 4 + 1] = um_[1] * cexpf(s4.y - mm) * rr;
            a_l[iq][uq * 4 + 2] = um_[2] * cexpf(s4.z - mm) * rr;
            a_l[iq][uq * 4 + 3] = um_[3] * cexpf(s4.w - mm) * rr;
        }
        __syncthreads();
        #pragma unroll 4
        for (int ii = 0; ii < 64; ++ii) {
            float hval = hb[(size_t)(i0 + ii) * HDD + t];
            #pragma unroll
            for (int q = 0; q < 4; ++q) {
                float4 a4 = *reinterpret_cast<const float4*>(&a_l[ii][q * 4]);
                acc[q * 4 + 0] += a4.x * hval;
                acc[q * 4 + 1] += a4.y * hval;
                acc[q * 4 + 2] += a4.z * hval;
                acc[q * 4 + 3] += a4.w * hval;
            }
        }
    }
    #pragma unroll
    for (int q = 0; q < 16; ++q)
        ws[CP_OFF + ((size_t)((b * 8 + ic) * LUU + u0 + q)) * HDD + t] = acc[q];
}

// ---------------- K3b: combine C partials -> C_bfT[b][hd][u] bf16 ------------
__global__ __launch_bounds__(256) void k_Ccomb(float* __restrict__ ws) {
    __shared__ float ct[8][264];
    int b = blockIdx.x, u0 = blockIdx.y * 8;
    int t = threadIdx.x;
    int ur = t >> 5, hq = t & 31;
    float acc[8];
    #pragma unroll
    for (int c = 0; c < 8; ++c) acc[c] = 0.f;
    #pragma unroll
    for (int ic = 0; ic < 8; ++ic) {
        const float* p = ws + CP_OFF + ((size_t)((b * 8 + ic) * LUU + u0 + ur)) * HDD + hq * 8;
        float4 x0 = *reinterpret_cast<const float4*>(p);
        float4 x1 = *reinterpret_cast<const float4*>(p + 4);
        acc[0] += x0.x; acc[1] += x0.y; acc[2] += x0.z; acc[3] += x0.w;
        acc[4] += x1.x; acc[5] += x1.y; acc[6] += x1.z; acc[7] += x1.w;
    }
    #pragma unroll
    for (int c = 0; c < 8; ++c) ct[ur][hq * 8 + c] = acc[c];
    __syncthreads();
    int hd = t;
    short* cbt = reinterpret_cast<short*>(ws + CBT_OFF);
    union { short8 s8; __hip_bfloat16 bh[8]; } pk;
    #pragma unroll
    for (int uu = 0; uu < 8; ++uu) pk.bh[uu] = __float2bfloat16(ct[uu][hd]);
    *reinterpret_cast<short8*>(&cbt[((size_t)(b * 256 + hd)) * 128 + u0]) = pk.s8;
}

// ---------------- K4 (MFMA): U=a_t·u, H=b_t·C, concat output ----------------
__global__ __launch_bounds__(256) void k_outm(const float* __restrict__ h,
                                              const void* __restrict__ h_mask,
                                              const void* __restrict__ u_mask,
                                              const float* __restrict__ ws,
                                              float* __restrict__ out) {
    __shared__ __align__(16) short la[64 * 32], lb[64 * 32];
    __shared__ __align__(16) short lu[128 * 32], lc[128 * 32];
    __shared__ float rm_l[64], ri_l[64], hm_l[64];
    __shared__ float cm_l[128], ci_l[128], um_l[128];

    int b = blockIdx.x, i0 = blockIdx.y * 64, hd0 = blockIdx.z * 128;
    int t = threadIdx.x;
    int flag = reinterpret_cast<const int*>(ws)[FLAG_OFF];
    int wave = t >> 6, lane = t & 63, lj = lane & 15, lq = lane >> 4;

    if (t < 64) {
        rm_l[t] = ws[RM_OFF + b * LHH + i0 + t];
        ri_l[t] = ws[RI_OFF + b * LHH + i0 + t];
        hm_l[t] = mval(h_mask, b * LHH + i0 + t, flag);
    } else if (t < 192) {
        int j = t - 64;
        cm_l[j] = ws[CM_OFF + b * LUU + j];
        ci_l[j] = ws[CI_OFF + b * LUU + j];
        um_l[j] = mval(u_mask, b * LUU + j, flag);
    }

    const short* ubt = reinterpret_cast<const short*>(ws + UBT_OFF) + ((size_t)(b * 256 + hd0)) * 128;
    const short* cbt = reinterpret_cast<const short*>(ws + CBT_OFF) + ((size_t)(b * 256 + hd0)) * 128;

    int air = t >> 2, ap = t & 3;
    int brow = t >> 1;
    int a_idx = (wave * 16 + lj) * 32 + ((lq ^ swz(wave * 16 + lj)) * 8);
    int b_idx[8];
    #pragma unroll
    for (int n = 0; n < 8; ++n) {
        int r = n * 16 + lj;
        b_idx[n] = r * 32 + ((lq ^ swz(r)) * 8);
    }

    f32x4 aU[8], aH[8];
    #pragma unroll
    for (int n = 0; n < 8; ++n) { aU[n] = (f32x4){0,0,0,0}; aH[n] = (f32x4){0,0,0,0}; }

    for (int step = 0; step < 4; ++step) {
        int j0 = step * 32;
        __syncthreads();
        {
            int lgc = ap ^ swz(air);
            const float* Sp = ws + S_OFF + ((size_t)(b * LHH + i0 + air)) * LUU + j0 + lgc * 8;
            float4 s0 = *reinterpret_cast<const float4*>(Sp);
            float4 s1 = *reinterpret_cast<const float4*>(Sp + 4);
            float rmv = rm_l[air], riv = ri_l[air], hmv = hm_l[air];
            float sv[8] = {s0.x, s0.y, s0.z, s0.w, s1.x, s1.y, s1.z, s1.w};
            union { short8 s8; __hip_bfloat16 bh[8]; } pa, pb;
            #pragma unroll
            for (int c = 0; c < 8; ++c) {
                int j = j0 + lgc * 8 + c;
                pa.bh[c] = __float2bfloat16(um_l[j] * cexpf(sv[c] - rmv) * riv);
                pb.bh[c] = __float2bfloat16(hmv * cexpf(sv[c] - cm_l[j]) * ci_l[j]);
            }
            *reinterpret_cast<short8*>(&la[air * 32 + ap * 8]) = pa.s8;
            *reinterpret_cast<short8*>(&lb[air * 32 + ap * 8]) = pb.s8;
        }
        #pragma unroll
        for (int pp = 0; pp < 2; ++pp) {
            int p = (t & 1) * 2 + pp;
            int lgc = p ^ swz(brow);
            *reinterpret_cast<short8*>(&lu[brow * 32 + p * 8]) =
                *reinterpret_cast<const short8*>(ubt + (size_t)brow * 128 + j0 + lgc * 8);
            *reinterpret_cast<short8*>(&lc[brow * 32 + p * 8]) =
                *reinterpret_cast<const short8*>(cbt + (size_t)brow * 128 + j0 + lgc * 8);
        }
        __syncthreads();
        short8 fa = *reinterpret_cast<const short8*>(&la[a_idx]);
        short8 fb = *reinterpret_cast<const short8*>(&lb[a_idx]);
        #pragma unroll
        for (int n = 0; n < 8; ++n) {
            short8 gu = *reinterpret_cast<const short8*>(&lu[b_idx[n]]);
            short8 gc = *reinterpret_cast<const short8*>(&lc[b_idx[n]]);
            aU[n] = __builtin_amdgcn_mfma_f32_16x16x32_bf16(fa, gu, aU[n], 0, 0, 0);
            aH[n] = __builtin_amdgcn_mfma_f32_16x16x32_bf16(fb, gc, aH[n], 0, 0, 0);
        }
    }

    #pragma unroll
    for (int n = 0; n < 8; ++n) {
        int hd = hd0 + n * 16 + lj;
        #pragma unroll
        for (int q = 0; q < 4; ++q) {
            int i = i0 + wave * 16 + lq * 4 + q;
            float hv = h[((size_t)(b * LHH + i)) * HDD + hd];
            size_t base = ((size_t)(b * LHH + i)) * (4 * HDD) + hd;
            float Uv = aU[n][q], Hv = aH[n][q];
            out[base]           = hv;
            out[base + HDD]     = Uv;
            out[base + 2 * HDD] = hv * Uv;
            out[base + 3 * HDD] = hv * Hv;
        }
    }
}

extern "C" void kernel_launch(void* const* d_in, const int* in_sizes, int n_in,
                              void* d_out, int out_size, void* d_ws, size_t ws_size,
                              hipStream_t stream) {
    const float* h = (const float*)d_in[0];
    const float* u = (const float*)d_in[1];
    const void*  h_mask = d_in[2];
    const void*  u_mask = d_in[3];
    const float* w    = (const float*)d_in[4];
    const float* bias = (const float*)d_in[5];
    float* ws  = (float*)d_ws;
    float* out = (float*)d_out;

    if (ws_size < WS_FLOATS * sizeof(float)) return;  // diagnostic: leaves out zeroed

    k_uwb<<<dim3(BB * LUU / 4), 256, 0, stream>>>(u, w, bias, (const unsigned char*)h_mask, ws);
    k_uT<<<dim3(BB, HDD / 32), 256, 0, stream>>>(u, ws);
    k_Smfma<<<dim3(BB, LHH / 64), 256, 0, stream>>>(h, u, u_mask, h_mask, w, ws);
    k_colcomb<<<dim3(BB), 128, 0, stream>>>(ws);
    k_C<<<dim3(BB, LUU / 16, 8), 256, 0, stream>>>(h, u_mask, ws);
    k_Ccomb<<<dim3(BB, LUU / 8), 256, 0, stream>>>(ws);
    k_outm<<<dim3(BB, LHH / 64, 2), 256, 0, stream>>>(h, h_mask, u_mask, ws, out);
}

// Round 9
// 95.744 us; speedup vs baseline: 10.0654x; 1.1970x over previous
//
#include <hip/hip_runtime.h>
#include <hip/hip_bf16.h>

#define BB  32
#define LHH 1024
#define LUU 128
#define HDD 256
#define NEGF (-1e30f)

typedef __attribute__((ext_vector_type(8))) short short8;
typedef __attribute__((ext_vector_type(4))) float f32x4;

// ---- workspace layout (float offsets) ----
static constexpr size_t S_OFF    = 0;                           // [B][LH][LU] full S f32
static constexpr size_t UWB_OFF  = S_OFF + (size_t)BB*LHH*LUU;  // [B][LU]
static constexpr size_t RM_OFF   = UWB_OFF + (size_t)BB*LUU;    // [B][LH] row max
static constexpr size_t RI_OFF   = RM_OFF + (size_t)BB*LHH;     // [B][LH] 1/row sum
static constexpr size_t PM_OFF   = RI_OFF + (size_t)BB*LHH;     // [B][16][LU] col-max partials
static constexpr size_t PS_OFF   = PM_OFF + (size_t)BB*16*LUU;  // [B][16][LU] col-sum partials
static constexpr size_t CM_OFF   = PS_OFF + (size_t)BB*16*LUU;  // [B][LU] col max
static constexpr size_t CI_OFF   = CM_OFF + (size_t)BB*LUU;     // [B][LU] 1/col sum
static constexpr size_t UBT_OFF  = CI_OFF + (size_t)BB*LUU;     // [B][HD][LU] bf16 u^T
static constexpr size_t CBT_OFF  = UBT_OFF + (size_t)BB*HDD*LUU/2; // [B][HD][LU] bf16 C^T
static constexpr size_t FLAG_OFF = CBT_OFF + (size_t)BB*HDD*LUU/2; // 1 int
static constexpr size_t WS_FLOATS= FLAG_OFF + 1;

__device__ __forceinline__ float mval(const void* p, int idx, int flag) {
    if (flag) return ((const unsigned char*)p)[idx] ? 1.0f : 0.0f;
    return (((const int*)p)[idx] != 0) ? 1.0f : 0.0f;
}
__device__ __forceinline__ float cexpf(float x) { return __expf(fminf(x, 60.0f)); }
__device__ __forceinline__ float grcp(float x)  { return 1.0f / fmaxf(x, 1e-38f); }
__device__ __forceinline__ int swz(int r) { return (r ^ (r >> 2)) & 3; }

// ---------------- K0: uwb[b,j] = u[b,j,:]·w_u + bias (+ mask dtype flag) -----
__global__ __launch_bounds__(256) void k_uwb(const float* __restrict__ u,
                                             const float* __restrict__ w,
                                             const float* __restrict__ bias,
                                             const unsigned char* __restrict__ hm,
                                             float* __restrict__ ws) {
    if (blockIdx.x == 0 && threadIdx.x == 0)
        reinterpret_cast<int*>(ws)[FLAG_OFF] = (hm[1] != 0) ? 1 : 0;
    int wave = threadIdx.x >> 6;
    int lane = threadIdx.x & 63;
    int idx  = blockIdx.x * 4 + wave;          // b*LU + j
    int b = idx >> 7, j = idx & 127;
    const float4* u4  = reinterpret_cast<const float4*>(u + ((size_t)(b * LUU + j)) * HDD);
    const float4* wu4 = reinterpret_cast<const float4*>(w + HDD);
    float4 a = u4[lane], c = wu4[lane];
    float s = a.x * c.x + a.y * c.y + a.z * c.z + a.w * c.w;
    #pragma unroll
    for (int off = 32; off; off >>= 1) s += __shfl_xor(s, off);
    if (lane == 0) ws[UWB_OFF + idx] = s + bias[0];
}

// ---------------- K0b: u_bfT[b][hd][j] = bf16(u[b][j][hd]) ----------------
__global__ __launch_bounds__(256) void k_uT(const float* __restrict__ u,
                                            float* __restrict__ ws) {
    __shared__ float ls[32][132];
    int b = blockIdx.x, hd0 = blockIdx.y * 32;
    int t = threadIdx.x;
    int hc = t & 7, jj = t >> 3;
    #pragma unroll
    for (int pass = 0; pass < 4; ++pass) {
        int j = jj + pass * 32;
        float4 v = *reinterpret_cast<const float4*>(u + ((size_t)(b * LUU + j)) * HDD + hd0 + hc * 4);
        ls[hc * 4 + 0][j] = v.x; ls[hc * 4 + 1][j] = v.y;
        ls[hc * 4 + 2][j] = v.z; ls[hc * 4 + 3][j] = v.w;
    }
    __syncthreads();
    int r = t >> 3, ck = t & 7;                // row hd0+r, j chunk of 16
    short* ubt = reinterpret_cast<short*>(ws + UBT_OFF);
    union { short8 s8; __hip_bfloat16 bh[8]; } pk;
    #pragma unroll
    for (int hhalf = 0; hhalf < 2; ++hhalf) {
        #pragma unroll
        for (int c = 0; c < 8; ++c)
            pk.bh[c] = __float2bfloat16(ls[r][ck * 16 + hhalf * 8 + c]);
        *reinterpret_cast<short8*>(&ubt[((size_t)(b * 256 + hd0 + r)) * 128 + ck * 16 + hhalf * 8]) = pk.s8;
    }
}

// ---------------- K1 (MFMA): S = h·v^T + uwb, row stats, col-stat partials ---
__global__ __launch_bounds__(256) void k_Smfma(const float* __restrict__ h,
                                               const float* __restrict__ u,
                                               const void* __restrict__ u_mask,
                                               const void* __restrict__ h_mask,
                                               const float* __restrict__ w,
                                               float* __restrict__ ws) {
    __shared__ __align__(16) short lh[64 * 32];
    __shared__ __align__(16) short lv[128 * 32];
    __shared__ float uwb_l[128], um_l[128], hm_l[64];
    __shared__ float credm[4][128], creds[4][128];

    int b  = blockIdx.x;
    int i0 = blockIdx.y * 64;
    int t  = threadIdx.x;
    int flag = reinterpret_cast<const int*>(ws)[FLAG_OFF];
    int wave = t >> 6, lane = t & 63;
    int lj = lane & 15, lq = lane >> 4;

    if (t < 128) {
        uwb_l[t] = ws[UWB_OFF + b * LUU + t];
        um_l[t]  = mval(u_mask, b * LUU + t, flag);
    } else if (t < 192) {
        hm_l[t - 128] = mval(h_mask, b * LHH + i0 + (t - 128), flag);
    }

    int hrow = t >> 2,  hc = t & 3,  hlc = hc ^ swz(hrow);
    int vrow0 = t >> 2, vc0 = t & 3, vlc0 = vc0 ^ swz(vrow0);
    int vrow1 = (t + 256) >> 2, vc1 = t & 3, vlc1 = vc1 ^ swz(vrow1);
    const float* hsrc = h + ((size_t)(b * LHH + i0 + hrow)) * HDD + hlc * 8;
    const float* us0  = u + ((size_t)(b * LUU + vrow0)) * HDD + vlc0 * 8;
    const float* us1  = u + ((size_t)(b * LUU + vrow1)) * HDD + vlc1 * 8;

    int arow = wave * 16 + lj;
    int a_idx = arow * 32 + ((lq ^ swz(arow)) * 8);
    int b_idx[8];
    #pragma unroll
    for (int n = 0; n < 8; ++n) {
        int j = n * 16 + lj;
        b_idx[n] = j * 32 + ((lq ^ swz(j)) * 8);
    }

    f32x4 acc[8];
    #pragma unroll
    for (int n = 0; n < 8; ++n) acc[n] = (f32x4){0.f, 0.f, 0.f, 0.f};

    for (int step = 0; step < 8; ++step) {
        int k0 = step * 32;
        if (step) __syncthreads();
        {
            float4 f0 = *reinterpret_cast<const float4*>(hsrc + k0);
            float4 f1 = *reinterpret_cast<const float4*>(hsrc + k0 + 4);
            union { short8 s8; __hip_bfloat16 bh[8]; } pk;
            pk.bh[0]=__float2bfloat16(f0.x); pk.bh[1]=__float2bfloat16(f0.y);
            pk.bh[2]=__float2bfloat16(f0.z); pk.bh[3]=__float2bfloat16(f0.w);
            pk.bh[4]=__float2bfloat16(f1.x); pk.bh[5]=__float2bfloat16(f1.y);
            pk.bh[6]=__float2bfloat16(f1.z); pk.bh[7]=__float2bfloat16(f1.w);
            *reinterpret_cast<short8*>(&lh[hrow * 32 + hc * 8]) = pk.s8;
        }
        #pragma unroll
        for (int p = 0; p < 2; ++p) {
            const float* usrc = p ? us1 : us0;
            int vlc = p ? vlc1 : vlc0;
            int vrow = p ? vrow1 : vrow0;
            int vc = p ? vc1 : vc0;
            float4 uu0 = *reinterpret_cast<const float4*>(usrc + k0);
            float4 uu1 = *reinterpret_cast<const float4*>(usrc + k0 + 4);
            float4 wh0 = *reinterpret_cast<const float4*>(w + k0 + vlc * 8);
            float4 wh1 = *reinterpret_cast<const float4*>(w + k0 + vlc * 8 + 4);
            float4 wu0 = *reinterpret_cast<const float4*>(w + 2 * HDD + k0 + vlc * 8);
            float4 wu1 = *reinterpret_cast<const float4*>(w + 2 * HDD + k0 + vlc * 8 + 4);
            union { short8 s8; __hip_bfloat16 bh[8]; } pk;
            pk.bh[0]=__float2bfloat16(wh0.x + wu0.x * uu0.x);
            pk.bh[1]=__float2bfloat16(wh0.y + wu0.y * uu0.y);
            pk.bh[2]=__float2bfloat16(wh0.z + wu0.z * uu0.z);
            pk.bh[3]=__float2bfloat16(wh0.w + wu0.w * uu0.w);
            pk.bh[4]=__float2bfloat16(wh1.x + wu1.x * uu1.x);
            pk.bh[5]=__float2bfloat16(wh1.y + wu1.y * uu1.y);
            pk.bh[6]=__float2bfloat16(wh1.z + wu1.z * uu1.z);
            pk.bh[7]=__float2bfloat16(wh1.w + wu1.w * uu1.w);
            *reinterpret_cast<short8*>(&lv[vrow * 32 + vc * 8]) = pk.s8;
        }
        __syncthreads();
        short8 af = *reinterpret_cast<const short8*>(&lh[a_idx]);
        #pragma unroll
        for (int n = 0; n < 8; ++n) {
            short8 bf = *reinterpret_cast<const short8*>(&lv[b_idx[n]]);
            acc[n] = __builtin_amdgcn_mfma_f32_16x16x32_bf16(af, bf, acc[n], 0, 0, 0);
        }
    }

    // ---- epilogue 1: add uwb, row stats over 128 j, write S f32 ----
    float sv[8][4];
    #pragma unroll
    for (int n = 0; n < 8; ++n) {
        float uw = uwb_l[n * 16 + lj];
        #pragma unroll
        for (int q = 0; q < 4; ++q) sv[n][q] = acc[n][q] + uw;
    }
    float umv[8];
    #pragma unroll
    for (int n = 0; n < 8; ++n) umv[n] = um_l[n * 16 + lj];

    #pragma unroll
    for (int q = 0; q < 4; ++q) {
        float ms = NEGF;
        #pragma unroll
        for (int n = 0; n < 8; ++n) ms = fmaxf(ms, umv[n] > 0.f ? sv[n][q] : NEGF);
        #pragma unroll
        for (int off = 8; off; off >>= 1) ms = fmaxf(ms, __shfl_xor(ms, off));
        float e = 0.f;
        #pragma unroll
        for (int n = 0; n < 8; ++n) e += umv[n] * cexpf(sv[n][q] - ms);
        #pragma unroll
        for (int off = 8; off; off >>= 1) e += __shfl_xor(e, off);
        int i = i0 + wave * 16 + lq * 4 + q;
        float* Srow = ws + S_OFF + ((size_t)(b * LHH + i)) * LUU;
        #pragma unroll
        for (int n = 0; n < 8; ++n) Srow[n * 16 + lj] = sv[n][q];
        if (lj == 0) {
            ws[RM_OFF + b * LHH + i] = ms;
            ws[RI_OFF + b * LHH + i] = grcp(e);
        }
    }

    // ---- epilogue 2: col-stat partials over this block's 64 i-rows ----
    float hmq[4];
    #pragma unroll
    for (int q = 0; q < 4; ++q) hmq[q] = hm_l[wave * 16 + lq * 4 + q];
    #pragma unroll
    for (int n = 0; n < 8; ++n) {
        float cmx = NEGF, csx = 0.f;
        #pragma unroll
        for (int q = 0; q < 4; ++q) {
            if (hmq[q] > 0.f) {
                float x  = sv[n][q];
                float mn = fmaxf(cmx, x);
                csx = csx * cexpf(cmx - mn) + cexpf(x - mn);
                cmx = mn;
            }
        }
        #pragma unroll
        for (int off = 16; off <= 32; off <<= 1) {
            float om = __shfl_xor(cmx, off);
            float os = __shfl_xor(csx, off);
            float mn = fmaxf(cmx, om);
            csx = csx * cexpf(cmx - mn) + os * cexpf(om - mn);
            cmx = mn;
        }
        if (lq == 0) { credm[wave][n * 16 + lj] = cmx; creds[wave][n * 16 + lj] = csx; }
    }
    __syncthreads();
    if (t < 128) {
        float m = credm[0][t], s = creds[0][t];
        #pragma unroll
        for (int wv = 1; wv < 4; ++wv) {
            float om = credm[wv][t], os = creds[wv][t];
            float mn = fmaxf(m, om);
            s = s * cexpf(m - mn) + os * cexpf(om - mn);
            m = mn;
        }
        ws[PM_OFF + (b * 16 + blockIdx.y) * LUU + t] = m;
        ws[PS_OFF + (b * 16 + blockIdx.y) * LUU + t] = s;
    }
}

// ---------------- K3 (MFMA): C^T[hd][u] = sum_i h[i,hd]·a_t[i,u] -> bf16 -----
// grid (B, 2 hd-halves, 2 u-halves). Per step of 32 i: stage h^T (128x32) and
// a_t^T (64x32, exp from S+stats in-flight) into swizzled LDS; 8 MFMA/wave.
// Also folds col-stat combine (CM/CI) into the (y==0,z==0) block per batch.
__global__ __launch_bounds__(256) void k_Cmfma(const float* __restrict__ h,
                                               const void* __restrict__ u_mask,
                                               float* __restrict__ ws) {
    __shared__ __align__(16) short lha[128 * 32];   // 8 KB  h^T tile
    __shared__ __align__(16) short lsa[64 * 32];    // 4 KB  a_t^T tile
    int b = blockIdx.x, hd0 = blockIdx.y * 128, u0 = blockIdx.z * 64;
    int t = threadIdx.x;
    int flag = reinterpret_cast<const int*>(ws)[FLAG_OFF];

    if (blockIdx.y == 0 && blockIdx.z == 0 && t < 128) {   // folded colcomb
        int j = t;
        float m = NEGF;
        #pragma unroll
        for (int c = 0; c < 16; ++c) m = fmaxf(m, ws[PM_OFF + (b * 16 + c) * LUU + j]);
        float s = 0.f;
        #pragma unroll
        for (int c = 0; c < 16; ++c)
            s += ws[PS_OFF + (b * 16 + c) * LUU + j] * cexpf(ws[PM_OFF + (b * 16 + c) * LUU + j] - m);
        ws[CM_OFF + b * LUU + j] = m;
        ws[CI_OFF + b * LUU + j] = grcp(s);
    }

    int wave = t >> 6, lane = t & 63, lj = lane & 15, lq = lane >> 4;
    int hd_r = t & 127, ah = t >> 7;           // A staging: row, chunk-pair select
    int u_r = t & 63, bc = t >> 6;             // B staging: row, chunk
    float umr = mval(u_mask, b * LUU + u0 + u_r, flag);
    const float* hbp = h + (size_t)b * LHH * HDD + hd0 + hd_r;
    const float* Sbp = ws + S_OFF + (size_t)b * LHH * LUU + u0 + u_r;
    const float* rm = ws + RM_OFF + b * LHH;
    const float* ri = ws + RI_OFF + b * LHH;

    int a_idx[2], b_idx[4];
    #pragma unroll
    for (int m = 0; m < 2; ++m) {
        int row = wave * 32 + m * 16 + lj;
        a_idx[m] = row * 32 + ((lq ^ swz(row)) * 8);
    }
    #pragma unroll
    for (int n = 0; n < 4; ++n) {
        int row = n * 16 + lj;
        b_idx[n] = row * 32 + ((lq ^ swz(row)) * 8);
    }

    f32x4 acc[2][4];
    #pragma unroll
    for (int m = 0; m < 2; ++m)
        #pragma unroll
        for (int n = 0; n < 4; ++n) acc[m][n] = (f32x4){0.f, 0.f, 0.f, 0.f};

    for (int step = 0; step < 32; ++step) {
        int i0 = step * 32;
        if (step) __syncthreads();
        #pragma unroll
        for (int cc = 0; cc < 2; ++cc) {       // stage h^T: 2 chunks/thread
            int c = ah * 2 + cc, p = c ^ swz(hd_r);
            union { short8 s8; __hip_bfloat16 bh[8]; } pk;
            #pragma unroll
            for (int e = 0; e < 8; ++e)
                pk.bh[e] = __float2bfloat16(hbp[(size_t)(i0 + c * 8 + e) * HDD]);
            *reinterpret_cast<short8*>(&lha[hd_r * 32 + p * 8]) = pk.s8;
        }
        {                                       // stage a_t^T: 1 chunk/thread
            int c = bc, p = c ^ swz(u_r);
            union { short8 s8; __hip_bfloat16 bh[8]; } pk;
            #pragma unroll
            for (int e = 0; e < 8; ++e) {
                int i = i0 + c * 8 + e;
                float sva = Sbp[(size_t)i * LUU];
                pk.bh[e] = __float2bfloat16(umr * cexpf(sva - rm[i]) * ri[i]);
            }
            *reinterpret_cast<short8*>(&lsa[u_r * 32 + p * 8]) = pk.s8;
        }
        __syncthreads();
        short8 af0 = *reinterpret_cast<const short8*>(&lha[a_idx[0]]);
        short8 af1 = *reinterpret_cast<const short8*>(&lha[a_idx[1]]);
        #pragma unroll
        for (int n = 0; n < 4; ++n) {
            short8 bf = *reinterpret_cast<const short8*>(&lsa[b_idx[n]]);
            acc[0][n] = __builtin_amdgcn_mfma_f32_16x16x32_bf16(af0, bf, acc[0][n], 0, 0, 0);
            acc[1][n] = __builtin_amdgcn_mfma_f32_16x16x32_bf16(af1, bf, acc[1][n], 0, 0, 0);
        }
    }

    __hip_bfloat16* cbt = reinterpret_cast<__hip_bfloat16*>(ws + CBT_OFF);
    #pragma unroll
    for (int m = 0; m < 2; ++m)
        #pragma unroll
        for (int q = 0; q < 4; ++q) {
            int hd = hd0 + wave * 32 + m * 16 + lq * 4 + q;
            #pragma unroll
            for (int n = 0; n < 4; ++n) {
                int uu = u0 + n * 16 + lj;
                cbt[(size_t)(b * 256 + hd) * 128 + uu] = __float2bfloat16(acc[m][n][q]);
            }
        }
}

// ---------------- K4 (MFMA): U=a_t·u, H=b_t·C, concat output ----------------
__global__ __launch_bounds__(256) void k_outm(const float* __restrict__ h,
                                              const void* __restrict__ h_mask,
                                              const void* __restrict__ u_mask,
                                              const float* __restrict__ ws,
                                              float* __restrict__ out) {
    __shared__ __align__(16) short la[64 * 32], lb[64 * 32];
    __shared__ __align__(16) short lu[128 * 32], lc[128 * 32];
    __shared__ float rm_l[64], ri_l[64], hm_l[64];
    __shared__ float cm_l[128], ci_l[128], um_l[128];

    int b = blockIdx.x, i0 = blockIdx.y * 64, hd0 = blockIdx.z * 128;
    int t = threadIdx.x;
    int flag = reinterpret_cast<const int*>(ws)[FLAG_OFF];
    int wave = t >> 6, lane = t & 63, lj = lane & 15, lq = lane >> 4;

    if (t < 64) {
        rm_l[t] = ws[RM_OFF + b * LHH + i0 + t];
        ri_l[t] = ws[RI_OFF + b * LHH + i0 + t];
        hm_l[t] = mval(h_mask, b * LHH + i0 + t, flag);
    } else if (t < 192) {
        int j = t - 64;
        cm_l[j] = ws[CM_OFF + b * LUU + j];
        ci_l[j] = ws[CI_OFF + b * LUU + j];
        um_l[j] = mval(u_mask, b * LUU + j, flag);
    }

    const short* ubt = reinterpret_cast<const short*>(ws + UBT_OFF) + ((size_t)(b * 256 + hd0)) * 128;
    const short* cbt = reinterpret_cast<const short*>(ws + CBT_OFF) + ((size_t)(b * 256 + hd0)) * 128;

    int air = t >> 2, ap = t & 3;
    int brow = t >> 1;
    int a_idx = (wave * 16 + lj) * 32 + ((lq ^ swz(wave * 16 + lj)) * 8);
    int b_idx[8];
    #pragma unroll
    for (int n = 0; n < 8; ++n) {
        int r = n * 16 + lj;
        b_idx[n] = r * 32 + ((lq ^ swz(r)) * 8);
    }

    f32x4 aU[8], aH[8];
    #pragma unroll
    for (int n = 0; n < 8; ++n) { aU[n] = (f32x4){0,0,0,0}; aH[n] = (f32x4){0,0,0,0}; }

    for (int step = 0; step < 4; ++step) {
        int j0 = step * 32;
        __syncthreads();
        {
            int lgc = ap ^ swz(air);
            const float* Sp = ws + S_OFF + ((size_t)(b * LHH + i0 + air)) * LUU + j0 + lgc * 8;
            float4 s0 = *reinterpret_cast<const float4*>(Sp);
            float4 s1 = *reinterpret_cast<const float4*>(Sp + 4);
            float rmv = rm_l[air], riv = ri_l[air], hmv = hm_l[air];
            float sv[8] = {s0.x, s0.y, s0.z, s0.w, s1.x, s1.y, s1.z, s1.w};
            union { short8 s8; __hip_bfloat16 bh[8]; } pa, pb;
            #pragma unroll
            for (int c = 0; c < 8; ++c) {
                int j = j0 + lgc * 8 + c;
                pa.bh[c] = __float2bfloat16(um_l[j] * cexpf(sv[c] - rmv) * riv);
                pb.bh[c] = __float2bfloat16(hmv * cexpf(sv[c] - cm_l[j]) * ci_l[j]);
            }
            *reinterpret_cast<short8*>(&la[air * 32 + ap * 8]) = pa.s8;
            *reinterpret_cast<short8*>(&lb[air * 32 + ap * 8]) = pb.s8;
        }
        #pragma unroll
        for (int pp = 0; pp < 2; ++pp) {
            int p = (t & 1) * 2 + pp;
            int lgc = p ^ swz(brow);
            *reinterpret_cast<short8*>(&lu[brow * 32 + p * 8]) =
                *reinterpret_cast<const short8*>(ubt + (size_t)brow * 128 + j0 + lgc * 8);
            *reinterpret_cast<short8*>(&lc[brow * 32 + p * 8]) =
                *reinterpret_cast<const short8*>(cbt + (size_t)brow * 128 + j0 + lgc * 8);
        }
        __syncthreads();
        short8 fa = *reinterpret_cast<const short8*>(&la[a_idx]);
        short8 fb = *reinterpret_cast<const short8*>(&lb[a_idx]);
        #pragma unroll
        for (int n = 0; n < 8; ++n) {
            short8 gu = *reinterpret_cast<const short8*>(&lu[b_idx[n]]);
            short8 gc = *reinterpret_cast<const short8*>(&lc[b_idx[n]]);
            aU[n] = __builtin_amdgcn_mfma_f32_16x16x32_bf16(fa, gu, aU[n], 0, 0, 0);
            aH[n] = __builtin_amdgcn_mfma_f32_16x16x32_bf16(fb, gc, aH[n], 0, 0, 0);
        }
    }

    #pragma unroll
    for (int n = 0; n < 8; ++n) {
        int hd = hd0 + n * 16 + lj;
        #pragma unroll
        for (int q = 0; q < 4; ++q) {
            int i = i0 + wave * 16 + lq * 4 + q;
            float hv = h[((size_t)(b * LHH + i)) * HDD + hd];
            size_t base = ((size_t)(b * LHH + i)) * (4 * HDD) + hd;
            float Uv = aU[n][q], Hv = aH[n][q];
            out[base]           = hv;
            out[base + HDD]     = Uv;
            out[base + 2 * HDD] = hv * Uv;
            out[base + 3 * HDD] = hv * Hv;
        }
    }
}

extern "C" void kernel_launch(void* const* d_in, const int* in_sizes, int n_in,
                              void* d_out, int out_size, void* d_ws, size_t ws_size,
                              hipStream_t stream) {
    const float* h = (const float*)d_in[0];
    const float* u = (const float*)d_in[1];
    const void*  h_mask = d_in[2];
    const void*  u_mask = d_in[3];
    const float* w    = (const float*)d_in[4];
    const float* bias = (const float*)d_in[5];
    float* ws  = (float*)d_ws;
    float* out = (float*)d_out;

    if (ws_size < WS_FLOATS * sizeof(float)) return;  // diagnostic: leaves out zeroed

    k_uwb<<<dim3(BB * LUU / 4), 256, 0, stream>>>(u, w, bias, (const unsigned char*)h_mask, ws);
    k_uT<<<dim3(BB, HDD / 32), 256, 0, stream>>>(u, ws);
    k_Smfma<<<dim3(BB, LHH / 64), 256, 0, stream>>>(h, u, u_mask, h_mask, w, ws);
    k_Cmfma<<<dim3(BB, 2, 2), 256, 0, stream>>>(h, u_mask, ws);
    k_outm<<<dim3(BB, LHH / 64, 2), 256, 0, stream>>>(h, h_mask, u_mask, ws, out);
}

// Round 10
// 87.352 us; speedup vs baseline: 11.0323x; 1.0961x over previous
//
#include <hip/hip_runtime.h>
#include <hip/hip_bf16.h>

#define BB  32
#define LHH 1024
#define LUU 128
#define HDD 256
#define NEGF (-1e30f)

typedef __attribute__((ext_vector_type(8))) short short8;
typedef __attribute__((ext_vector_type(4))) short short4v;
typedef __attribute__((ext_vector_type(4))) float f32x4;

// ---- workspace layout (float offsets) ----
static constexpr size_t P_OFF    = 0;                            // bf16 [B][LH][LU] P=exp(S-rm)
static constexpr size_t UWB_OFF  = P_OFF + (size_t)BB*LHH*LUU/2; // [B][LU]
static constexpr size_t RM_OFF   = UWB_OFF + (size_t)BB*LUU;     // [B][LH] row max
static constexpr size_t RI_OFF   = RM_OFF + (size_t)BB*LHH;      // [B][LH] 1/row sum
static constexpr size_t PM_OFF   = RI_OFF + (size_t)BB*LHH;      // [B][16][LU] col-max partials
static constexpr size_t PS_OFF   = PM_OFF + (size_t)BB*16*LUU;   // [B][16][LU] col-sum partials
static constexpr size_t CM_OFF   = PS_OFF + (size_t)BB*16*LUU;   // [B][LU] col max
static constexpr size_t CI_OFF   = CM_OFF + (size_t)BB*LUU;      // [B][LU] 1/col sum
static constexpr size_t UBT_OFF  = CI_OFF + (size_t)BB*LUU;      // bf16 [B][HD][LU] u^T
static constexpr size_t CBT_OFF  = UBT_OFF + (size_t)BB*HDD*LUU/2; // bf16 [B][HD][LU] C^T
static constexpr size_t VBF_OFF  = CBT_OFF + (size_t)BB*HDD*LUU/2; // bf16 [B][LU][HD] v
static constexpr size_t FLAG_OFF = VBF_OFF + (size_t)BB*LUU*HDD/2; // 1 int
static constexpr size_t WS_FLOATS= FLAG_OFF + 1;

__device__ __forceinline__ float mval(const void* p, int idx, int flag) {
    if (flag) return ((const unsigned char*)p)[idx] ? 1.0f : 0.0f;
    return (((const int*)p)[idx] != 0) ? 1.0f : 0.0f;
}
__device__ __forceinline__ float cexpf(float x) { return __expf(fminf(x, 60.0f)); }
__device__ __forceinline__ float grcp(float x)  { return 1.0f / fmaxf(x, 1e-38f); }
__device__ __forceinline__ int swz(int r) { return (r ^ (r >> 2)) & 3; }
__device__ __forceinline__ float b2f(short v) {
    return __uint_as_float(((unsigned)(unsigned short)v) << 16);
}
__device__ __forceinline__ short f2b(float x) {
    __hip_bfloat16 h = __float2bfloat16(x);
    return *reinterpret_cast<short*>(&h);
}

// ---- K0: uwb = u·w_u + bias; v_bf = bf16(w_h + w_hu*u); mask dtype flag ----
__global__ __launch_bounds__(256) void k_prep(const float* __restrict__ u,
                                              const float* __restrict__ w,
                                              const float* __restrict__ bias,
                                              const unsigned char* __restrict__ hm,
                                              float* __restrict__ ws) {
    if (blockIdx.x == 0 && threadIdx.x == 0)
        reinterpret_cast<int*>(ws)[FLAG_OFF] = (hm[1] != 0) ? 1 : 0;
    int wave = threadIdx.x >> 6;
    int lane = threadIdx.x & 63;
    int idx  = blockIdx.x * 4 + wave;          // b*LU + j
    int b = idx >> 7, j = idx & 127;
    float4 uu   = reinterpret_cast<const float4*>(u + ((size_t)(b * LUU + j)) * HDD)[lane];
    float4 whv  = reinterpret_cast<const float4*>(w)[lane];
    float4 wuv  = reinterpret_cast<const float4*>(w + HDD)[lane];
    float4 whuv = reinterpret_cast<const float4*>(w + 2 * HDD)[lane];
    float s = uu.x * wuv.x + uu.y * wuv.y + uu.z * wuv.z + uu.w * wuv.w;
    #pragma unroll
    for (int off = 32; off; off >>= 1) s += __shfl_xor(s, off);
    if (lane == 0) ws[UWB_OFF + idx] = s + bias[0];
    union { short4v s4; __hip_bfloat16 bh[4]; } pk;
    pk.bh[0] = __float2bfloat16(whv.x + whuv.x * uu.x);
    pk.bh[1] = __float2bfloat16(whv.y + whuv.y * uu.y);
    pk.bh[2] = __float2bfloat16(whv.z + whuv.z * uu.z);
    pk.bh[3] = __float2bfloat16(whv.w + whuv.w * uu.w);
    short* vbf = reinterpret_cast<short*>(ws + VBF_OFF);
    *reinterpret_cast<short4v*>(&vbf[((size_t)(b * LUU + j)) * HDD + lane * 4]) = pk.s4;
}

// ---------------- K0b: u_bfT[b][hd][j] = bf16(u[b][j][hd]) ----------------
__global__ __launch_bounds__(256) void k_uT(const float* __restrict__ u,
                                            float* __restrict__ ws) {
    __shared__ float ls[32][132];
    int b = blockIdx.x, hd0 = blockIdx.y * 32;
    int t = threadIdx.x;
    int hc = t & 7, jj = t >> 3;
    #pragma unroll
    for (int pass = 0; pass < 4; ++pass) {
        int j = jj + pass * 32;
        float4 v = *reinterpret_cast<const float4*>(u + ((size_t)(b * LUU + j)) * HDD + hd0 + hc * 4);
        ls[hc * 4 + 0][j] = v.x; ls[hc * 4 + 1][j] = v.y;
        ls[hc * 4 + 2][j] = v.z; ls[hc * 4 + 3][j] = v.w;
    }
    __syncthreads();
    int r = t >> 3, ck = t & 7;                // row hd0+r, j chunk of 16
    short* ubt = reinterpret_cast<short*>(ws + UBT_OFF);
    union { short8 s8; __hip_bfloat16 bh[8]; } pk;
    #pragma unroll
    for (int hhalf = 0; hhalf < 2; ++hhalf) {
        #pragma unroll
        for (int c = 0; c < 8; ++c)
            pk.bh[c] = __float2bfloat16(ls[r][ck * 16 + hhalf * 8 + c]);
        *reinterpret_cast<short8*>(&ubt[((size_t)(b * 256 + hd0 + r)) * 128 + ck * 16 + hhalf * 8]) = pk.s8;
    }
}

// -------- K1 (MFMA): S = h·v^T + uwb; write P bf16; row stats; col partials --
__global__ __launch_bounds__(256) void k_Smfma(const float* __restrict__ h,
                                               const void* __restrict__ u_mask,
                                               const void* __restrict__ h_mask,
                                               float* __restrict__ ws) {
    __shared__ __align__(16) short lh[64 * 32];
    __shared__ __align__(16) short lv[128 * 32];
    __shared__ float uwb_l[128], um_l[128], hm_l[64];
    __shared__ float credm[4][128], creds[4][128];

    int b  = blockIdx.x;
    int i0 = blockIdx.y * 64;
    int t  = threadIdx.x;
    int flag = reinterpret_cast<const int*>(ws)[FLAG_OFF];
    int wave = t >> 6, lane = t & 63;
    int lj = lane & 15, lq = lane >> 4;

    if (t < 128) {
        uwb_l[t] = ws[UWB_OFF + b * LUU + t];
        um_l[t]  = mval(u_mask, b * LUU + t, flag);
    } else if (t < 192) {
        hm_l[t - 128] = mval(h_mask, b * LHH + i0 + (t - 128), flag);
    }

    int hrow = t >> 2,  hc = t & 3,  hlc = hc ^ swz(hrow);
    int vrow0 = t >> 2, vc0 = t & 3, vlc0 = vc0 ^ swz(vrow0);
    int vrow1 = (t + 256) >> 2, vc1 = t & 3, vlc1 = vc1 ^ swz(vrow1);
    const float* hsrc = h + ((size_t)(b * LHH + i0 + hrow)) * HDD + hlc * 8;
    const short* vbf  = reinterpret_cast<const short*>(ws + VBF_OFF);
    const short* vsrc0 = vbf + ((size_t)(b * LUU + vrow0)) * HDD + vlc0 * 8;
    const short* vsrc1 = vbf + ((size_t)(b * LUU + vrow1)) * HDD + vlc1 * 8;

    int arow = wave * 16 + lj;
    int a_idx = arow * 32 + ((lq ^ swz(arow)) * 8);
    int b_idx[8];
    #pragma unroll
    for (int n = 0; n < 8; ++n) {
        int j = n * 16 + lj;
        b_idx[n] = j * 32 + ((lq ^ swz(j)) * 8);
    }

    f32x4 acc[8];
    #pragma unroll
    for (int n = 0; n < 8; ++n) acc[n] = (f32x4){0.f, 0.f, 0.f, 0.f};

    for (int step = 0; step < 8; ++step) {
        int k0 = step * 32;
        if (step) __syncthreads();
        {
            float4 f0 = *reinterpret_cast<const float4*>(hsrc + k0);
            float4 f1 = *reinterpret_cast<const float4*>(hsrc + k0 + 4);
            union { short8 s8; __hip_bfloat16 bh[8]; } pk;
            pk.bh[0]=__float2bfloat16(f0.x); pk.bh[1]=__float2bfloat16(f0.y);
            pk.bh[2]=__float2bfloat16(f0.z); pk.bh[3]=__float2bfloat16(f0.w);
            pk.bh[4]=__float2bfloat16(f1.x); pk.bh[5]=__float2bfloat16(f1.y);
            pk.bh[6]=__float2bfloat16(f1.z); pk.bh[7]=__float2bfloat16(f1.w);
            *reinterpret_cast<short8*>(&lh[hrow * 32 + hc * 8]) = pk.s8;
        }
        *reinterpret_cast<short8*>(&lv[vrow0 * 32 + vc0 * 8]) =
            *reinterpret_cast<const short8*>(vsrc0 + k0);
        *reinterpret_cast<short8*>(&lv[vrow1 * 32 + vc1 * 8]) =
            *reinterpret_cast<const short8*>(vsrc1 + k0);
        __syncthreads();
        short8 af = *reinterpret_cast<const short8*>(&lh[a_idx]);
        #pragma unroll
        for (int n = 0; n < 8; ++n) {
            short8 bf = *reinterpret_cast<const short8*>(&lv[b_idx[n]]);
            acc[n] = __builtin_amdgcn_mfma_f32_16x16x32_bf16(af, bf, acc[n], 0, 0, 0);
        }
    }

    // ---- epilogue 1: add uwb, row stats, write P = bf16(exp(S - rm)) ----
    float sv[8][4];
    #pragma unroll
    for (int n = 0; n < 8; ++n) {
        float uw = uwb_l[n * 16 + lj];
        #pragma unroll
        for (int q = 0; q < 4; ++q) sv[n][q] = acc[n][q] + uw;
    }
    float umv[8];
    #pragma unroll
    for (int n = 0; n < 8; ++n) umv[n] = um_l[n * 16 + lj];

    short* Pg = reinterpret_cast<short*>(ws + P_OFF);
    #pragma unroll
    for (int q = 0; q < 4; ++q) {
        float ms = NEGF;
        #pragma unroll
        for (int n = 0; n < 8; ++n) ms = fmaxf(ms, umv[n] > 0.f ? sv[n][q] : NEGF);
        #pragma unroll
        for (int off = 8; off; off >>= 1) ms = fmaxf(ms, __shfl_xor(ms, off));
        float pe[8], e = 0.f;
        #pragma unroll
        for (int n = 0; n < 8; ++n) { pe[n] = cexpf(sv[n][q] - ms); e += umv[n] * pe[n]; }
        #pragma unroll
        for (int off = 8; off; off >>= 1) e += __shfl_xor(e, off);
        int i = i0 + wave * 16 + lq * 4 + q;
        short* Prow = Pg + ((size_t)(b * LHH + i)) * LUU;
        #pragma unroll
        for (int n = 0; n < 8; ++n) Prow[n * 16 + lj] = f2b(pe[n]);
        if (lj == 0) {
            ws[RM_OFF + b * LHH + i] = ms;
            ws[RI_OFF + b * LHH + i] = grcp(e);
        }
    }

    // ---- epilogue 2: col-stat partials over this block's 64 i-rows ----
    float hmq[4];
    #pragma unroll
    for (int q = 0; q < 4; ++q) hmq[q] = hm_l[wave * 16 + lq * 4 + q];
    #pragma unroll
    for (int n = 0; n < 8; ++n) {
        float cmx = NEGF, csx = 0.f;
        #pragma unroll
        for (int q = 0; q < 4; ++q) {
            if (hmq[q] > 0.f) {
                float x  = sv[n][q];
                float mn = fmaxf(cmx, x);
                csx = csx * cexpf(cmx - mn) + cexpf(x - mn);
                cmx = mn;
            }
        }
        #pragma unroll
        for (int off = 16; off <= 32; off <<= 1) {
            float om = __shfl_xor(cmx, off);
            float os = __shfl_xor(csx, off);
            float mn = fmaxf(cmx, om);
            csx = csx * cexpf(cmx - mn) + os * cexpf(om - mn);
            cmx = mn;
        }
        if (lq == 0) { credm[wave][n * 16 + lj] = cmx; creds[wave][n * 16 + lj] = csx; }
    }
    __syncthreads();
    if (t < 128) {
        float m = credm[0][t], s = creds[0][t];
        #pragma unroll
        for (int wv = 1; wv < 4; ++wv) {
            float om = credm[wv][t], os = creds[wv][t];
            float mn = fmaxf(m, om);
            s = s * cexpf(m - mn) + os * cexpf(om - mn);
            m = mn;
        }
        ws[PM_OFF + (b * 16 + blockIdx.y) * LUU + t] = m;
        ws[PS_OFF + (b * 16 + blockIdx.y) * LUU + t] = s;
    }
}

// ---- K3 (MFMA): C^T[hd][u] = um_u · Σ_i h[i,hd]·(P[i,u]·ri_i) -> bf16 ------
__global__ __launch_bounds__(256) void k_Cmfma(const float* __restrict__ h,
                                               const void* __restrict__ u_mask,
                                               float* __restrict__ ws) {
    __shared__ __align__(16) short lha[128 * 32];   // h^T tile
    __shared__ __align__(16) short lsa[64 * 32];    // (P·ri)^T tile
    __shared__ float um_s[64];
    int b = blockIdx.x, hd0 = blockIdx.y * 128, u0 = blockIdx.z * 64;
    int t = threadIdx.x;
    int flag = reinterpret_cast<const int*>(ws)[FLAG_OFF];

    if (t < 64) um_s[t] = mval(u_mask, b * LUU + u0 + t, flag);

    if (blockIdx.y == 0 && blockIdx.z == 0 && t >= 64 && t < 192) {  // folded colcomb
        int j = t - 64;
        float m = NEGF;
        #pragma unroll
        for (int c = 0; c < 16; ++c) m = fmaxf(m, ws[PM_OFF + (b * 16 + c) * LUU + j]);
        float s = 0.f;
        #pragma unroll
        for (int c = 0; c < 16; ++c)
            s += ws[PS_OFF + (b * 16 + c) * LUU + j] * cexpf(ws[PM_OFF + (b * 16 + c) * LUU + j] - m);
        ws[CM_OFF + b * LUU + j] = m;
        ws[CI_OFF + b * LUU + j] = grcp(s);
    }

    int wave = t >> 6, lane = t & 63, lj = lane & 15, lq = lane >> 4;
    int hd_r = t & 127, ah = t >> 7;           // A staging: row, chunk-pair select
    int u_r = t & 63, bc = t >> 6;             // B staging: row, chunk
    const float* hbp = h + (size_t)b * LHH * HDD + hd0 + hd_r;
    const short* Pbp = reinterpret_cast<const short*>(ws + P_OFF) + (size_t)b * LHH * LUU + u0 + u_r;
    const float* ri = ws + RI_OFF + b * LHH;

    int a_idx[2], b_idx[4];
    #pragma unroll
    for (int m = 0; m < 2; ++m) {
        int row = wave * 32 + m * 16 + lj;
        a_idx[m] = row * 32 + ((lq ^ swz(row)) * 8);
    }
    #pragma unroll
    for (int n = 0; n < 4; ++n) {
        int row = n * 16 + lj;
        b_idx[n] = row * 32 + ((lq ^ swz(row)) * 8);
    }

    f32x4 acc[2][4];
    #pragma unroll
    for (int m = 0; m < 2; ++m)
        #pragma unroll
        for (int n = 0; n < 4; ++n) acc[m][n] = (f32x4){0.f, 0.f, 0.f, 0.f};

    for (int step = 0; step < 32; ++step) {
        int i0 = step * 32;
        if (step) __syncthreads();
        #pragma unroll
        for (int cc = 0; cc < 2; ++cc) {       // stage h^T: 2 chunks/thread
            int c = ah * 2 + cc, p = c ^ swz(hd_r);
            union { short8 s8; __hip_bfloat16 bh[8]; } pk;
            #pragma unroll
            for (int e = 0; e < 8; ++e)
                pk.bh[e] = __float2bfloat16(hbp[(size_t)(i0 + c * 8 + e) * HDD]);
            *reinterpret_cast<short8*>(&lha[hd_r * 32 + p * 8]) = pk.s8;
        }
        {                                       // stage (P·ri)^T: 1 chunk/thread
            int c = bc, p = c ^ swz(u_r);
            union { short8 s8; __hip_bfloat16 bh[8]; } pk;
            #pragma unroll
            for (int e = 0; e < 8; ++e) {
                int i = i0 + c * 8 + e;
                float pv = b2f(Pbp[(size_t)i * LUU]);
                pk.bh[e] = __float2bfloat16(pv * ri[i]);
            }
            *reinterpret_cast<short8*>(&lsa[u_r * 32 + p * 8]) = pk.s8;
        }
        __syncthreads();
        short8 af0 = *reinterpret_cast<const short8*>(&lha[a_idx[0]]);
        short8 af1 = *reinterpret_cast<const short8*>(&lha[a_idx[1]]);
        #pragma unroll
        for (int n = 0; n < 4; ++n) {
            short8 bf = *reinterpret_cast<const short8*>(&lsa[b_idx[n]]);
            acc[0][n] = __builtin_amdgcn_mfma_f32_16x16x32_bf16(af0, bf, acc[0][n], 0, 0, 0);
            acc[1][n] = __builtin_amdgcn_mfma_f32_16x16x32_bf16(af1, bf, acc[1][n], 0, 0, 0);
        }
    }

    __hip_bfloat16* cbt = reinterpret_cast<__hip_bfloat16*>(ws + CBT_OFF);
    #pragma unroll
    for (int m = 0; m < 2; ++m)
        #pragma unroll
        for (int q = 0; q < 4; ++q) {
            int hd = hd0 + wave * 32 + m * 16 + lq * 4 + q;
            #pragma unroll
            for (int n = 0; n < 4; ++n) {
                int uu = n * 16 + lj;
                cbt[(size_t)(b * 256 + hd) * 128 + u0 + uu] =
                    __float2bfloat16(acc[m][n][q] * um_s[uu]);
            }
        }
}

// ---------------- K4 (MFMA): U=a_t·u, H=b_t·C, concat output ----------------
// a_t = um_j·P·ri_i ; b_t = P·(hm_i·e^{rm_i})·(e^{-cm_j}·ci_j)  — no exps in loop
__global__ __launch_bounds__(256) void k_outm(const float* __restrict__ h,
                                              const void* __restrict__ h_mask,
                                              const void* __restrict__ u_mask,
                                              const float* __restrict__ ws,
                                              float* __restrict__ out) {
    __shared__ __align__(16) short la[64 * 32], lb[64 * 32];
    __shared__ __align__(16) short lu[128 * 32], lc[128 * 32];
    __shared__ float ri_l[64], R_l[64];
    __shared__ float um_l[128], Cc_l[128];

    int b = blockIdx.x, i0 = blockIdx.y * 64, hd0 = blockIdx.z * 128;
    int t = threadIdx.x;
    int flag = reinterpret_cast<const int*>(ws)[FLAG_OFF];
    int wave = t >> 6, lane = t & 63, lj = lane & 15, lq = lane >> 4;

    if (t < 64) {
        float rmv = ws[RM_OFF + b * LHH + i0 + t];
        ri_l[t] = ws[RI_OFF + b * LHH + i0 + t];
        R_l[t]  = mval(h_mask, b * LHH + i0 + t, flag) * cexpf(rmv);
    } else if (t < 192) {
        int j = t - 64;
        float cmv = ws[CM_OFF + b * LUU + j];
        Cc_l[j] = cexpf(-cmv) * ws[CI_OFF + b * LUU + j];
        um_l[j] = mval(u_mask, b * LUU + j, flag);
    }

    const short* Pbase = reinterpret_cast<const short*>(ws + P_OFF) + (size_t)b * LHH * LUU;
    const short* ubt = reinterpret_cast<const short*>(ws + UBT_OFF) + ((size_t)(b * 256 + hd0)) * 128;
    const short* cbt = reinterpret_cast<const short*>(ws + CBT_OFF) + ((size_t)(b * 256 + hd0)) * 128;

    int air = t >> 2, ap = t & 3;
    int brow = t >> 1;
    int a_idx = (wave * 16 + lj) * 32 + ((lq ^ swz(wave * 16 + lj)) * 8);
    int b_idx[8];
    #pragma unroll
    for (int n = 0; n < 8; ++n) {
        int r = n * 16 + lj;
        b_idx[n] = r * 32 + ((lq ^ swz(r)) * 8);
    }

    f32x4 aU[8], aH[8];
    #pragma unroll
    for (int n = 0; n < 8; ++n) { aU[n] = (f32x4){0,0,0,0}; aH[n] = (f32x4){0,0,0,0}; }

    for (int step = 0; step < 4; ++step) {
        int j0 = step * 32;
        __syncthreads();
        {
            int lgc = ap ^ swz(air);
            short8 pv8 = *reinterpret_cast<const short8*>(
                Pbase + (size_t)(i0 + air) * LUU + j0 + lgc * 8);
            float riv = ri_l[air], Rv = R_l[air];
            union { short8 s8; __hip_bfloat16 bh[8]; } pa, pb;
            #pragma unroll
            for (int c = 0; c < 8; ++c) {
                int j = j0 + lgc * 8 + c;
                float p = b2f(pv8[c]);
                pa.bh[c] = __float2bfloat16(p * um_l[j] * riv);
                pb.bh[c] = __float2bfloat16(p * Rv * Cc_l[j]);
            }
            *reinterpret_cast<short8*>(&la[air * 32 + ap * 8]) = pa.s8;
            *reinterpret_cast<short8*>(&lb[air * 32 + ap * 8]) = pb.s8;
        }
        #pragma unroll
        for (int pp = 0; pp < 2; ++pp) {
            int p = (t & 1) * 2 + pp;
            int lgc = p ^ swz(brow);
            *reinterpret_cast<short8*>(&lu[brow * 32 + p * 8]) =
                *reinterpret_cast<const short8*>(ubt + (size_t)brow * 128 + j0 + lgc * 8);
            *reinterpret_cast<short8*>(&lc[brow * 32 + p * 8]) =
                *reinterpret_cast<const short8*>(cbt + (size_t)brow * 128 + j0 + lgc * 8);
        }
        __syncthreads();
        short8 fa = *reinterpret_cast<const short8*>(&la[a_idx]);
        short8 fb = *reinterpret_cast<const short8*>(&lb[a_idx]);
        #pragma unroll
        for (int n = 0; n < 8; ++n) {
            short8 gu = *reinterpret_cast<const short8*>(&lu[b_idx[n]]);
            short8 gc = *reinterpret_cast<const short8*>(&lc[b_idx[n]]);
            aU[n] = __builtin_amdgcn_mfma_f32_16x16x32_bf16(fa, gu, aU[n], 0, 0, 0);
            aH[n] = __builtin_amdgcn_mfma_f32_16x16x32_bf16(fb, gc, aH[n], 0, 0, 0);
        }
    }

    #pragma unroll
    for (int n = 0; n < 8; ++n) {
        int hd = hd0 + n * 16 + lj;
        #pragma unroll
        for (int q = 0; q < 4; ++q) {
            int i = i0 + wave * 16 + lq * 4 + q;
            float hv = h[((size_t)(b * LHH + i)) * HDD + hd];
            size_t base = ((size_t)(b * LHH + i)) * (4 * HDD) + hd;
            float Uv = aU[n][q], Hv = aH[n][q];
            out[base]           = hv;
            out[base + HDD]     = Uv;
            out[base + 2 * HDD] = hv * Uv;
            out[base + 3 * HDD] = hv * Hv;
        }
    }
}

extern "C" void kernel_launch(void* const* d_in, const int* in_sizes, int n_in,
                              void* d_out, int out_size, void* d_ws, size_t ws_size,
                              hipStream_t stream) {
    const float* h = (const float*)d_in[0];
    const float* u = (const float*)d_in[1];
    const void*  h_mask = d_in[2];
    const void*  u_mask = d_in[3];
    const float* w    = (const float*)d_in[4];
    const float* bias = (const float*)d_in[5];
    float* ws  = (float*)d_ws;
    float* out = (float*)d_out;

    if (ws_size < WS_FLOATS * sizeof(float)) return;  // diagnostic: leaves out zeroed

    k_prep<<<dim3(BB * LUU / 4), 256, 0, stream>>>(u, w, bias, (const unsigned char*)h_mask, ws);
    k_uT<<<dim3(BB, HDD / 32), 256, 0, stream>>>(u, ws);
    k_Smfma<<<dim3(BB, LHH / 64), 256, 0, stream>>>(h, u_mask, h_mask, ws);
    k_Cmfma<<<dim3(BB, 2, 2), 256, 0, stream>>>(h, u_mask, ws);
    k_outm<<<dim3(BB, LHH / 64, 2), 256, 0, stream>>>(h, h_mask, u_mask, ws, out);
}

// Round 11
// 84.754 us; speedup vs baseline: 11.3706x; 1.0307x over previous
//
#include <hip/hip_runtime.h>
#include <hip/hip_bf16.h>

#define BB  32
#define LHH 1024
#define LUU 128
#define HDD 256
#define NEGF (-1e30f)

typedef __attribute__((ext_vector_type(8))) short short8;
typedef __attribute__((ext_vector_type(4))) short short4v;
typedef __attribute__((ext_vector_type(4))) float f32x4;

// ---- workspace layout (float offsets) ----
static constexpr size_t P_OFF    = 0;                            // bf16 [B][LH][LU] P=exp(S-rm)
static constexpr size_t UWBP_OFF = P_OFF + (size_t)BB*LHH*LUU/2; // [B][8][LU] uwb partials
static constexpr size_t RM_OFF   = UWBP_OFF + (size_t)BB*8*LUU;  // [B][LH] row max
static constexpr size_t RI_OFF   = RM_OFF + (size_t)BB*LHH;      // [B][LH] 1/row sum
static constexpr size_t PM_OFF   = RI_OFF + (size_t)BB*LHH;      // [B][16][LU] col-max partials
static constexpr size_t PS_OFF   = PM_OFF + (size_t)BB*16*LUU;   // [B][16][LU] col-sum partials
static constexpr size_t CM_OFF   = PS_OFF + (size_t)BB*16*LUU;   // [B][LU] col max
static constexpr size_t CI_OFF   = CM_OFF + (size_t)BB*LUU;      // [B][LU] 1/col sum
static constexpr size_t UBT_OFF  = CI_OFF + (size_t)BB*LUU;      // bf16 [B][HD][LU] u^T
static constexpr size_t CBT_OFF  = UBT_OFF + (size_t)BB*HDD*LUU/2; // bf16 [B][HD][LU] C^T
static constexpr size_t VBF_OFF  = CBT_OFF + (size_t)BB*HDD*LUU/2; // bf16 [B][LU][HD] v
static constexpr size_t FLAG_OFF = VBF_OFF + (size_t)BB*LUU*HDD/2; // 1 int
static constexpr size_t WS_FLOATS= FLAG_OFF + 1;

__device__ __forceinline__ float mval(const void* p, int idx, int flag) {
    if (flag) return ((const unsigned char*)p)[idx] ? 1.0f : 0.0f;
    return (((const int*)p)[idx] != 0) ? 1.0f : 0.0f;
}
__device__ __forceinline__ float cexpf(float x) { return __expf(fminf(x, 60.0f)); }
__device__ __forceinline__ float grcp(float x)  { return 1.0f / fmaxf(x, 1e-38f); }
__device__ __forceinline__ int swz(int r) { return (r ^ (r >> 2)) & 3; }
__device__ __forceinline__ float b2f(short v) {
    return __uint_as_float(((unsigned)(unsigned short)v) << 16);
}
__device__ __forceinline__ short f2b(float x) {
    __hip_bfloat16 h = __float2bfloat16(x);
    return *reinterpret_cast<short*>(&h);
}

// ---- K0 (fused): reads u ONCE -> ubt (bf16 u^T), vbf (bf16 v), uwb partials, flag
__global__ __launch_bounds__(256) void k_prep(const float* __restrict__ u,
                                              const float* __restrict__ w,
                                              const unsigned char* __restrict__ hm,
                                              float* __restrict__ ws) {
    __shared__ float ls[32][132];
    int b = blockIdx.x, hd0 = blockIdx.y * 32;
    int t = threadIdx.x;
    if (blockIdx.x == 0 && blockIdx.y == 0 && t == 0)
        reinterpret_cast<int*>(ws)[FLAG_OFF] = (hm[1] != 0) ? 1 : 0;
    int hc = t & 7, jj = t >> 3;
    float4 whv  = *reinterpret_cast<const float4*>(w + hd0 + hc * 4);
    float4 wuv  = *reinterpret_cast<const float4*>(w + HDD + hd0 + hc * 4);
    float4 whuv = *reinterpret_cast<const float4*>(w + 2 * HDD + hd0 + hc * 4);
    short* vbf = reinterpret_cast<short*>(ws + VBF_OFF);
    #pragma unroll
    for (int pass = 0; pass < 4; ++pass) {
        int j = jj + pass * 32;
        float4 v = *reinterpret_cast<const float4*>(u + ((size_t)(b * LUU + j)) * HDD + hd0 + hc * 4);
        ls[hc * 4 + 0][j] = v.x; ls[hc * 4 + 1][j] = v.y;
        ls[hc * 4 + 2][j] = v.z; ls[hc * 4 + 3][j] = v.w;
        // v = bf16(w_h + w_hu * u)
        union { short4v s4; __hip_bfloat16 bh[4]; } pv;
        pv.bh[0] = __float2bfloat16(whv.x + whuv.x * v.x);
        pv.bh[1] = __float2bfloat16(whv.y + whuv.y * v.y);
        pv.bh[2] = __float2bfloat16(whv.z + whuv.z * v.z);
        pv.bh[3] = __float2bfloat16(whv.w + whuv.w * v.w);
        *reinterpret_cast<short4v*>(&vbf[((size_t)(b * LUU + j)) * HDD + hd0 + hc * 4]) = pv.s4;
        // uwb partial over this 32-hd chunk (8-lane group reduce)
        float s = v.x * wuv.x + v.y * wuv.y + v.z * wuv.z + v.w * wuv.w;
        s += __shfl_xor(s, 1); s += __shfl_xor(s, 2); s += __shfl_xor(s, 4);
        if (hc == 0) ws[UWBP_OFF + (b * 8 + blockIdx.y) * LUU + j] = s;
    }
    __syncthreads();
    int r = t >> 3, ck = t & 7;                // row hd0+r, j chunk of 16
    short* ubt = reinterpret_cast<short*>(ws + UBT_OFF);
    union { short8 s8; __hip_bfloat16 bh[8]; } pk;
    #pragma unroll
    for (int hhalf = 0; hhalf < 2; ++hhalf) {
        #pragma unroll
        for (int c = 0; c < 8; ++c)
            pk.bh[c] = __float2bfloat16(ls[r][ck * 16 + hhalf * 8 + c]);
        *reinterpret_cast<short8*>(&ubt[((size_t)(b * 256 + hd0 + r)) * 128 + ck * 16 + hhalf * 8]) = pk.s8;
    }
}

// -------- K1 (MFMA): S = h·v^T + uwb; write P bf16; row stats; col partials --
__global__ __launch_bounds__(256) void k_Smfma(const float* __restrict__ h,
                                               const void* __restrict__ u_mask,
                                               const void* __restrict__ h_mask,
                                               const float* __restrict__ bias,
                                               float* __restrict__ ws) {
    __shared__ __align__(16) short lh[64 * 32];
    __shared__ __align__(16) short lv[128 * 32];
    __shared__ float uwb_l[128], um_l[128], hm_l[64];
    __shared__ float credm[4][128], creds[4][128];

    int b  = blockIdx.x;
    int i0 = blockIdx.y * 64;
    int t  = threadIdx.x;
    int flag = reinterpret_cast<const int*>(ws)[FLAG_OFF];
    int wave = t >> 6, lane = t & 63;
    int lj = lane & 15, lq = lane >> 4;

    if (t < 128) {
        float s = bias[0];
        #pragma unroll
        for (int c = 0; c < 8; ++c) s += ws[UWBP_OFF + (b * 8 + c) * LUU + t];
        uwb_l[t] = s;
        um_l[t]  = mval(u_mask, b * LUU + t, flag);
    } else if (t < 192) {
        hm_l[t - 128] = mval(h_mask, b * LHH + i0 + (t - 128), flag);
    }

    int hrow = t >> 2,  hc = t & 3,  hlc = hc ^ swz(hrow);
    int vrow0 = t >> 2, vc0 = t & 3, vlc0 = vc0 ^ swz(vrow0);
    int vrow1 = (t + 256) >> 2, vc1 = t & 3, vlc1 = vc1 ^ swz(vrow1);
    const float* hsrc = h + ((size_t)(b * LHH + i0 + hrow)) * HDD + hlc * 8;
    const short* vbf  = reinterpret_cast<const short*>(ws + VBF_OFF);
    const short* vsrc0 = vbf + ((size_t)(b * LUU + vrow0)) * HDD + vlc0 * 8;
    const short* vsrc1 = vbf + ((size_t)(b * LUU + vrow1)) * HDD + vlc1 * 8;

    int arow = wave * 16 + lj;
    int a_idx = arow * 32 + ((lq ^ swz(arow)) * 8);
    int b_idx[8];
    #pragma unroll
    for (int n = 0; n < 8; ++n) {
        int j = n * 16 + lj;
        b_idx[n] = j * 32 + ((lq ^ swz(j)) * 8);
    }

    f32x4 acc[8];
    #pragma unroll
    for (int n = 0; n < 8; ++n) acc[n] = (f32x4){0.f, 0.f, 0.f, 0.f};

    for (int step = 0; step < 8; ++step) {
        int k0 = step * 32;
        if (step) __syncthreads();
        {
            float4 f0 = *reinterpret_cast<const float4*>(hsrc + k0);
            float4 f1 = *reinterpret_cast<const float4*>(hsrc + k0 + 4);
            union { short8 s8; __hip_bfloat16 bh[8]; } pk;
            pk.bh[0]=__float2bfloat16(f0.x); pk.bh[1]=__float2bfloat16(f0.y);
            pk.bh[2]=__float2bfloat16(f0.z); pk.bh[3]=__float2bfloat16(f0.w);
            pk.bh[4]=__float2bfloat16(f1.x); pk.bh[5]=__float2bfloat16(f1.y);
            pk.bh[6]=__float2bfloat16(f1.z); pk.bh[7]=__float2bfloat16(f1.w);
            *reinterpret_cast<short8*>(&lh[hrow * 32 + hc * 8]) = pk.s8;
        }
        *reinterpret_cast<short8*>(&lv[vrow0 * 32 + vc0 * 8]) =
            *reinterpret_cast<const short8*>(vsrc0 + k0);
        *reinterpret_cast<short8*>(&lv[vrow1 * 32 + vc1 * 8]) =
            *reinterpret_cast<const short8*>(vsrc1 + k0);
        __syncthreads();
        short8 af = *reinterpret_cast<const short8*>(&lh[a_idx]);
        #pragma unroll
        for (int n = 0; n < 8; ++n) {
            short8 bf = *reinterpret_cast<const short8*>(&lv[b_idx[n]]);
            acc[n] = __builtin_amdgcn_mfma_f32_16x16x32_bf16(af, bf, acc[n], 0, 0, 0);
        }
    }

    // ---- epilogue 1: add uwb, row stats, write P = bf16(exp(S - rm)) ----
    float sv[8][4];
    #pragma unroll
    for (int n = 0; n < 8; ++n) {
        float uw = uwb_l[n * 16 + lj];
        #pragma unroll
        for (int q = 0; q < 4; ++q) sv[n][q] = acc[n][q] + uw;
    }
    float umv[8];
    #pragma unroll
    for (int n = 0; n < 8; ++n) umv[n] = um_l[n * 16 + lj];

    short* Pg = reinterpret_cast<short*>(ws + P_OFF);
    #pragma unroll
    for (int q = 0; q < 4; ++q) {
        float ms = NEGF;
        #pragma unroll
        for (int n = 0; n < 8; ++n) ms = fmaxf(ms, umv[n] > 0.f ? sv[n][q] : NEGF);
        #pragma unroll
        for (int off = 8; off; off >>= 1) ms = fmaxf(ms, __shfl_xor(ms, off));
        float pe[8], e = 0.f;
        #pragma unroll
        for (int n = 0; n < 8; ++n) { pe[n] = cexpf(sv[n][q] - ms); e += umv[n] * pe[n]; }
        #pragma unroll
        for (int off = 8; off; off >>= 1) e += __shfl_xor(e, off);
        int i = i0 + wave * 16 + lq * 4 + q;
        short* Prow = Pg + ((size_t)(b * LHH + i)) * LUU;
        #pragma unroll
        for (int n = 0; n < 8; ++n) Prow[n * 16 + lj] = f2b(pe[n]);
        if (lj == 0) {
            ws[RM_OFF + b * LHH + i] = ms;
            ws[RI_OFF + b * LHH + i] = grcp(e);
        }
    }

    // ---- epilogue 2: col-stat partials over this block's 64 i-rows ----
    float hmq[4];
    #pragma unroll
    for (int q = 0; q < 4; ++q) hmq[q] = hm_l[wave * 16 + lq * 4 + q];
    #pragma unroll
    for (int n = 0; n < 8; ++n) {
        float cmx = NEGF, csx = 0.f;
        #pragma unroll
        for (int q = 0; q < 4; ++q) {
            if (hmq[q] > 0.f) {
                float x  = sv[n][q];
                float mn = fmaxf(cmx, x);
                csx = csx * cexpf(cmx - mn) + cexpf(x - mn);
                cmx = mn;
            }
        }
        #pragma unroll
        for (int off = 16; off <= 32; off <<= 1) {
            float om = __shfl_xor(cmx, off);
            float os = __shfl_xor(csx, off);
            float mn = fmaxf(cmx, om);
            csx = csx * cexpf(cmx - mn) + os * cexpf(om - mn);
            cmx = mn;
        }
        if (lq == 0) { credm[wave][n * 16 + lj] = cmx; creds[wave][n * 16 + lj] = csx; }
    }
    __syncthreads();
    if (t < 128) {
        float m = credm[0][t], s = creds[0][t];
        #pragma unroll
        for (int wv = 1; wv < 4; ++wv) {
            float om = credm[wv][t], os = creds[wv][t];
            float mn = fmaxf(m, om);
            s = s * cexpf(m - mn) + os * cexpf(om - mn);
            m = mn;
        }
        ws[PM_OFF + (b * 16 + blockIdx.y) * LUU + t] = m;
        ws[PS_OFF + (b * 16 + blockIdx.y) * LUU + t] = s;
    }
}

// ---- K3 (MFMA): C^T[hd][u] = um_u · Σ_i h[i,hd]·(P[i,u]·ri_i) -> bf16 ------
__global__ __launch_bounds__(256) void k_Cmfma(const float* __restrict__ h,
                                               const void* __restrict__ u_mask,
                                               float* __restrict__ ws) {
    __shared__ __align__(16) short lha[128 * 32];   // h^T tile
    __shared__ __align__(16) short lsa[64 * 32];    // (P·ri)^T tile
    __shared__ float um_s[64];
    int b = blockIdx.x, hd0 = blockIdx.y * 128, u0 = blockIdx.z * 64;
    int t = threadIdx.x;
    int flag = reinterpret_cast<const int*>(ws)[FLAG_OFF];

    if (t < 64) um_s[t] = mval(u_mask, b * LUU + u0 + t, flag);

    if (blockIdx.y == 0 && blockIdx.z == 0 && t >= 64 && t < 192) {  // folded colcomb
        int j = t - 64;
        float m = NEGF;
        #pragma unroll
        for (int c = 0; c < 16; ++c) m = fmaxf(m, ws[PM_OFF + (b * 16 + c) * LUU + j]);
        float s = 0.f;
        #pragma unroll
        for (int c = 0; c < 16; ++c)
            s += ws[PS_OFF + (b * 16 + c) * LUU + j] * cexpf(ws[PM_OFF + (b * 16 + c) * LUU + j] - m);
        ws[CM_OFF + b * LUU + j] = m;
        ws[CI_OFF + b * LUU + j] = grcp(s);
    }

    int wave = t >> 6, lane = t & 63, lj = lane & 15, lq = lane >> 4;
    int hd_r = t & 127, ah = t >> 7;           // A staging: row, chunk-pair select
    int u_r = t & 63, bc = t >> 6;             // B staging: row, chunk
    const float* hbp = h + (size_t)b * LHH * HDD + hd0 + hd_r;
    const short* Pbp = reinterpret_cast<const short*>(ws + P_OFF) + (size_t)b * LHH * LUU + u0 + u_r;
    const float* ri = ws + RI_OFF + b * LHH;

    int a_idx[2], b_idx[4];
    #pragma unroll
    for (int m = 0; m < 2; ++m) {
        int row = wave * 32 + m * 16 + lj;
        a_idx[m] = row * 32 + ((lq ^ swz(row)) * 8);
    }
    #pragma unroll
    for (int n = 0; n < 4; ++n) {
        int row = n * 16 + lj;
        b_idx[n] = row * 32 + ((lq ^ swz(row)) * 8);
    }

    f32x4 acc[2][4];
    #pragma unroll
    for (int m = 0; m < 2; ++m)
        #pragma unroll
        for (int n = 0; n < 4; ++n) acc[m][n] = (f32x4){0.f, 0.f, 0.f, 0.f};

    for (int step = 0; step < 32; ++step) {
        int i0 = step * 32;
        if (step) __syncthreads();
        #pragma unroll
        for (int cc = 0; cc < 2; ++cc) {       // stage h^T: 2 chunks/thread
            int c = ah * 2 + cc, p = c ^ swz(hd_r);
            union { short8 s8; __hip_bfloat16 bh[8]; } pk;
            #pragma unroll
            for (int e = 0; e < 8; ++e)
                pk.bh[e] = __float2bfloat16(hbp[(size_t)(i0 + c * 8 + e) * HDD]);
            *reinterpret_cast<short8*>(&lha[hd_r * 32 + p * 8]) = pk.s8;
        }
        {                                       // stage (P·ri)^T: 1 chunk/thread
            int c = bc, p = c ^ swz(u_r);
            union { short8 s8; __hip_bfloat16 bh[8]; } pk;
            #pragma unroll
            for (int e = 0; e < 8; ++e) {
                int i = i0 + c * 8 + e;
                float pv = b2f(Pbp[(size_t)i * LUU]);
                pk.bh[e] = __float2bfloat16(pv * ri[i]);
            }
            *reinterpret_cast<short8*>(&lsa[u_r * 32 + p * 8]) = pk.s8;
        }
        __syncthreads();
        short8 af0 = *reinterpret_cast<const short8*>(&lha[a_idx[0]]);
        short8 af1 = *reinterpret_cast<const short8*>(&lha[a_idx[1]]);
        #pragma unroll
        for (int n = 0; n < 4; ++n) {
            short8 bf = *reinterpret_cast<const short8*>(&lsa[b_idx[n]]);
            acc[0][n] = __builtin_amdgcn_mfma_f32_16x16x32_bf16(af0, bf, acc[0][n], 0, 0, 0);
            acc[1][n] = __builtin_amdgcn_mfma_f32_16x16x32_bf16(af1, bf, acc[1][n], 0, 0, 0);
        }
    }

    __hip_bfloat16* cbt = reinterpret_cast<__hip_bfloat16*>(ws + CBT_OFF);
    #pragma unroll
    for (int m = 0; m < 2; ++m)
        #pragma unroll
        for (int q = 0; q < 4; ++q) {
            int hd = hd0 + wave * 32 + m * 16 + lq * 4 + q;
            #pragma unroll
            for (int n = 0; n < 4; ++n) {
                int uu = n * 16 + lj;
                cbt[(size_t)(b * 256 + hd) * 128 + u0 + uu] =
                    __float2bfloat16(acc[m][n][q] * um_s[uu]);
            }
        }
}

// ---------------- K4 (MFMA): U=a_t·u, H=b_t·C, concat output ----------------
__global__ __launch_bounds__(256) void k_outm(const float* __restrict__ h,
                                              const void* __restrict__ h_mask,
                                              const void* __restrict__ u_mask,
                                              const float* __restrict__ ws,
                                              float* __restrict__ out) {
    __shared__ __align__(16) short la[64 * 32], lb[64 * 32];
    __shared__ __align__(16) short lu[128 * 32], lc[128 * 32];
    __shared__ float ri_l[64], R_l[64];
    __shared__ float um_l[128], Cc_l[128];

    int b = blockIdx.x, i0 = blockIdx.y * 64, hd0 = blockIdx.z * 128;
    int t = threadIdx.x;
    int flag = reinterpret_cast<const int*>(ws)[FLAG_OFF];
    int wave = t >> 6, lane = t & 63, lj = lane & 15, lq = lane >> 4;

    if (t < 64) {
        float rmv = ws[RM_OFF + b * LHH + i0 + t];
        ri_l[t] = ws[RI_OFF + b * LHH + i0 + t];
        R_l[t]  = mval(h_mask, b * LHH + i0 + t, flag) * cexpf(rmv);
    } else if (t < 192) {
        int j = t - 64;
        float cmv = ws[CM_OFF + b * LUU + j];
        Cc_l[j] = cexpf(-cmv) * ws[CI_OFF + b * LUU + j];
        um_l[j] = mval(u_mask, b * LUU + j, flag);
    }

    const short* Pbase = reinterpret_cast<const short*>(ws + P_OFF) + (size_t)b * LHH * LUU;
    const short* ubt = reinterpret_cast<const short*>(ws + UBT_OFF) + ((size_t)(b * 256 + hd0)) * 128;
    const short* cbt = reinterpret_cast<const short*>(ws + CBT_OFF) + ((size_t)(b * 256 + hd0)) * 128;

    int air = t >> 2, ap = t & 3;
    int brow = t >> 1;
    int a_idx = (wave * 16 + lj) * 32 + ((lq ^ swz(wave * 16 + lj)) * 8);
    int b_idx[8];
    #pragma unroll
    for (int n = 0; n < 8; ++n) {
        int r = n * 16 + lj;
        b_idx[n] = r * 32 + ((lq ^ swz(r)) * 8);
    }

    f32x4 aU[8], aH[8];
    #pragma unroll
    for (int n = 0; n < 8; ++n) { aU[n] = (f32x4){0,0,0,0}; aH[n] = (f32x4){0,0,0,0}; }

    for (int step = 0; step < 4; ++step) {
        int j0 = step * 32;
        __syncthreads();
        {
            int lgc = ap ^ swz(air);
            short8 pv8 = *reinterpret_cast<const short8*>(
                Pbase + (size_t)(i0 + air) * LUU + j0 + lgc * 8);
            float riv = ri_l[air], Rv = R_l[air];
            union { short8 s8; __hip_bfloat16 bh[8]; } pa, pb;
            #pragma unroll
            for (int c = 0; c < 8; ++c) {
                int j = j0 + lgc * 8 + c;
                float p = b2f(pv8[c]);
                pa.bh[c] = __float2bfloat16(p * um_l[j] * riv);
                pb.bh[c] = __float2bfloat16(p * Rv * Cc_l[j]);
            }
            *reinterpret_cast<short8*>(&la[air * 32 + ap * 8]) = pa.s8;
            *reinterpret_cast<short8*>(&lb[air * 32 + ap * 8]) = pb.s8;
        }
        #pragma unroll
        for (int pp = 0; pp < 2; ++pp) {
            int p = (t & 1) * 2 + pp;
            int lgc = p ^ swz(brow);
            *reinterpret_cast<short8*>(&lu[brow * 32 + p * 8]) =
                *reinterpret_cast<const short8*>(ubt + (size_t)brow * 128 + j0 + lgc * 8);
            *reinterpret_cast<short8*>(&lc[brow * 32 + p * 8]) =
                *reinterpret_cast<const short8*>(cbt + (size_t)brow * 128 + j0 + lgc * 8);
        }
        __syncthreads();
        short8 fa = *reinterpret_cast<const short8*>(&la[a_idx]);
        short8 fb = *reinterpret_cast<const short8*>(&lb[a_idx]);
        #pragma unroll
        for (int n = 0; n < 8; ++n) {
            short8 gu = *reinterpret_cast<const short8*>(&lu[b_idx[n]]);
            short8 gc = *reinterpret_cast<const short8*>(&lc[b_idx[n]]);
            aU[n] = __builtin_amdgcn_mfma_f32_16x16x32_bf16(fa, gu, aU[n], 0, 0, 0);
            aH[n] = __builtin_amdgcn_mfma_f32_16x16x32_bf16(fb, gc, aH[n], 0, 0, 0);
        }
    }

    #pragma unroll
    for (int n = 0; n < 8; ++n) {
        int hd = hd0 + n * 16 + lj;
        #pragma unroll
        for (int q = 0; q < 4; ++q) {
            int i = i0 + wave * 16 + lq * 4 + q;
            float hv = h[((size_t)(b * LHH + i)) * HDD + hd];
            size_t base = ((size_t)(b * LHH + i)) * (4 * HDD) + hd;
            float Uv = aU[n][q], Hv = aH[n][q];
            out[base]           = hv;
            out[base + HDD]     = Uv;
            out[base + 2 * HDD] = hv * Uv;
            out[base + 3 * HDD] = hv * Hv;
        }
    }
}

extern "C" void kernel_launch(void* const* d_in, const int* in_sizes, int n_in,
                              void* d_out, int out_size, void* d_ws, size_t ws_size,
                              hipStream_t stream) {
    const float* h = (const float*)d_in[0];
    const float* u = (const float*)d_in[1];
    const void*  h_mask = d_in[2];
    const void*  u_mask = d_in[3];
    const float* w    = (const float*)d_in[4];
    const float* bias = (const float*)d_in[5];
    float* ws  = (float*)d_ws;
    float* out = (float*)d_out;

    if (ws_size < WS_FLOATS * sizeof(float)) return;  // diagnostic: leaves out zeroed

    k_prep<<<dim3(BB, HDD / 32), 256, 0, stream>>>(u, w, (const unsigned char*)h_mask, ws);
    k_Smfma<<<dim3(BB, LHH / 64), 256, 0, stream>>>(h, u_mask, h_mask, bias, ws);
    k_Cmfma<<<dim3(BB, 2, 2), 256, 0, stream>>>(h, u_mask, ws);
    k_outm<<<dim3(BB, LHH / 64, 2), 256, 0, stream>>>(h, h_mask, u_mask, ws, out);
}

// Round 12
// 84.250 us; speedup vs baseline: 11.4387x; 1.0060x over previous
//
#include <hip/hip_runtime.h>
#include <hip/hip_bf16.h>

#define BB  32
#define LHH 1024
#define LUU 128
#define HDD 256
#define NEGF (-1e30f)

typedef __attribute__((ext_vector_type(8))) short short8;
typedef __attribute__((ext_vector_type(4))) short short4v;
typedef __attribute__((ext_vector_type(4))) float f32x4;

// ---- workspace layout (float offsets) ----
static constexpr size_t P_OFF    = 0;                            // bf16 [B][LH][LU] P' = exp(S-rm)*ri
static constexpr size_t UWBP_OFF = P_OFF + (size_t)BB*LHH*LUU/2; // [B][8][LU] uwb partials
static constexpr size_t RM_OFF   = UWBP_OFF + (size_t)BB*8*LUU;  // [B][LH] row max
static constexpr size_t RI_OFF   = RM_OFF + (size_t)BB*LHH;      // [B][LH] 1/row sum
static constexpr size_t PM_OFF   = RI_OFF + (size_t)BB*LHH;      // [B][16][LU] col-max partials
static constexpr size_t PS_OFF   = PM_OFF + (size_t)BB*16*LUU;   // [B][16][LU] col-sum partials
static constexpr size_t CM_OFF   = PS_OFF + (size_t)BB*16*LUU;   // [B][LU] col max
static constexpr size_t CI_OFF   = CM_OFF + (size_t)BB*LUU;      // [B][LU] 1/col sum
static constexpr size_t UBT_OFF  = CI_OFF + (size_t)BB*LUU;      // bf16 [B][HD][LU] u^T
static constexpr size_t CBT_OFF  = UBT_OFF + (size_t)BB*HDD*LUU/2; // bf16 [B][HD][LU] C^T
static constexpr size_t VBF_OFF  = CBT_OFF + (size_t)BB*HDD*LUU/2; // bf16 [B][LU][HD] v
static constexpr size_t FLAG_OFF = VBF_OFF + (size_t)BB*LUU*HDD/2; // 1 int
static constexpr size_t WS_FLOATS= FLAG_OFF + 1;

__device__ __forceinline__ float mval(const void* p, int idx, int flag) {
    if (flag) return ((const unsigned char*)p)[idx] ? 1.0f : 0.0f;
    return (((const int*)p)[idx] != 0) ? 1.0f : 0.0f;
}
__device__ __forceinline__ float cexpf(float x) { return __expf(fminf(x, 60.0f)); }
__device__ __forceinline__ float grcp(float x)  { return 1.0f / fmaxf(x, 1e-38f); }
__device__ __forceinline__ int swz(int r) { return (r ^ (r >> 2)) & 3; }
__device__ __forceinline__ float b2f(short v) {
    return __uint_as_float(((unsigned)(unsigned short)v) << 16);
}
__device__ __forceinline__ short f2b(float x) {
    __hip_bfloat16 h = __float2bfloat16(x);
    return *reinterpret_cast<short*>(&h);
}

// ---- K0 (fused): reads u ONCE -> ubt (bf16 u^T), vbf (bf16 v), uwb partials, flag
__global__ __launch_bounds__(256) void k_prep(const float* __restrict__ u,
                                              const float* __restrict__ w,
                                              const unsigned char* __restrict__ hm,
                                              float* __restrict__ ws) {
    __shared__ float ls[32][132];
    int b = blockIdx.x, hd0 = blockIdx.y * 32;
    int t = threadIdx.x;
    if (blockIdx.x == 0 && blockIdx.y == 0 && t == 0)
        reinterpret_cast<int*>(ws)[FLAG_OFF] = (hm[1] != 0) ? 1 : 0;
    int hc = t & 7, jj = t >> 3;
    float4 whv  = *reinterpret_cast<const float4*>(w + hd0 + hc * 4);
    float4 wuv  = *reinterpret_cast<const float4*>(w + HDD + hd0 + hc * 4);
    float4 whuv = *reinterpret_cast<const float4*>(w + 2 * HDD + hd0 + hc * 4);
    short* vbf = reinterpret_cast<short*>(ws + VBF_OFF);
    #pragma unroll
    for (int pass = 0; pass < 4; ++pass) {
        int j = jj + pass * 32;
        float4 v = *reinterpret_cast<const float4*>(u + ((size_t)(b * LUU + j)) * HDD + hd0 + hc * 4);
        ls[hc * 4 + 0][j] = v.x; ls[hc * 4 + 1][j] = v.y;
        ls[hc * 4 + 2][j] = v.z; ls[hc * 4 + 3][j] = v.w;
        union { short4v s4; __hip_bfloat16 bh[4]; } pv;
        pv.bh[0] = __float2bfloat16(whv.x + whuv.x * v.x);
        pv.bh[1] = __float2bfloat16(whv.y + whuv.y * v.y);
        pv.bh[2] = __float2bfloat16(whv.z + whuv.z * v.z);
        pv.bh[3] = __float2bfloat16(whv.w + whuv.w * v.w);
        *reinterpret_cast<short4v*>(&vbf[((size_t)(b * LUU + j)) * HDD + hd0 + hc * 4]) = pv.s4;
        float s = v.x * wuv.x + v.y * wuv.y + v.z * wuv.z + v.w * wuv.w;
        s += __shfl_xor(s, 1); s += __shfl_xor(s, 2); s += __shfl_xor(s, 4);
        if (hc == 0) ws[UWBP_OFF + (b * 8 + blockIdx.y) * LUU + j] = s;
    }
    __syncthreads();
    int r = t >> 3, ck = t & 7;
    short* ubt = reinterpret_cast<short*>(ws + UBT_OFF);
    union { short8 s8; __hip_bfloat16 bh[8]; } pk;
    #pragma unroll
    for (int hhalf = 0; hhalf < 2; ++hhalf) {
        #pragma unroll
        for (int c = 0; c < 8; ++c)
            pk.bh[c] = __float2bfloat16(ls[r][ck * 16 + hhalf * 8 + c]);
        *reinterpret_cast<short8*>(&ubt[((size_t)(b * 256 + hd0 + r)) * 128 + ck * 16 + hhalf * 8]) = pk.s8;
    }
}

// -------- K1 (MFMA): S = h·v^T + uwb; write P' bf16; row stats; col partials --
__global__ __launch_bounds__(256) void k_Smfma(const float* __restrict__ h,
                                               const void* __restrict__ u_mask,
                                               const void* __restrict__ h_mask,
                                               const float* __restrict__ bias,
                                               float* __restrict__ ws) {
    __shared__ __align__(16) short lh[64 * 32];
    __shared__ __align__(16) short lv[128 * 32];
    __shared__ float uwb_l[128], um_l[128], hm_l[64];
    __shared__ float credm[4][128], creds[4][128];

    int b  = blockIdx.x;
    int i0 = blockIdx.y * 64;
    int t  = threadIdx.x;
    int flag = reinterpret_cast<const int*>(ws)[FLAG_OFF];
    int wave = t >> 6, lane = t & 63;
    int lj = lane & 15, lq = lane >> 4;

    if (t < 128) {
        float s = bias[0];
        #pragma unroll
        for (int c = 0; c < 8; ++c) s += ws[UWBP_OFF + (b * 8 + c) * LUU + t];
        uwb_l[t] = s;
        um_l[t]  = mval(u_mask, b * LUU + t, flag);
    } else if (t < 192) {
        hm_l[t - 128] = mval(h_mask, b * LHH + i0 + (t - 128), flag);
    }

    int hrow = t >> 2,  hc = t & 3,  hlc = hc ^ swz(hrow);
    int vrow0 = t >> 2, vc0 = t & 3, vlc0 = vc0 ^ swz(vrow0);
    int vrow1 = (t + 256) >> 2, vc1 = t & 3, vlc1 = vc1 ^ swz(vrow1);
    const float* hsrc = h + ((size_t)(b * LHH + i0 + hrow)) * HDD + hlc * 8;
    const short* vbf  = reinterpret_cast<const short*>(ws + VBF_OFF);
    const short* vsrc0 = vbf + ((size_t)(b * LUU + vrow0)) * HDD + vlc0 * 8;
    const short* vsrc1 = vbf + ((size_t)(b * LUU + vrow1)) * HDD + vlc1 * 8;

    int arow = wave * 16 + lj;
    int a_idx = arow * 32 + ((lq ^ swz(arow)) * 8);
    int b_idx[8];
    #pragma unroll
    for (int n = 0; n < 8; ++n) {
        int j = n * 16 + lj;
        b_idx[n] = j * 32 + ((lq ^ swz(j)) * 8);
    }

    f32x4 acc[8];
    #pragma unroll
    for (int n = 0; n < 8; ++n) acc[n] = (f32x4){0.f, 0.f, 0.f, 0.f};

    for (int step = 0; step < 8; ++step) {
        int k0 = step * 32;
        if (step) __syncthreads();
        {
            float4 f0 = *reinterpret_cast<const float4*>(hsrc + k0);
            float4 f1 = *reinterpret_cast<const float4*>(hsrc + k0 + 4);
            union { short8 s8; __hip_bfloat16 bh[8]; } pk;
            pk.bh[0]=__float2bfloat16(f0.x); pk.bh[1]=__float2bfloat16(f0.y);
            pk.bh[2]=__float2bfloat16(f0.z); pk.bh[3]=__float2bfloat16(f0.w);
            pk.bh[4]=__float2bfloat16(f1.x); pk.bh[5]=__float2bfloat16(f1.y);
            pk.bh[6]=__float2bfloat16(f1.z); pk.bh[7]=__float2bfloat16(f1.w);
            *reinterpret_cast<short8*>(&lh[hrow * 32 + hc * 8]) = pk.s8;
        }
        *reinterpret_cast<short8*>(&lv[vrow0 * 32 + vc0 * 8]) =
            *reinterpret_cast<const short8*>(vsrc0 + k0);
        *reinterpret_cast<short8*>(&lv[vrow1 * 32 + vc1 * 8]) =
            *reinterpret_cast<const short8*>(vsrc1 + k0);
        __syncthreads();
        short8 af = *reinterpret_cast<const short8*>(&lh[a_idx]);
        #pragma unroll
        for (int n = 0; n < 8; ++n) {
            short8 bf = *reinterpret_cast<const short8*>(&lv[b_idx[n]]);
            acc[n] = __builtin_amdgcn_mfma_f32_16x16x32_bf16(af, bf, acc[n], 0, 0, 0);
        }
    }

    // ---- epilogue 1: add uwb, row stats, write P' = bf16(exp(S-rm)*ri) ----
    float sv[8][4];
    #pragma unroll
    for (int n = 0; n < 8; ++n) {
        float uw = uwb_l[n * 16 + lj];
        #pragma unroll
        for (int q = 0; q < 4; ++q) sv[n][q] = acc[n][q] + uw;
    }
    float umv[8];
    #pragma unroll
    for (int n = 0; n < 8; ++n) umv[n] = um_l[n * 16 + lj];

    short* Pg = reinterpret_cast<short*>(ws + P_OFF);
    #pragma unroll
    for (int q = 0; q < 4; ++q) {
        float ms = NEGF;
        #pragma unroll
        for (int n = 0; n < 8; ++n) ms = fmaxf(ms, umv[n] > 0.f ? sv[n][q] : NEGF);
        #pragma unroll
        for (int off = 8; off; off >>= 1) ms = fmaxf(ms, __shfl_xor(ms, off));
        float pe[8], e = 0.f;
        #pragma unroll
        for (int n = 0; n < 8; ++n) { pe[n] = cexpf(sv[n][q] - ms); e += umv[n] * pe[n]; }
        #pragma unroll
        for (int off = 8; off; off >>= 1) e += __shfl_xor(e, off);
        float riv = grcp(e);
        int i = i0 + wave * 16 + lq * 4 + q;
        short* Prow = Pg + ((size_t)(b * LHH + i)) * LUU;
        #pragma unroll
        for (int n = 0; n < 8; ++n) Prow[n * 16 + lj] = f2b(pe[n] * riv);
        if (lj == 0) {
            ws[RM_OFF + b * LHH + i] = ms;
            ws[RI_OFF + b * LHH + i] = riv;
        }
    }

    // ---- epilogue 2: col-stat partials over this block's 64 i-rows ----
    float hmq[4];
    #pragma unroll
    for (int q = 0; q < 4; ++q) hmq[q] = hm_l[wave * 16 + lq * 4 + q];
    #pragma unroll
    for (int n = 0; n < 8; ++n) {
        float cmx = NEGF, csx = 0.f;
        #pragma unroll
        for (int q = 0; q < 4; ++q) {
            if (hmq[q] > 0.f) {
                float x  = sv[n][q];
                float mn = fmaxf(cmx, x);
                csx = csx * cexpf(cmx - mn) + cexpf(x - mn);
                cmx = mn;
            }
        }
        #pragma unroll
        for (int off = 16; off <= 32; off <<= 1) {
            float om = __shfl_xor(cmx, off);
            float os = __shfl_xor(csx, off);
            float mn = fmaxf(cmx, om);
            csx = csx * cexpf(cmx - mn) + os * cexpf(om - mn);
            cmx = mn;
        }
        if (lq == 0) { credm[wave][n * 16 + lj] = cmx; creds[wave][n * 16 + lj] = csx; }
    }
    __syncthreads();
    if (t < 128) {
        float m = credm[0][t], s = creds[0][t];
        #pragma unroll
        for (int wv = 1; wv < 4; ++wv) {
            float om = credm[wv][t], os = creds[wv][t];
            float mn = fmaxf(m, om);
            s = s * cexpf(m - mn) + os * cexpf(om - mn);
            m = mn;
        }
        ws[PM_OFF + (b * 16 + blockIdx.y) * LUU + t] = m;
        ws[PS_OFF + (b * 16 + blockIdx.y) * LUU + t] = s;
    }
}

// ---- K3 (MFMA): C^T[hd][u] = um_u · Σ_i h[i,hd]·P'[i,u] -> bf16 -------------
// grid (B, 4 hd-quarters, 2 u-halves) = 256 blocks (full machine).
__global__ __launch_bounds__(256) void k_Cmfma(const float* __restrict__ h,
                                               const void* __restrict__ u_mask,
                                               float* __restrict__ ws) {
    __shared__ __align__(16) short lha[64 * 32];    // h^T tile (64 hd x 32 i)
    __shared__ __align__(16) short lsa[64 * 32];    // P'^T tile (64 u x 32 i)
    __shared__ float um_s[64];
    int b = blockIdx.x, hd0 = blockIdx.y * 64, u0 = blockIdx.z * 64;
    int t = threadIdx.x;
    int flag = reinterpret_cast<const int*>(ws)[FLAG_OFF];

    if (t < 64) um_s[t] = mval(u_mask, b * LUU + u0 + t, flag);

    if (blockIdx.y == 0 && blockIdx.z == 0 && t >= 64 && t < 192) {  // folded colcomb
        int j = t - 64;
        float m = NEGF;
        #pragma unroll
        for (int c = 0; c < 16; ++c) m = fmaxf(m, ws[PM_OFF + (b * 16 + c) * LUU + j]);
        float s = 0.f;
        #pragma unroll
        for (int c = 0; c < 16; ++c)
            s += ws[PS_OFF + (b * 16 + c) * LUU + j] * cexpf(ws[PM_OFF + (b * 16 + c) * LUU + j] - m);
        ws[CM_OFF + b * LUU + j] = m;
        ws[CI_OFF + b * LUU + j] = grcp(s);
    }

    int wave = t >> 6, lane = t & 63, lj = lane & 15, lq = lane >> 4;
    int hd_r = t >> 2, ac = t & 3;             // A staging: row 0..63, chunk 0..3
    int u_r = t & 63, bc = t >> 6;             // B staging: row 0..63, chunk 0..3
    const float* hbp = h + (size_t)b * LHH * HDD + hd0 + hd_r;
    const short* Pbp = reinterpret_cast<const short*>(ws + P_OFF) + (size_t)b * LHH * LUU + u0 + u_r;

    int arow = wave * 16 + lj;
    int a_idx = arow * 32 + ((lq ^ swz(arow)) * 8);
    int b_idx[4];
    #pragma unroll
    for (int n = 0; n < 4; ++n) {
        int row = n * 16 + lj;
        b_idx[n] = row * 32 + ((lq ^ swz(row)) * 8);
    }

    f32x4 acc[4];
    #pragma unroll
    for (int n = 0; n < 4; ++n) acc[n] = (f32x4){0.f, 0.f, 0.f, 0.f};

    for (int step = 0; step < 32; ++step) {
        int i0 = step * 32;
        if (step) __syncthreads();
        {                                       // stage h^T: 1 chunk/thread
            int p = ac ^ swz(hd_r);
            union { short8 s8; __hip_bfloat16 bh[8]; } pk;
            #pragma unroll
            for (int e = 0; e < 8; ++e)
                pk.bh[e] = __float2bfloat16(hbp[(size_t)(i0 + ac * 8 + e) * HDD]);
            *reinterpret_cast<short8*>(&lha[hd_r * 32 + p * 8]) = pk.s8;
        }
        {                                       // stage P'^T: 1 chunk/thread (pure gather)
            int p = bc ^ swz(u_r);
            short8 pk;
            #pragma unroll
            for (int e = 0; e < 8; ++e)
                pk[e] = Pbp[(size_t)(i0 + bc * 8 + e) * LUU];
            *reinterpret_cast<short8*>(&lsa[u_r * 32 + p * 8]) = pk;
        }
        __syncthreads();
        short8 af = *reinterpret_cast<const short8*>(&lha[a_idx]);
        #pragma unroll
        for (int n = 0; n < 4; ++n) {
            short8 bf = *reinterpret_cast<const short8*>(&lsa[b_idx[n]]);
            acc[n] = __builtin_amdgcn_mfma_f32_16x16x32_bf16(af, bf, acc[n], 0, 0, 0);
        }
    }

    __hip_bfloat16* cbt = reinterpret_cast<__hip_bfloat16*>(ws + CBT_OFF);
    #pragma unroll
    for (int q = 0; q < 4; ++q) {
        int hd = hd0 + wave * 16 + lq * 4 + q;
        #pragma unroll
        for (int n = 0; n < 4; ++n) {
            int uu = n * 16 + lj;
            cbt[(size_t)(b * 256 + hd) * 128 + u0 + uu] =
                __float2bfloat16(acc[n][q] * um_s[uu]);
        }
    }
}

// ---------------- K4 (MFMA): U=a_t·u, H=b_t·C, concat output ----------------
// a_t = P'·um_j ; b_t = P'·R2_i·Cc_j with R2 = hm·e^{rm}/ri, Cc = e^{-cm}·ci
__global__ __launch_bounds__(256) void k_outm(const float* __restrict__ h,
                                              const void* __restrict__ h_mask,
                                              const void* __restrict__ u_mask,
                                              const float* __restrict__ ws,
                                              float* __restrict__ out) {
    __shared__ __align__(16) short la[64 * 32], lb[64 * 32];
    __shared__ __align__(16) short lu[128 * 32], lc[128 * 32];
    __shared__ float R2_l[64];
    __shared__ float um_l[128], Cc_l[128];

    int b = blockIdx.x, i0 = blockIdx.y * 64, hd0 = blockIdx.z * 128;
    int t = threadIdx.x;
    int flag = reinterpret_cast<const int*>(ws)[FLAG_OFF];
    int wave = t >> 6, lane = t & 63, lj = lane & 15, lq = lane >> 4;

    if (t < 64) {
        float rmv = ws[RM_OFF + b * LHH + i0 + t];
        float riv = ws[RI_OFF + b * LHH + i0 + t];
        R2_l[t] = mval(h_mask, b * LHH + i0 + t, flag) * cexpf(rmv) / riv;
    } else if (t < 192) {
        int j = t - 64;
        float cmv = ws[CM_OFF + b * LUU + j];
        Cc_l[j] = cexpf(-cmv) * ws[CI_OFF + b * LUU + j];
        um_l[j] = mval(u_mask, b * LUU + j, flag);
    }

    const short* Pbase = reinterpret_cast<const short*>(ws + P_OFF) + (size_t)b * LHH * LUU;
    const short* ubt = reinterpret_cast<const short*>(ws + UBT_OFF) + ((size_t)(b * 256 + hd0)) * 128;
    const short* cbt = reinterpret_cast<const short*>(ws + CBT_OFF) + ((size_t)(b * 256 + hd0)) * 128;

    int air = t >> 2, ap = t & 3;
    int brow = t >> 1;
    int a_idx = (wave * 16 + lj) * 32 + ((lq ^ swz(wave * 16 + lj)) * 8);
    int b_idx[8];
    #pragma unroll
    for (int n = 0; n < 8; ++n) {
        int r = n * 16 + lj;
        b_idx[n] = r * 32 + ((lq ^ swz(r)) * 8);
    }

    f32x4 aU[8], aH[8];
    #pragma unroll
    for (int n = 0; n < 8; ++n) { aU[n] = (f32x4){0,0,0,0}; aH[n] = (f32x4){0,0,0,0}; }

    for (int step = 0; step < 4; ++step) {
        int j0 = step * 32;
        __syncthreads();
        {
            int lgc = ap ^ swz(air);
            short8 pv8 = *reinterpret_cast<const short8*>(
                Pbase + (size_t)(i0 + air) * LUU + j0 + lgc * 8);
            float R2v = R2_l[air];
            union { short8 s8; __hip_bfloat16 bh[8]; } pa, pb;
            #pragma unroll
            for (int c = 0; c < 8; ++c) {
                int j = j0 + lgc * 8 + c;
                float p = b2f(pv8[c]);
                pa.bh[c] = __float2bfloat16(p * um_l[j]);
                pb.bh[c] = __float2bfloat16(p * R2v * Cc_l[j]);
            }
            *reinterpret_cast<short8*>(&la[air * 32 + ap * 8]) = pa.s8;
            *reinterpret_cast<short8*>(&lb[air * 32 + ap * 8]) = pb.s8;
        }
        #pragma unroll
        for (int pp = 0; pp < 2; ++pp) {
            int p = (t & 1) * 2 + pp;
            int lgc = p ^ swz(brow);
            *reinterpret_cast<short8*>(&lu[brow * 32 + p * 8]) =
                *reinterpret_cast<const short8*>(ubt + (size_t)brow * 128 + j0 + lgc * 8);
            *reinterpret_cast<short8*>(&lc[brow * 32 + p * 8]) =
                *reinterpret_cast<const short8*>(cbt + (size_t)brow * 128 + j0 + lgc * 8);
        }
        __syncthreads();
        short8 fa = *reinterpret_cast<const short8*>(&la[a_idx]);
        short8 fb = *reinterpret_cast<const short8*>(&lb[a_idx]);
        #pragma unroll
        for (int n = 0; n < 8; ++n) {
            short8 gu = *reinterpret_cast<const short8*>(&lu[b_idx[n]]);
            short8 gc = *reinterpret_cast<const short8*>(&lc[b_idx[n]]);
            aU[n] = __builtin_amdgcn_mfma_f32_16x16x32_bf16(fa, gu, aU[n], 0, 0, 0);
            aH[n] = __builtin_amdgcn_mfma_f32_16x16x32_bf16(fb, gc, aH[n], 0, 0, 0);
        }
    }

    #pragma unroll
    for (int n = 0; n < 8; ++n) {
        int hd = hd0 + n * 16 + lj;
        #pragma unroll
        for (int q = 0; q < 4; ++q) {
            int i = i0 + wave * 16 + lq * 4 + q;
            float hv = h[((size_t)(b * LHH + i)) * HDD + hd];
            size_t base = ((size_t)(b * LHH + i)) * (4 * HDD) + hd;
            float Uv = aU[n][q], Hv = aH[n][q];
            out[base]           = hv;
            out[base + HDD]     = Uv;
            out[base + 2 * HDD] = hv * Uv;
            out[base + 3 * HDD] = hv * Hv;
        }
    }
}

extern "C" void kernel_launch(void* const* d_in, const int* in_sizes, int n_in,
                              void* d_out, int out_size, void* d_ws, size_t ws_size,
                              hipStream_t stream) {
    const float* h = (const float*)d_in[0];
    const float* u = (const float*)d_in[1];
    const void*  h_mask = d_in[2];
    const void*  u_mask = d_in[3];
    const float* w    = (const float*)d_in[4];
    const float* bias = (const float*)d_in[5];
    float* ws  = (float*)d_ws;
    float* out = (float*)d_out;

    if (ws_size < WS_FLOATS * sizeof(float)) return;  // diagnostic: leaves out zeroed

    k_prep<<<dim3(BB, HDD / 32), 256, 0, stream>>>(u, w, (const unsigned char*)h_mask, ws);
    k_Smfma<<<dim3(BB, LHH / 64), 256, 0, stream>>>(h, u_mask, h_mask, bias, ws);
    k_Cmfma<<<dim3(BB, 4, 2), 256, 0, stream>>>(h, u_mask, ws);
    k_outm<<<dim3(BB, LHH / 64, 2), 256, 0, stream>>>(h, h_mask, u_mask, ws, out);
}